// Round 2
// baseline (587.415 us; speedup 1.0000x reference)
//
#include <hip/hip_runtime.h>

// ProtocolTreeGAttention: aligner Linear -> GAT(128->128,H=4,concat) -> ELU ->
// GAT(512->128,H=1) -> mean-pool -> MLP classifier.
// Round 2: bf16 storage for big intermediates + region aliasing (peak ws ~156 MB,
// was ~307 MB -> suspected ws overflow crash). Compute stays f32.

namespace {

constexpr int NNODE = 65536;   // B*F
constexpr int NEDGE = 262144;
constexpr int NGRAPH = 2048;
constexpr int FPG = 32;

__device__ __forceinline__ float lrelu02(float x) { return x > 0.f ? x : 0.2f * x; }
__device__ __forceinline__ float b2f(unsigned short u) {
  return __uint_as_float(((unsigned)u) << 16);
}
__device__ __forceinline__ unsigned short f2b(float f) {  // RNE bf16 round
  unsigned u = __float_as_uint(f);
  return (unsigned short)((u + 0x7fffu + ((u >> 16) & 1u)) >> 16);
}

// ---- 8-wide loaders (A-tile) ----
__device__ __forceinline__ void load8(const float* p, float o[8]) {
  float4 a = *(const float4*)p;
  float4 b = *(const float4*)(p + 4);
  o[0] = a.x; o[1] = a.y; o[2] = a.z; o[3] = a.w;
  o[4] = b.x; o[5] = b.y; o[6] = b.z; o[7] = b.w;
}
__device__ __forceinline__ void load8(const unsigned short* p, float o[8]) {
  int4 r = *(const int4*)p;  // 8 bf16
  const unsigned* w = (const unsigned*)&r;
#pragma unroll
  for (int i = 0; i < 4; ++i) {
    o[2 * i] = __uint_as_float(w[i] << 16);
    o[2 * i + 1] = __uint_as_float(w[i] & 0xffff0000u);
  }
}
// ---- 4-wide stores (C-tile) ----
__device__ __forceinline__ void store4(float* p, const float v[4]) {
  float4 o; o.x = v[0]; o.y = v[1]; o.z = v[2]; o.w = v[3];
  *(float4*)p = o;
}
__device__ __forceinline__ void store4(unsigned short* p, const float v[4]) {
  ushort4 o; o.x = f2b(v[0]); o.y = f2b(v[1]); o.z = f2b(v[2]); o.w = f2b(v[3]);
  *(ushort4*)p = o;
}

// ---------------- CSR build ----------------

__global__ __launch_bounds__(256) void hist_kernel(const int* __restrict__ dst, int* __restrict__ deg) {
  int e = blockIdx.x * 256 + threadIdx.x;
  if (e < NEDGE) atomicAdd(&deg[dst[e]], 1);
}

__global__ __launch_bounds__(1024) void scan_kernel(const int* __restrict__ deg, int* __restrict__ rowptr,
                                                    int* __restrict__ cursor) {
  __shared__ int sums[1024];
  int t = threadIdx.x;
  int base = t * 64;
  int s = 0;
  for (int i = 0; i < 64; ++i) s += deg[base + i];
  sums[t] = s;
  __syncthreads();
  for (int off = 1; off < 1024; off <<= 1) {
    int v = (t >= off) ? sums[t - off] : 0;
    __syncthreads();
    sums[t] += v;
    __syncthreads();
  }
  int run = (t == 0) ? 0 : sums[t - 1];
  for (int i = 0; i < 64; ++i) {
    rowptr[base + i] = run;
    cursor[base + i] = run;
    run += deg[base + i];
  }
  if (t == 1023) rowptr[NNODE] = run;
}

__global__ __launch_bounds__(256) void scatter_kernel(const int* __restrict__ src, const int* __restrict__ dst,
                                                      int* __restrict__ cursor, int* __restrict__ csr_src) {
  int e = blockIdx.x * 256 + threadIdx.x;
  if (e < NEDGE) {
    int d = dst[e];
    int p = atomicAdd(&cursor[d], 1);
    csr_src[p] = src[e];
  }
}

// ---------------- mixed GEMM: C[M x Nc] = A[M x K] @ B[K x Nc] (+bias) ----------------
// BM=BN=128, BK=16, 256 threads, 8x8 per thread. A: f32 or bf16; B: f32; C: f32 or bf16.

template <typename TA, typename TC>
__global__ __launch_bounds__(256) void gemm_kernel(const TA* __restrict__ A, const float* __restrict__ B,
                                                   TC* __restrict__ C, const float* __restrict__ bias,
                                                   int Nc, int K) {
  __shared__ float As[16][132];  // As[k][m]
  __shared__ float Bs[16][132];  // Bs[k][n]
  const int tid = threadIdx.x;
  const int tx = tid & 15, ty = tid >> 4;
  const int bm = blockIdx.x, bn = blockIdx.y;
  const int m_l = tid >> 1;      // A load: row within tile (2 threads/row)
  const int kh = (tid & 1) * 8;  // A load: k offset
  const int kb = tid >> 4;       // B load: k row
  const int nq = (tid & 15) * 8; // B load: col offset
  const TA* Ap = A + (size_t)(bm * 128 + m_l) * K + kh;
  const float* Bp = B + (size_t)kb * Nc + bn * 128 + nq;

  float acc[8][8];
#pragma unroll
  for (int i = 0; i < 8; ++i)
#pragma unroll
    for (int j = 0; j < 8; ++j) acc[i][j] = 0.f;

  const int ksteps = K / 16;
  for (int t = 0; t < ksteps; ++t) {
    float av8[8], bv8[8];
    load8(Ap + t * 16, av8);
    load8(Bp + (size_t)t * 16 * Nc, bv8);
    __syncthreads();  // previous tile fully consumed
#pragma unroll
    for (int q = 0; q < 8; ++q) As[kh + q][m_l] = av8[q];
    *(float4*)&Bs[kb][nq] = *(float4*)&bv8[0];
    *(float4*)&Bs[kb][nq + 4] = *(float4*)&bv8[4];
    __syncthreads();
#pragma unroll
    for (int kk = 0; kk < 16; ++kk) {
      float4 av0 = *(const float4*)&As[kk][ty * 4];
      float4 av1 = *(const float4*)&As[kk][64 + ty * 4];
      float4 bv0 = *(const float4*)&Bs[kk][tx * 4];
      float4 bv1 = *(const float4*)&Bs[kk][64 + tx * 4];
      float av[8] = {av0.x, av0.y, av0.z, av0.w, av1.x, av1.y, av1.z, av1.w};
      float bv[8] = {bv0.x, bv0.y, bv0.z, bv0.w, bv1.x, bv1.y, bv1.z, bv1.w};
#pragma unroll
      for (int i = 0; i < 8; ++i)
#pragma unroll
        for (int j = 0; j < 8; ++j) acc[i][j] += av[i] * bv[j];
    }
  }

  const int cn0 = bn * 128 + tx * 4;
#pragma unroll
  for (int i = 0; i < 8; ++i) {
    int r = bm * 128 + ((i < 4) ? (ty * 4 + i) : (64 + ty * 4 + i - 4));
    TC* Crow = C + (size_t)r * Nc;
    float o0[4] = {acc[i][0], acc[i][1], acc[i][2], acc[i][3]};
    float o1[4] = {acc[i][4], acc[i][5], acc[i][6], acc[i][7]};
    if (bias != nullptr) {
#pragma unroll
      for (int j = 0; j < 4; ++j) {
        o0[j] += bias[cn0 + j];
        o1[j] += bias[cn0 + 64 + j];
      }
    }
    store4(Crow + cn0, o0);
    store4(Crow + cn0 + 64, o1);
  }
}

// ---------------- attention logits ----------------

__global__ __launch_bounds__(256) void al1_kernel(const unsigned short* __restrict__ hx,
                                                  const float* __restrict__ att_src,
                                                  const float* __restrict__ att_dst,
                                                  float* __restrict__ al_s, float* __restrict__ al_d) {
  int n = blockIdx.x;
  int h = threadIdx.x >> 6;
  int lane = threadIdx.x & 63;
  unsigned v = *(const unsigned*)&hx[(size_t)n * 512 + h * 128 + lane * 2];
  float v0 = __uint_as_float(v << 16);
  float v1 = __uint_as_float(v & 0xffff0000u);
  float2 as = *(const float2*)&att_src[h * 128 + lane * 2];
  float2 ad = *(const float2*)&att_dst[h * 128 + lane * 2];
  float s = v0 * as.x + v1 * as.y;
  float d = v0 * ad.x + v1 * ad.y;
  for (int off = 32; off; off >>= 1) {
    s += __shfl_down(s, off);
    d += __shfl_down(d, off);
  }
  if (lane == 0) {
    al_s[n * 4 + h] = s;
    al_d[n * 4 + h] = d;
  }
}

__global__ __launch_bounds__(256) void al2_kernel(const float* __restrict__ hx,
                                                  const float* __restrict__ att_src,
                                                  const float* __restrict__ att_dst,
                                                  float* __restrict__ al_s, float* __restrict__ al_d) {
  int n = blockIdx.x * 4 + (threadIdx.x >> 6);
  int lane = threadIdx.x & 63;
  float2 v = *(const float2*)&hx[(size_t)n * 128 + lane * 2];
  float2 as = *(const float2*)&att_src[lane * 2];
  float2 ad = *(const float2*)&att_dst[lane * 2];
  float s = v.x * as.x + v.y * as.y;
  float d = v.x * ad.x + v.y * ad.y;
  for (int off = 32; off; off >>= 1) {
    s += __shfl_down(s, off);
    d += __shfl_down(d, off);
  }
  if (lane == 0) {
    al_s[n] = s;
    al_d[n] = d;
  }
}

// ---------------- GAT aggregation (softmax fused; logits O(1) so no segment-max) ----------------

__global__ __launch_bounds__(512) void agg1_kernel(const unsigned short* __restrict__ hx,
                                                   const float* __restrict__ al_s, const float* __restrict__ al_d,
                                                   const int* __restrict__ rowptr, const int* __restrict__ csr_src,
                                                   const float* __restrict__ b1, unsigned short* __restrict__ xout) {
  int n = blockIdx.x;
  int h = threadIdx.x >> 7;
  int c = threadIdx.x & 127;
  float ad = al_d[n * 4 + h];
  float w0 = expf(lrelu02(al_s[n * 4 + h] + ad));  // self-loop
  float acc = w0 * b2f(hx[(size_t)n * 512 + h * 128 + c]);
  float den = w0;
  int p0 = rowptr[n], p1 = rowptr[n + 1];
  for (int p = p0; p < p1; ++p) {
    int s = csr_src[p];
    float ww = expf(lrelu02(al_s[s * 4 + h] + ad));
    acc += ww * b2f(hx[(size_t)s * 512 + h * 128 + c]);
    den += ww;
  }
  float v = acc / (den + 1e-16f) + b1[h * 128 + c];
  xout[(size_t)n * 512 + threadIdx.x] = f2b(v > 0.f ? v : expm1f(v));  // fused ELU
}

__global__ __launch_bounds__(128) void agg2_kernel(const float* __restrict__ hx,
                                                   const float* __restrict__ al_s, const float* __restrict__ al_d,
                                                   const int* __restrict__ rowptr, const int* __restrict__ csr_src,
                                                   const float* __restrict__ b2, float* __restrict__ out) {
  int n = blockIdx.x;
  int c = threadIdx.x;
  float ad = al_d[n];
  float w0 = expf(lrelu02(al_s[n] + ad));
  float acc = w0 * hx[(size_t)n * 128 + c];
  float den = w0;
  int p0 = rowptr[n], p1 = rowptr[n + 1];
  for (int p = p0; p < p1; ++p) {
    int s = csr_src[p];
    float ww = expf(lrelu02(al_s[s] + ad));
    acc += ww * hx[(size_t)s * 128 + c];
    den += ww;
  }
  out[(size_t)n * 128 + c] = acc / (den + 1e-16f) + b2[c];
}

// ---------------- mean-pool + classifier MLP ----------------

__global__ __launch_bounds__(128) void poolcls_kernel(const float* __restrict__ x, const float* __restrict__ Wc1,
                                                      const float* __restrict__ bc1, const float* __restrict__ Wc2,
                                                      const float* __restrict__ bc2, float* __restrict__ out) {
  __shared__ float g[128];
  __shared__ float hcls[64];
  int b = blockIdx.x;
  int t = threadIdx.x;
  const float* base = x + (size_t)b * FPG * 128;
  float s = 0.f;
#pragma unroll
  for (int i = 0; i < FPG; ++i) s += base[i * 128 + t];
  g[t] = s * (1.0f / FPG);
  __syncthreads();
  if (t < 64) {
    float a = bc1[t];
#pragma unroll 4
    for (int k = 0; k < 128; ++k) a += g[k] * Wc1[k * 64 + t];
    hcls[t] = a > 0.f ? a : 0.01f * a;
  }
  __syncthreads();
  if (t < 10) {
    float a = bc2[t];
#pragma unroll
    for (int k = 0; k < 64; ++k) a += hcls[k] * Wc2[k * 10 + t];
    out[b * 10 + t] = a;
  }
}

}  // namespace

extern "C" void kernel_launch(void* const* d_in, const int* in_sizes, int n_in,
                              void* d_out, int out_size, void* d_ws, size_t ws_size,
                              hipStream_t stream) {
  const float* emb = (const float*)d_in[0];
  const int* edge = (const int*)d_in[1];
  // d_in[2] = batch = arange(N)//FPG -> exploited structurally in poolcls
  const float* W_align = (const float*)d_in[3];
  const float* b_align = (const float*)d_in[4];
  const float* W1 = (const float*)d_in[5];
  const float* att_src1 = (const float*)d_in[6];
  const float* att_dst1 = (const float*)d_in[7];
  const float* b1 = (const float*)d_in[8];
  const float* W2 = (const float*)d_in[9];
  const float* att_src2 = (const float*)d_in[10];
  const float* att_dst2 = (const float*)d_in[11];
  const float* b2 = (const float*)d_in[12];
  const float* Wc1 = (const float*)d_in[13];
  const float* bc1 = (const float*)d_in[14];
  const float* Wc2 = (const float*)d_in[15];
  const float* bc2 = (const float*)d_in[16];

  // workspace bump allocator (256B aligned). Peak ~156 MB.
  char* ws = (char*)d_ws;
  size_t off = 0;
  auto alloc = [&](size_t bytes) -> char* {
    char* p = ws + off;
    off += (bytes + 255) & ~(size_t)255;
    return p;
  };
  unsigned short* x0 = (unsigned short*)alloc((size_t)NNODE * 128 * 2);  // aligned x, bf16 (16.8 MB)
  char* big = alloc((size_t)NNODE * 512 * 2);                            // 67.1 MB region
  unsigned short* x1 = (unsigned short*)alloc((size_t)NNODE * 512 * 2);  // ELU(GAT1), bf16 (67.1 MB)
  float* al_s1 = (float*)alloc((size_t)NNODE * 4 * 4);
  float* al_d1 = (float*)alloc((size_t)NNODE * 4 * 4);
  float* al_s2 = (float*)alloc((size_t)NNODE * 4);
  float* al_d2 = (float*)alloc((size_t)NNODE * 4);
  int* deg = (int*)alloc((size_t)NNODE * 4);
  int* rowptr = (int*)alloc((size_t)(NNODE + 1) * 4);
  int* cursor = (int*)alloc((size_t)NNODE * 4);
  int* csr = (int*)alloc((size_t)NEDGE * 4);

  // region aliasing: hx1 (bf16 [N,512]) lives in `big` until agg1 completes;
  // afterwards hx2 (f32 [N,128]) and out2 (f32 [N,128]) share the same region.
  unsigned short* hx1 = (unsigned short*)big;
  float* hx2 = (float*)big;                                    // offset 0, 33.5 MB
  float* out2 = (float*)(big + (size_t)NNODE * 128 * 4);       // offset 33.5 MB

  const int* src = edge;
  const int* dst = edge + NEDGE;

  // CSR by dst (shared by both GAT layers)
  hipMemsetAsync(deg, 0, (size_t)NNODE * 4, stream);
  hist_kernel<<<NEDGE / 256, 256, 0, stream>>>(dst, deg);
  scan_kernel<<<1, 1024, 0, stream>>>(deg, rowptr, cursor);
  scatter_kernel<<<NEDGE / 256, 256, 0, stream>>>(src, dst, cursor, csr);

  // aligner: x0 = emb @ W_align + b_align   [65536,64]@[64,128] -> bf16
  gemm_kernel<float, unsigned short>
      <<<dim3(NNODE / 128, 1), 256, 0, stream>>>(emb, W_align, x0, b_align, 128, 64);
  // GAT1 transform: hx1 = x0 @ W1           [65536,128]@[128,512] -> bf16
  gemm_kernel<unsigned short, unsigned short>
      <<<dim3(NNODE / 128, 4), 256, 0, stream>>>(x0, W1, hx1, nullptr, 512, 128);
  al1_kernel<<<NNODE, 256, 0, stream>>>(hx1, att_src1, att_dst1, al_s1, al_d1);
  agg1_kernel<<<NNODE, 512, 0, stream>>>(hx1, al_s1, al_d1, rowptr, csr, b1, x1);
  // GAT2 transform: hx2 = x1 @ W2           [65536,512]@[512,128] -> f32 (aliases dead hx1)
  gemm_kernel<unsigned short, float>
      <<<dim3(NNODE / 128, 1), 256, 0, stream>>>(x1, W2, hx2, nullptr, 128, 512);
  al2_kernel<<<NNODE / 4, 256, 0, stream>>>(hx2, att_src2, att_dst2, al_s2, al_d2);
  agg2_kernel<<<NNODE, 128, 0, stream>>>(hx2, al_s2, al_d2, rowptr, csr, b2, out2);
  // pool + classifier
  poolcls_kernel<<<NGRAPH, 128, 0, stream>>>(out2, Wc1, bc1, Wc2, bc2, (float*)d_out);
}

// Round 3
// 486.298 us; speedup vs baseline: 1.2079x; 1.2079x over previous
//
#include <hip/hip_runtime.h>

// ProtocolTreeGAttention: aligner Linear -> GAT(128->128,H=4,concat) -> ELU ->
// GAT(512->128,H=1) -> mean-pool -> MLP classifier.
// Round 3: per-edge attention weights precomputed in CSR order (w1/w2), so the
// aggregation kernels become pure weighted gathers (no per-channel expf).

namespace {

constexpr int NNODE = 65536;   // B*F
constexpr int NEDGE = 262144;
constexpr int NGRAPH = 2048;
constexpr int FPG = 32;

__device__ __forceinline__ float lrelu02(float x) { return x > 0.f ? x : 0.2f * x; }
__device__ __forceinline__ float bf_lo(unsigned u) { return __uint_as_float(u << 16); }
__device__ __forceinline__ float bf_hi(unsigned u) { return __uint_as_float(u & 0xffff0000u); }
__device__ __forceinline__ unsigned short f2b(float f) {  // RNE bf16 round
  unsigned u = __float_as_uint(f);
  return (unsigned short)((u + 0x7fffu + ((u >> 16) & 1u)) >> 16);
}

// ---- 8-wide loaders (GEMM A/B tiles) ----
__device__ __forceinline__ void load8(const float* p, float o[8]) {
  float4 a = *(const float4*)p;
  float4 b = *(const float4*)(p + 4);
  o[0] = a.x; o[1] = a.y; o[2] = a.z; o[3] = a.w;
  o[4] = b.x; o[5] = b.y; o[6] = b.z; o[7] = b.w;
}
__device__ __forceinline__ void load8(const unsigned short* p, float o[8]) {
  int4 r = *(const int4*)p;  // 8 bf16
  const unsigned* w = (const unsigned*)&r;
#pragma unroll
  for (int i = 0; i < 4; ++i) {
    o[2 * i] = bf_lo(w[i]);
    o[2 * i + 1] = bf_hi(w[i]);
  }
}
// ---- 4-wide stores (GEMM C tiles) ----
__device__ __forceinline__ void store4(float* p, const float v[4]) {
  float4 o; o.x = v[0]; o.y = v[1]; o.z = v[2]; o.w = v[3];
  *(float4*)p = o;
}
__device__ __forceinline__ void store4(unsigned short* p, const float v[4]) {
  ushort4 o; o.x = f2b(v[0]); o.y = f2b(v[1]); o.z = f2b(v[2]); o.w = f2b(v[3]);
  *(ushort4*)p = o;
}

// ---------------- CSR build ----------------

__global__ __launch_bounds__(256) void hist_kernel(const int* __restrict__ dst, int* __restrict__ deg) {
  int e = blockIdx.x * 256 + threadIdx.x;
  if (e < NEDGE) atomicAdd(&deg[dst[e]], 1);
}

__global__ __launch_bounds__(1024) void scan_kernel(const int* __restrict__ deg, int* __restrict__ rowptr,
                                                    int* __restrict__ cursor) {
  __shared__ int sums[1024];
  int t = threadIdx.x;
  int base = t * 64;
  int s = 0;
  for (int i = 0; i < 64; ++i) s += deg[base + i];
  sums[t] = s;
  __syncthreads();
  for (int off = 1; off < 1024; off <<= 1) {
    int v = (t >= off) ? sums[t - off] : 0;
    __syncthreads();
    sums[t] += v;
    __syncthreads();
  }
  int run = (t == 0) ? 0 : sums[t - 1];
  for (int i = 0; i < 64; ++i) {
    rowptr[base + i] = run;
    cursor[base + i] = run;
    run += deg[base + i];
  }
  if (t == 1023) rowptr[NNODE] = run;
}

__global__ __launch_bounds__(256) void scatter_kernel(const int* __restrict__ src, const int* __restrict__ dst,
                                                      int* __restrict__ cursor, int* __restrict__ csr_src,
                                                      int* __restrict__ csr_dst) {
  int e = blockIdx.x * 256 + threadIdx.x;
  if (e < NEDGE) {
    int s = src[e], d = dst[e];
    int p = atomicAdd(&cursor[d], 1);
    csr_src[p] = s;
    csr_dst[p] = d;
  }
}

// ---------------- per-edge attention weights (CSR order) ----------------

__global__ __launch_bounds__(256) void edgew1_kernel(const int* __restrict__ csr_src, const int* __restrict__ csr_dst,
                                                     const float* __restrict__ al_s, const float* __restrict__ al_d,
                                                     float* __restrict__ w1) {
  int p = blockIdx.x * 256 + threadIdx.x;
  if (p >= NEDGE) return;
  int s = csr_src[p], d = csr_dst[p];
  float4 as = *(const float4*)&al_s[s * 4];
  float4 ad = *(const float4*)&al_d[d * 4];
  float4 w;
  w.x = expf(lrelu02(as.x + ad.x));
  w.y = expf(lrelu02(as.y + ad.y));
  w.z = expf(lrelu02(as.z + ad.z));
  w.w = expf(lrelu02(as.w + ad.w));
  *(float4*)&w1[(size_t)p * 4] = w;
}

__global__ __launch_bounds__(256) void edgew2_kernel(const int* __restrict__ csr_src, const int* __restrict__ csr_dst,
                                                     const float* __restrict__ al_s, const float* __restrict__ al_d,
                                                     float* __restrict__ w2) {
  int p = blockIdx.x * 256 + threadIdx.x;
  if (p >= NEDGE) return;
  w2[p] = expf(lrelu02(al_s[csr_src[p]] + al_d[csr_dst[p]]));
}

// ---------------- mixed GEMM: C[M x Nc] = A[M x K] @ B[K x Nc] (+bias) ----------------
// BM=BN=128, BK=16, 256 threads, 8x8 per thread. A: f32 or bf16; B: f32; C: f32 or bf16.

template <typename TA, typename TC>
__global__ __launch_bounds__(256) void gemm_kernel(const TA* __restrict__ A, const float* __restrict__ B,
                                                   TC* __restrict__ C, const float* __restrict__ bias,
                                                   int Nc, int K) {
  __shared__ float As[16][132];  // As[k][m]
  __shared__ float Bs[16][132];  // Bs[k][n]
  const int tid = threadIdx.x;
  const int tx = tid & 15, ty = tid >> 4;
  const int bm = blockIdx.x, bn = blockIdx.y;
  const int m_l = tid >> 1;      // A load: row within tile (2 threads/row)
  const int kh = (tid & 1) * 8;  // A load: k offset
  const int kb = tid >> 4;       // B load: k row
  const int nq = (tid & 15) * 8; // B load: col offset
  const TA* Ap = A + (size_t)(bm * 128 + m_l) * K + kh;
  const float* Bp = B + (size_t)kb * Nc + bn * 128 + nq;

  float acc[8][8];
#pragma unroll
  for (int i = 0; i < 8; ++i)
#pragma unroll
    for (int j = 0; j < 8; ++j) acc[i][j] = 0.f;

  const int ksteps = K / 16;
  for (int t = 0; t < ksteps; ++t) {
    float av8[8], bv8[8];
    load8(Ap + t * 16, av8);
    load8(Bp + (size_t)t * 16 * Nc, bv8);
    __syncthreads();  // previous tile fully consumed
#pragma unroll
    for (int q = 0; q < 8; ++q) As[kh + q][m_l] = av8[q];
    *(float4*)&Bs[kb][nq] = *(float4*)&bv8[0];
    *(float4*)&Bs[kb][nq + 4] = *(float4*)&bv8[4];
    __syncthreads();
#pragma unroll
    for (int kk = 0; kk < 16; ++kk) {
      float4 av0 = *(const float4*)&As[kk][ty * 4];
      float4 av1 = *(const float4*)&As[kk][64 + ty * 4];
      float4 bv0 = *(const float4*)&Bs[kk][tx * 4];
      float4 bv1 = *(const float4*)&Bs[kk][64 + tx * 4];
      float av[8] = {av0.x, av0.y, av0.z, av0.w, av1.x, av1.y, av1.z, av1.w};
      float bv[8] = {bv0.x, bv0.y, bv0.z, bv0.w, bv1.x, bv1.y, bv1.z, bv1.w};
#pragma unroll
      for (int i = 0; i < 8; ++i)
#pragma unroll
        for (int j = 0; j < 8; ++j) acc[i][j] += av[i] * bv[j];
    }
  }

  const int cn0 = bn * 128 + tx * 4;
#pragma unroll
  for (int i = 0; i < 8; ++i) {
    int r = bm * 128 + ((i < 4) ? (ty * 4 + i) : (64 + ty * 4 + i - 4));
    TC* Crow = C + (size_t)r * Nc;
    float o0[4] = {acc[i][0], acc[i][1], acc[i][2], acc[i][3]};
    float o1[4] = {acc[i][4], acc[i][5], acc[i][6], acc[i][7]};
    if (bias != nullptr) {
#pragma unroll
      for (int j = 0; j < 4; ++j) {
        o0[j] += bias[cn0 + j];
        o1[j] += bias[cn0 + 64 + j];
      }
    }
    store4(Crow + cn0, o0);
    store4(Crow + cn0 + 64, o1);
  }
}

// ---------------- attention logits ----------------

__global__ __launch_bounds__(256) void al1_kernel(const unsigned short* __restrict__ hx,
                                                  const float* __restrict__ att_src,
                                                  const float* __restrict__ att_dst,
                                                  float* __restrict__ al_s, float* __restrict__ al_d) {
  int n = blockIdx.x;
  int h = threadIdx.x >> 6;
  int lane = threadIdx.x & 63;
  unsigned v = *(const unsigned*)&hx[(size_t)n * 512 + h * 128 + lane * 2];
  float v0 = bf_lo(v), v1 = bf_hi(v);
  float2 as = *(const float2*)&att_src[h * 128 + lane * 2];
  float2 ad = *(const float2*)&att_dst[h * 128 + lane * 2];
  float s = v0 * as.x + v1 * as.y;
  float d = v0 * ad.x + v1 * ad.y;
  for (int off = 32; off; off >>= 1) {
    s += __shfl_down(s, off);
    d += __shfl_down(d, off);
  }
  if (lane == 0) {
    al_s[n * 4 + h] = s;
    al_d[n * 4 + h] = d;
  }
}

__global__ __launch_bounds__(256) void al2_kernel(const float* __restrict__ hx,
                                                  const float* __restrict__ att_src,
                                                  const float* __restrict__ att_dst,
                                                  float* __restrict__ al_s, float* __restrict__ al_d) {
  int n = blockIdx.x * 4 + (threadIdx.x >> 6);
  int lane = threadIdx.x & 63;
  float2 v = *(const float2*)&hx[(size_t)n * 128 + lane * 2];
  float2 as = *(const float2*)&att_src[lane * 2];
  float2 ad = *(const float2*)&att_dst[lane * 2];
  float s = v.x * as.x + v.y * as.y;
  float d = v.x * ad.x + v.y * ad.y;
  for (int off = 32; off; off >>= 1) {
    s += __shfl_down(s, off);
    d += __shfl_down(d, off);
  }
  if (lane == 0) {
    al_s[n] = s;
    al_d[n] = d;
  }
}

// ---------------- GAT aggregation: pure weighted gather ----------------
// agg1: 256 threads/node = 4 heads x 64 lanes x 2 bf16 channels.

__global__ __launch_bounds__(256) void agg1_kernel(const unsigned short* __restrict__ hx,
                                                   const float* __restrict__ al_s, const float* __restrict__ al_d,
                                                   const int* __restrict__ rowptr, const int* __restrict__ csr_src,
                                                   const float* __restrict__ w1, const float* __restrict__ b1,
                                                   unsigned short* __restrict__ xout) {
  int n = blockIdx.x;
  int h = threadIdx.x >> 6;
  int c2 = (threadIdx.x & 63) * 2;
  const int col = h * 128 + c2;
  float w0 = expf(lrelu02(al_s[n * 4 + h] + al_d[n * 4 + h]));  // self-loop
  unsigned u = *(const unsigned*)&hx[(size_t)n * 512 + col];
  float acc0 = w0 * bf_lo(u), acc1 = w0 * bf_hi(u);
  float den = w0;
  int p0 = rowptr[n], p1 = rowptr[n + 1];
  for (int p = p0; p < p1; ++p) {
    int s = csr_src[p];
    float w = w1[(size_t)p * 4 + h];  // broadcast across the 64 lanes of this head
    unsigned uu = *(const unsigned*)&hx[(size_t)s * 512 + col];
    acc0 += w * bf_lo(uu);
    acc1 += w * bf_hi(uu);
    den += w;
  }
  float inv = 1.f / (den + 1e-16f);
  float v0 = acc0 * inv + b1[col];
  float v1 = acc1 * inv + b1[col + 1];
  v0 = v0 > 0.f ? v0 : expm1f(v0);  // fused ELU
  v1 = v1 > 0.f ? v1 : expm1f(v1);
  ushort2 o; o.x = f2b(v0); o.y = f2b(v1);
  *(ushort2*)&xout[(size_t)n * 512 + col] = o;
}

// agg2: 64 threads/node (4 nodes per 256-block), 2 f32 channels per thread.

__global__ __launch_bounds__(256) void agg2_kernel(const float* __restrict__ hx,
                                                   const float* __restrict__ al_s, const float* __restrict__ al_d,
                                                   const int* __restrict__ rowptr, const int* __restrict__ csr_src,
                                                   const float* __restrict__ w2, const float* __restrict__ b2,
                                                   float* __restrict__ out) {
  int n = blockIdx.x * 4 + (threadIdx.x >> 6);
  int c2 = (threadIdx.x & 63) * 2;
  float w0 = expf(lrelu02(al_s[n] + al_d[n]));
  float2 v = *(const float2*)&hx[(size_t)n * 128 + c2];
  float acc0 = w0 * v.x, acc1 = w0 * v.y;
  float den = w0;
  int p0 = rowptr[n], p1 = rowptr[n + 1];
  for (int p = p0; p < p1; ++p) {
    int s = csr_src[p];
    float w = w2[p];
    float2 vv = *(const float2*)&hx[(size_t)s * 128 + c2];
    acc0 += w * vv.x;
    acc1 += w * vv.y;
    den += w;
  }
  float inv = 1.f / (den + 1e-16f);
  float2 o;
  o.x = acc0 * inv + b2[c2];
  o.y = acc1 * inv + b2[c2 + 1];
  *(float2*)&out[(size_t)n * 128 + c2] = o;
}

// ---------------- mean-pool + classifier MLP ----------------

__global__ __launch_bounds__(128) void poolcls_kernel(const float* __restrict__ x, const float* __restrict__ Wc1,
                                                      const float* __restrict__ bc1, const float* __restrict__ Wc2,
                                                      const float* __restrict__ bc2, float* __restrict__ out) {
  __shared__ float g[128];
  __shared__ float hcls[64];
  int b = blockIdx.x;
  int t = threadIdx.x;
  const float* base = x + (size_t)b * FPG * 128;
  float s = 0.f;
#pragma unroll
  for (int i = 0; i < FPG; ++i) s += base[i * 128 + t];
  g[t] = s * (1.0f / FPG);
  __syncthreads();
  if (t < 64) {
    float a = bc1[t];
#pragma unroll 4
    for (int k = 0; k < 128; ++k) a += g[k] * Wc1[k * 64 + t];
    hcls[t] = a > 0.f ? a : 0.01f * a;
  }
  __syncthreads();
  if (t < 10) {
    float a = bc2[t];
#pragma unroll
    for (int k = 0; k < 64; ++k) a += hcls[k] * Wc2[k * 10 + t];
    out[b * 10 + t] = a;
  }
}

}  // namespace

extern "C" void kernel_launch(void* const* d_in, const int* in_sizes, int n_in,
                              void* d_out, int out_size, void* d_ws, size_t ws_size,
                              hipStream_t stream) {
  const float* emb = (const float*)d_in[0];
  const int* edge = (const int*)d_in[1];
  // d_in[2] = batch = arange(N)//FPG -> exploited structurally in poolcls
  const float* W_align = (const float*)d_in[3];
  const float* b_align = (const float*)d_in[4];
  const float* W1 = (const float*)d_in[5];
  const float* att_src1 = (const float*)d_in[6];
  const float* att_dst1 = (const float*)d_in[7];
  const float* b1 = (const float*)d_in[8];
  const float* W2 = (const float*)d_in[9];
  const float* att_src2 = (const float*)d_in[10];
  const float* att_dst2 = (const float*)d_in[11];
  const float* b2 = (const float*)d_in[12];
  const float* Wc1 = (const float*)d_in[13];
  const float* bc1 = (const float*)d_in[14];
  const float* Wc2 = (const float*)d_in[15];
  const float* bc2 = (const float*)d_in[16];

  // workspace bump allocator (256B aligned). Peak ~162 MB.
  char* ws = (char*)d_ws;
  size_t off = 0;
  auto alloc = [&](size_t bytes) -> char* {
    char* p = ws + off;
    off += (bytes + 255) & ~(size_t)255;
    return p;
  };
  unsigned short* x0 = (unsigned short*)alloc((size_t)NNODE * 128 * 2);  // aligned x, bf16
  char* big = alloc((size_t)NNODE * 512 * 2);                            // 67.1 MB region
  unsigned short* x1 = (unsigned short*)alloc((size_t)NNODE * 512 * 2);  // ELU(GAT1), bf16
  float* al_s1 = (float*)alloc((size_t)NNODE * 4 * 4);
  float* al_d1 = (float*)alloc((size_t)NNODE * 4 * 4);
  float* al_s2 = (float*)alloc((size_t)NNODE * 4);
  float* al_d2 = (float*)alloc((size_t)NNODE * 4);
  int* deg = (int*)alloc((size_t)NNODE * 4);
  int* rowptr = (int*)alloc((size_t)(NNODE + 1) * 4);
  int* cursor = (int*)alloc((size_t)NNODE * 4);
  int* csr_src = (int*)alloc((size_t)NEDGE * 4);
  int* csr_dst = (int*)alloc((size_t)NEDGE * 4);
  float* w1 = (float*)alloc((size_t)NEDGE * 4 * 4);  // per-edge weights, 4 heads
  float* w2 = (float*)alloc((size_t)NEDGE * 4);

  // region aliasing: hx1 (bf16 [N,512]) lives in `big` until agg1 completes;
  // afterwards hx2 (f32 [N,128]) and out2 (f32 [N,128]) share the same region.
  unsigned short* hx1 = (unsigned short*)big;
  float* hx2 = (float*)big;                               // offset 0
  float* out2 = (float*)(big + (size_t)NNODE * 128 * 4);  // offset 33.5 MB

  const int* src = edge;
  const int* dst = edge + NEDGE;

  // CSR by dst (shared by both GAT layers)
  hipMemsetAsync(deg, 0, (size_t)NNODE * 4, stream);
  hist_kernel<<<NEDGE / 256, 256, 0, stream>>>(dst, deg);
  scan_kernel<<<1, 1024, 0, stream>>>(deg, rowptr, cursor);
  scatter_kernel<<<NEDGE / 256, 256, 0, stream>>>(src, dst, cursor, csr_src, csr_dst);

  // aligner: x0 = emb @ W_align + b_align   [65536,64]@[64,128] -> bf16
  gemm_kernel<float, unsigned short>
      <<<dim3(NNODE / 128, 1), 256, 0, stream>>>(emb, W_align, x0, b_align, 128, 64);
  // GAT1 transform: hx1 = x0 @ W1           [65536,128]@[128,512] -> bf16
  gemm_kernel<unsigned short, unsigned short>
      <<<dim3(NNODE / 128, 4), 256, 0, stream>>>(x0, W1, hx1, nullptr, 512, 128);
  al1_kernel<<<NNODE, 256, 0, stream>>>(hx1, att_src1, att_dst1, al_s1, al_d1);
  edgew1_kernel<<<NEDGE / 256, 256, 0, stream>>>(csr_src, csr_dst, al_s1, al_d1, w1);
  agg1_kernel<<<NNODE, 256, 0, stream>>>(hx1, al_s1, al_d1, rowptr, csr_src, w1, b1, x1);
  // GAT2 transform: hx2 = x1 @ W2           [65536,512]@[512,128] -> f32 (aliases dead hx1)
  gemm_kernel<unsigned short, float>
      <<<dim3(NNODE / 128, 1), 256, 0, stream>>>(x1, W2, hx2, nullptr, 128, 512);
  al2_kernel<<<NNODE / 4, 256, 0, stream>>>(hx2, att_src2, att_dst2, al_s2, al_d2);
  edgew2_kernel<<<NEDGE / 256, 256, 0, stream>>>(csr_src, csr_dst, al_s2, al_d2, w2);
  agg2_kernel<<<NNODE / 4, 256, 0, stream>>>(hx2, al_s2, al_d2, rowptr, csr_src, w2, b2, out2);
  // pool + classifier
  poolcls_kernel<<<NGRAPH, 128, 0, stream>>>(out2, Wc1, bc1, Wc2, bc2, (float*)d_out);
}

// Round 4
// 398.560 us; speedup vs baseline: 1.4738x; 1.2201x over previous
//
#include <hip/hip_runtime.h>

// ProtocolTreeGAttention: aligner Linear -> GAT(128->128,H=4,concat) -> ELU ->
// GAT(512->128,H=1) -> mean-pool -> MLP classifier.
// Round 4: bf16 MFMA (16x16x32) for the two big GEMMs; weights converted/
// transposed to [N][K] bf16 on device; XOR-swizzled LDS tiles.

namespace {

constexpr int NNODE = 65536;   // B*F
constexpr int NEDGE = 262144;
constexpr int NGRAPH = 2048;
constexpr int FPG = 32;

typedef __attribute__((ext_vector_type(8))) short bf16x8;
typedef __attribute__((ext_vector_type(4))) float f32x4;

__device__ __forceinline__ float lrelu02(float x) { return x > 0.f ? x : 0.2f * x; }
__device__ __forceinline__ float bf_lo(unsigned u) { return __uint_as_float(u << 16); }
__device__ __forceinline__ float bf_hi(unsigned u) { return __uint_as_float(u & 0xffff0000u); }
__device__ __forceinline__ unsigned short f2b(float f) {  // RNE bf16 round
  unsigned u = __float_as_uint(f);
  return (unsigned short)((u + 0x7fffu + ((u >> 16) & 1u)) >> 16);
}

// ---- 8-wide loaders (vector GEMM tiles) ----
__device__ __forceinline__ void load8(const float* p, float o[8]) {
  float4 a = *(const float4*)p;
  float4 b = *(const float4*)(p + 4);
  o[0] = a.x; o[1] = a.y; o[2] = a.z; o[3] = a.w;
  o[4] = b.x; o[5] = b.y; o[6] = b.z; o[7] = b.w;
}
__device__ __forceinline__ void store4(unsigned short* p, const float v[4]) {
  ushort4 o; o.x = f2b(v[0]); o.y = f2b(v[1]); o.z = f2b(v[2]); o.w = f2b(v[3]);
  *(ushort4*)p = o;
}

// ---------------- CSR build ----------------

__global__ __launch_bounds__(256) void hist_kernel(const int* __restrict__ dst, int* __restrict__ deg) {
  int e = blockIdx.x * 256 + threadIdx.x;
  if (e < NEDGE) atomicAdd(&deg[dst[e]], 1);
}

__global__ __launch_bounds__(1024) void scan_kernel(const int* __restrict__ deg, int* __restrict__ rowptr,
                                                    int* __restrict__ cursor) {
  __shared__ int sums[1024];
  int t = threadIdx.x;
  int base = t * 64;
  int s = 0;
  for (int i = 0; i < 64; ++i) s += deg[base + i];
  sums[t] = s;
  __syncthreads();
  for (int off = 1; off < 1024; off <<= 1) {
    int v = (t >= off) ? sums[t - off] : 0;
    __syncthreads();
    sums[t] += v;
    __syncthreads();
  }
  int run = (t == 0) ? 0 : sums[t - 1];
  for (int i = 0; i < 64; ++i) {
    rowptr[base + i] = run;
    cursor[base + i] = run;
    run += deg[base + i];
  }
  if (t == 1023) rowptr[NNODE] = run;
}

__global__ __launch_bounds__(256) void scatter_kernel(const int* __restrict__ src, const int* __restrict__ dst,
                                                      int* __restrict__ cursor, int* __restrict__ csr_src,
                                                      int* __restrict__ csr_dst) {
  int e = blockIdx.x * 256 + threadIdx.x;
  if (e < NEDGE) {
    int s = src[e], d = dst[e];
    int p = atomicAdd(&cursor[d], 1);
    csr_src[p] = s;
    csr_dst[p] = d;
  }
}

// ---------------- weight convert: Wt[n][k] = bf16(W[k][n]) ----------------

__global__ __launch_bounds__(256) void convw_kernel(const float* __restrict__ W, unsigned short* __restrict__ Wt,
                                                    int K, int N) {
  int idx = blockIdx.x * 256 + threadIdx.x;
  if (idx >= K * N) return;
  int n = idx / K, k = idx - n * K;
  Wt[idx] = f2b(W[(size_t)k * N + n]);
}

// ---------------- per-edge attention weights (CSR order) ----------------

__global__ __launch_bounds__(256) void edgew1_kernel(const int* __restrict__ csr_src, const int* __restrict__ csr_dst,
                                                     const float* __restrict__ al_s, const float* __restrict__ al_d,
                                                     float* __restrict__ w1) {
  int p = blockIdx.x * 256 + threadIdx.x;
  if (p >= NEDGE) return;
  int s = csr_src[p], d = csr_dst[p];
  float4 as = *(const float4*)&al_s[s * 4];
  float4 ad = *(const float4*)&al_d[d * 4];
  float4 w;
  w.x = expf(lrelu02(as.x + ad.x));
  w.y = expf(lrelu02(as.y + ad.y));
  w.z = expf(lrelu02(as.z + ad.z));
  w.w = expf(lrelu02(as.w + ad.w));
  *(float4*)&w1[(size_t)p * 4] = w;
}

__global__ __launch_bounds__(256) void edgew2_kernel(const int* __restrict__ csr_src, const int* __restrict__ csr_dst,
                                                     const float* __restrict__ al_s, const float* __restrict__ al_d,
                                                     float* __restrict__ w2) {
  int p = blockIdx.x * 256 + threadIdx.x;
  if (p >= NEDGE) return;
  w2[p] = expf(lrelu02(al_s[csr_src[p]] + al_d[csr_dst[p]]));
}

// ---------------- MFMA GEMM: C[M x Nc] = A[M x K] @ Wt[Nc x K]^T ----------------
// BM=BN=128, BK=64, 256 threads = 4 waves (2x2), each wave 64x64 out (4x4 frags).
// LDS tiles [128 rows][64 bf16] with byte-XOR swizzle ((row&7)<<4) on 16B chunks.
// Frag layout (m91-verified): lane&15 = m/n; k = (lane>>4)*4 + (j&3) + 16*(j>>2).

__device__ __forceinline__ bf16x8 frag_ld(const unsigned short* lds, int row, int kbyte) {
  const char* base = (const char*)lds + row * 128;
  int sw = (row & 7) << 4;
  uint2 lo = *(const uint2*)(base + (kbyte ^ sw));
  uint2 hi = *(const uint2*)(base + ((kbyte + 32) ^ sw));
  union { bf16x8 v; uint2 u2[2]; } f;
  f.u2[0] = lo;
  f.u2[1] = hi;
  return f.v;
}

template <int K, typename TC>
__global__ __launch_bounds__(256) void gemm_mfma_kernel(const unsigned short* __restrict__ A,
                                                        const unsigned short* __restrict__ Bt,
                                                        TC* __restrict__ C, int Nc) {
  __shared__ unsigned short As[128 * 64];
  __shared__ unsigned short Bs[128 * 64];
  const int tid = threadIdx.x;
  const int lane = tid & 63;
  const int wave = tid >> 6;
  const int wm = wave >> 1, wn = wave & 1;
  const size_t bm = (size_t)blockIdx.x * 128;
  const int bn = blockIdx.y * 128;

  // staging: thread covers rows {srow, srow+32, srow+64, srow+96}, 16B each
  const int srow = tid >> 3;
  const int scolb = (tid & 7) << 4;
  const int sdst = srow * 64 + ((scolb ^ ((srow & 7) << 4)) >> 1);  // ushort index
  const char* Ag = (const char*)(A + (bm + srow) * K) + scolb;
  const char* Bg = (const char*)(Bt + (size_t)(bn + srow) * K) + scolb;

  f32x4 zero = {0.f, 0.f, 0.f, 0.f};
  f32x4 acc[4][4];
#pragma unroll
  for (int i = 0; i < 4; ++i)
#pragma unroll
    for (int j = 0; j < 4; ++j) acc[i][j] = zero;

  const int fr_a = wm * 64 + (lane & 15);  // + mt*16
  const int fr_b = wn * 64 + (lane & 15);  // + nt*16
  const int kb0 = (lane >> 4) << 3;        // 0,8,16,24 bytes

  for (int kt = 0; kt < K; kt += 64) {
    uint4 av[4], bv[4];
#pragma unroll
    for (int i = 0; i < 4; ++i) {
      av[i] = *(const uint4*)(Ag + (size_t)32 * i * K * 2);
      bv[i] = *(const uint4*)(Bg + (size_t)32 * i * K * 2);
    }
    Ag += 128;  // +64 bf16 in k
    Bg += 128;
    if (kt) __syncthreads();  // previous tile fully consumed before overwrite
#pragma unroll
    for (int i = 0; i < 4; ++i) {
      *(uint4*)(As + sdst + 2048 * i) = av[i];
      *(uint4*)(Bs + sdst + 2048 * i) = bv[i];
    }
    __syncthreads();
#pragma unroll
    for (int kk = 0; kk < 2; ++kk) {
      bf16x8 af[4], bfr[4];
#pragma unroll
      for (int mt = 0; mt < 4; ++mt) af[mt] = frag_ld(As, fr_a + mt * 16, kk * 64 + kb0);
#pragma unroll
      for (int nt = 0; nt < 4; ++nt) bfr[nt] = frag_ld(Bs, fr_b + nt * 16, kk * 64 + kb0);
#pragma unroll
      for (int mt = 0; mt < 4; ++mt)
#pragma unroll
        for (int nt = 0; nt < 4; ++nt)
          acc[mt][nt] = __builtin_amdgcn_mfma_f32_16x16x32_bf16(af[mt], bfr[nt], acc[mt][nt], 0, 0, 0);
    }
  }

  // epilogue: C/D layout col = lane&15, row = (lane>>4)*4 + reg
  const int ln = lane & 15, lg = lane >> 4;
#pragma unroll
  for (int mt = 0; mt < 4; ++mt) {
#pragma unroll
    for (int r = 0; r < 4; ++r) {
      size_t row = bm + wm * 64 + mt * 16 + lg * 4 + r;
      TC* Cp = C + row * Nc + bn + wn * 64 + ln;
#pragma unroll
      for (int nt = 0; nt < 4; ++nt) {
        float v = acc[mt][nt][r];
        if constexpr (sizeof(TC) == 2)
          Cp[nt * 16] = f2b(v);
        else
          Cp[nt * 16] = v;
      }
    }
  }
}

// ---------------- vector GEMM (aligner only): C = A[M x K] @ B[K x Nc] + bias ----------------

__global__ __launch_bounds__(256) void gemm_align_kernel(const float* __restrict__ A, const float* __restrict__ B,
                                                         unsigned short* __restrict__ C, const float* __restrict__ bias,
                                                         int Nc, int K) {
  __shared__ float Asm[16][132];
  __shared__ float Bsm[16][132];
  const int tid = threadIdx.x;
  const int tx = tid & 15, ty = tid >> 4;
  const int bm = blockIdx.x, bn = blockIdx.y;
  const int m_l = tid >> 1;
  const int kh = (tid & 1) * 8;
  const int kb = tid >> 4;
  const int nq = (tid & 15) * 8;
  const float* Ap = A + (size_t)(bm * 128 + m_l) * K + kh;
  const float* Bp = B + (size_t)kb * Nc + bn * 128 + nq;

  float acc[8][8];
#pragma unroll
  for (int i = 0; i < 8; ++i)
#pragma unroll
    for (int j = 0; j < 8; ++j) acc[i][j] = 0.f;

  const int ksteps = K / 16;
  for (int t = 0; t < ksteps; ++t) {
    float av8[8], bv8[8];
    load8(Ap + t * 16, av8);
    load8(Bp + (size_t)t * 16 * Nc, bv8);
    __syncthreads();
#pragma unroll
    for (int q = 0; q < 8; ++q) Asm[kh + q][m_l] = av8[q];
    *(float4*)&Bsm[kb][nq] = *(float4*)&bv8[0];
    *(float4*)&Bsm[kb][nq + 4] = *(float4*)&bv8[4];
    __syncthreads();
#pragma unroll
    for (int kk = 0; kk < 16; ++kk) {
      float4 av0 = *(const float4*)&Asm[kk][ty * 4];
      float4 av1 = *(const float4*)&Asm[kk][64 + ty * 4];
      float4 bv0 = *(const float4*)&Bsm[kk][tx * 4];
      float4 bv1 = *(const float4*)&Bsm[kk][64 + tx * 4];
      float av[8] = {av0.x, av0.y, av0.z, av0.w, av1.x, av1.y, av1.z, av1.w};
      float bv[8] = {bv0.x, bv0.y, bv0.z, bv0.w, bv1.x, bv1.y, bv1.z, bv1.w};
#pragma unroll
      for (int i = 0; i < 8; ++i)
#pragma unroll
        for (int j = 0; j < 8; ++j) acc[i][j] += av[i] * bv[j];
    }
  }

  const int cn0 = bn * 128 + tx * 4;
#pragma unroll
  for (int i = 0; i < 8; ++i) {
    int r = bm * 128 + ((i < 4) ? (ty * 4 + i) : (64 + ty * 4 + i - 4));
    unsigned short* Crow = C + (size_t)r * Nc;
    float o0[4] = {acc[i][0], acc[i][1], acc[i][2], acc[i][3]};
    float o1[4] = {acc[i][4], acc[i][5], acc[i][6], acc[i][7]};
#pragma unroll
    for (int j = 0; j < 4; ++j) {
      o0[j] += bias[cn0 + j];
      o1[j] += bias[cn0 + 64 + j];
    }
    store4(Crow + cn0, o0);
    store4(Crow + cn0 + 64, o1);
  }
}

// ---------------- attention logits ----------------

__global__ __launch_bounds__(256) void al1_kernel(const unsigned short* __restrict__ hx,
                                                  const float* __restrict__ att_src,
                                                  const float* __restrict__ att_dst,
                                                  float* __restrict__ al_s, float* __restrict__ al_d) {
  int n = blockIdx.x;
  int h = threadIdx.x >> 6;
  int lane = threadIdx.x & 63;
  unsigned v = *(const unsigned*)&hx[(size_t)n * 512 + h * 128 + lane * 2];
  float v0 = bf_lo(v), v1 = bf_hi(v);
  float2 as = *(const float2*)&att_src[h * 128 + lane * 2];
  float2 ad = *(const float2*)&att_dst[h * 128 + lane * 2];
  float s = v0 * as.x + v1 * as.y;
  float d = v0 * ad.x + v1 * ad.y;
  for (int off = 32; off; off >>= 1) {
    s += __shfl_down(s, off);
    d += __shfl_down(d, off);
  }
  if (lane == 0) {
    al_s[n * 4 + h] = s;
    al_d[n * 4 + h] = d;
  }
}

__global__ __launch_bounds__(256) void al2_kernel(const float* __restrict__ hx,
                                                  const float* __restrict__ att_src,
                                                  const float* __restrict__ att_dst,
                                                  float* __restrict__ al_s, float* __restrict__ al_d) {
  int n = blockIdx.x * 4 + (threadIdx.x >> 6);
  int lane = threadIdx.x & 63;
  float2 v = *(const float2*)&hx[(size_t)n * 128 + lane * 2];
  float2 as = *(const float2*)&att_src[lane * 2];
  float2 ad = *(const float2*)&att_dst[lane * 2];
  float s = v.x * as.x + v.y * as.y;
  float d = v.x * ad.x + v.y * ad.y;
  for (int off = 32; off; off >>= 1) {
    s += __shfl_down(s, off);
    d += __shfl_down(d, off);
  }
  if (lane == 0) {
    al_s[n] = s;
    al_d[n] = d;
  }
}

// ---------------- GAT aggregation: pure weighted gather ----------------

__global__ __launch_bounds__(256) void agg1_kernel(const unsigned short* __restrict__ hx,
                                                   const float* __restrict__ al_s, const float* __restrict__ al_d,
                                                   const int* __restrict__ rowptr, const int* __restrict__ csr_src,
                                                   const float* __restrict__ w1, const float* __restrict__ b1,
                                                   unsigned short* __restrict__ xout) {
  int n = blockIdx.x;
  int h = threadIdx.x >> 6;
  int c2 = (threadIdx.x & 63) * 2;
  const int col = h * 128 + c2;
  float w0 = expf(lrelu02(al_s[n * 4 + h] + al_d[n * 4 + h]));  // self-loop
  unsigned u = *(const unsigned*)&hx[(size_t)n * 512 + col];
  float acc0 = w0 * bf_lo(u), acc1 = w0 * bf_hi(u);
  float den = w0;
  int p0 = rowptr[n], p1 = rowptr[n + 1];
  for (int p = p0; p < p1; ++p) {
    int s = csr_src[p];
    float w = w1[(size_t)p * 4 + h];
    unsigned uu = *(const unsigned*)&hx[(size_t)s * 512 + col];
    acc0 += w * bf_lo(uu);
    acc1 += w * bf_hi(uu);
    den += w;
  }
  float inv = 1.f / (den + 1e-16f);
  float v0 = acc0 * inv + b1[col];
  float v1 = acc1 * inv + b1[col + 1];
  v0 = v0 > 0.f ? v0 : expm1f(v0);  // fused ELU
  v1 = v1 > 0.f ? v1 : expm1f(v1);
  ushort2 o; o.x = f2b(v0); o.y = f2b(v1);
  *(ushort2*)&xout[(size_t)n * 512 + col] = o;
}

__global__ __launch_bounds__(256) void agg2_kernel(const float* __restrict__ hx,
                                                   const float* __restrict__ al_s, const float* __restrict__ al_d,
                                                   const int* __restrict__ rowptr, const int* __restrict__ csr_src,
                                                   const float* __restrict__ w2, const float* __restrict__ b2,
                                                   float* __restrict__ out) {
  int n = blockIdx.x * 4 + (threadIdx.x >> 6);
  int c2 = (threadIdx.x & 63) * 2;
  float w0 = expf(lrelu02(al_s[n] + al_d[n]));
  float2 v = *(const float2*)&hx[(size_t)n * 128 + c2];
  float acc0 = w0 * v.x, acc1 = w0 * v.y;
  float den = w0;
  int p0 = rowptr[n], p1 = rowptr[n + 1];
  for (int p = p0; p < p1; ++p) {
    int s = csr_src[p];
    float w = w2[p];
    float2 vv = *(const float2*)&hx[(size_t)s * 128 + c2];
    acc0 += w * vv.x;
    acc1 += w * vv.y;
    den += w;
  }
  float inv = 1.f / (den + 1e-16f);
  float2 o;
  o.x = acc0 * inv + b2[c2];
  o.y = acc1 * inv + b2[c2 + 1];
  *(float2*)&out[(size_t)n * 128 + c2] = o;
}

// ---------------- mean-pool + classifier MLP ----------------

__global__ __launch_bounds__(128) void poolcls_kernel(const float* __restrict__ x, const float* __restrict__ Wc1,
                                                      const float* __restrict__ bc1, const float* __restrict__ Wc2,
                                                      const float* __restrict__ bc2, float* __restrict__ out) {
  __shared__ float g[128];
  __shared__ float hcls[64];
  int b = blockIdx.x;
  int t = threadIdx.x;
  const float* base = x + (size_t)b * FPG * 128;
  float s = 0.f;
#pragma unroll
  for (int i = 0; i < FPG; ++i) s += base[i * 128 + t];
  g[t] = s * (1.0f / FPG);
  __syncthreads();
  if (t < 64) {
    float a = bc1[t];
#pragma unroll 4
    for (int k = 0; k < 128; ++k) a += g[k] * Wc1[k * 64 + t];
    hcls[t] = a > 0.f ? a : 0.01f * a;
  }
  __syncthreads();
  if (t < 10) {
    float a = bc2[t];
#pragma unroll
    for (int k = 0; k < 64; ++k) a += hcls[k] * Wc2[k * 10 + t];
    out[b * 10 + t] = a;
  }
}

}  // namespace

extern "C" void kernel_launch(void* const* d_in, const int* in_sizes, int n_in,
                              void* d_out, int out_size, void* d_ws, size_t ws_size,
                              hipStream_t stream) {
  const float* emb = (const float*)d_in[0];
  const int* edge = (const int*)d_in[1];
  // d_in[2] = batch = arange(N)//FPG -> exploited structurally in poolcls
  const float* W_align = (const float*)d_in[3];
  const float* b_align = (const float*)d_in[4];
  const float* W1 = (const float*)d_in[5];
  const float* att_src1 = (const float*)d_in[6];
  const float* att_dst1 = (const float*)d_in[7];
  const float* b1 = (const float*)d_in[8];
  const float* W2 = (const float*)d_in[9];
  const float* att_src2 = (const float*)d_in[10];
  const float* att_dst2 = (const float*)d_in[11];
  const float* b2 = (const float*)d_in[12];
  const float* Wc1 = (const float*)d_in[13];
  const float* bc1 = (const float*)d_in[14];
  const float* Wc2 = (const float*)d_in[15];
  const float* bc2 = (const float*)d_in[16];

  // workspace bump allocator (256B aligned). Peak ~163 MB.
  char* ws = (char*)d_ws;
  size_t off = 0;
  auto alloc = [&](size_t bytes) -> char* {
    char* p = ws + off;
    off += (bytes + 255) & ~(size_t)255;
    return p;
  };
  unsigned short* x0 = (unsigned short*)alloc((size_t)NNODE * 128 * 2);  // aligned x, bf16
  char* big = alloc((size_t)NNODE * 512 * 2);                            // 67.1 MB region
  unsigned short* x1 = (unsigned short*)alloc((size_t)NNODE * 512 * 2);  // ELU(GAT1), bf16
  float* al_s1 = (float*)alloc((size_t)NNODE * 4 * 4);
  float* al_d1 = (float*)alloc((size_t)NNODE * 4 * 4);
  float* al_s2 = (float*)alloc((size_t)NNODE * 4);
  float* al_d2 = (float*)alloc((size_t)NNODE * 4);
  int* deg = (int*)alloc((size_t)NNODE * 4);
  int* rowptr = (int*)alloc((size_t)(NNODE + 1) * 4);
  int* cursor = (int*)alloc((size_t)NNODE * 4);
  int* csr_src = (int*)alloc((size_t)NEDGE * 4);
  int* csr_dst = (int*)alloc((size_t)NEDGE * 4);
  float* w1 = (float*)alloc((size_t)NEDGE * 4 * 4);
  float* w2 = (float*)alloc((size_t)NEDGE * 4);
  unsigned short* w1t = (unsigned short*)alloc((size_t)512 * 128 * 2);  // W1^T bf16 [512][128]
  unsigned short* w2t = (unsigned short*)alloc((size_t)128 * 512 * 2);  // W2^T bf16 [128][512]

  // region aliasing: hx1 (bf16 [N,512]) lives in `big` until agg1 completes;
  // afterwards hx2 (f32 [N,128]) and out2 (f32 [N,128]) share the same region.
  unsigned short* hx1 = (unsigned short*)big;
  float* hx2 = (float*)big;
  float* out2 = (float*)(big + (size_t)NNODE * 128 * 4);

  const int* src = edge;
  const int* dst = edge + NEDGE;

  // CSR by dst (shared by both GAT layers) + weight conversion
  hipMemsetAsync(deg, 0, (size_t)NNODE * 4, stream);
  hist_kernel<<<NEDGE / 256, 256, 0, stream>>>(dst, deg);
  scan_kernel<<<1, 1024, 0, stream>>>(deg, rowptr, cursor);
  scatter_kernel<<<NEDGE / 256, 256, 0, stream>>>(src, dst, cursor, csr_src, csr_dst);
  convw_kernel<<<256, 256, 0, stream>>>(W1, w1t, 128, 512);
  convw_kernel<<<256, 256, 0, stream>>>(W2, w2t, 512, 128);

  // aligner: x0 = emb @ W_align + b_align   [65536,64]@[64,128] -> bf16
  gemm_align_kernel<<<dim3(NNODE / 128, 1), 256, 0, stream>>>(emb, W_align, x0, b_align, 128, 64);
  // GAT1 transform: hx1 = x0 @ W1           [65536,128]@[128,512] -> bf16 (MFMA)
  gemm_mfma_kernel<128, unsigned short><<<dim3(512, 4), 256, 0, stream>>>(x0, w1t, hx1, 512);
  al1_kernel<<<NNODE, 256, 0, stream>>>(hx1, att_src1, att_dst1, al_s1, al_d1);
  edgew1_kernel<<<NEDGE / 256, 256, 0, stream>>>(csr_src, csr_dst, al_s1, al_d1, w1);
  agg1_kernel<<<NNODE, 256, 0, stream>>>(hx1, al_s1, al_d1, rowptr, csr_src, w1, b1, x1);
  // GAT2 transform: hx2 = x1 @ W2           [65536,512]@[512,128] -> f32 (MFMA, aliases dead hx1)
  gemm_mfma_kernel<512, float><<<dim3(512, 1), 256, 0, stream>>>(x1, w2t, hx2, 128);
  al2_kernel<<<NNODE / 4, 256, 0, stream>>>(hx2, att_src2, att_dst2, al_s2, al_d2);
  edgew2_kernel<<<NEDGE / 256, 256, 0, stream>>>(csr_src, csr_dst, al_s2, al_d2, w2);
  agg2_kernel<<<NNODE / 4, 256, 0, stream>>>(hx2, al_s2, al_d2, rowptr, csr_src, w2, b2, out2);
  // pool + classifier
  poolcls_kernel<<<NGRAPH, 128, 0, stream>>>(out2, Wc1, bc1, Wc2, bc2, (float*)d_out);
}

// Round 5
// 381.682 us; speedup vs baseline: 1.5390x; 1.0442x over previous
//
#include <hip/hip_runtime.h>

// ProtocolTreeGAttention: aligner Linear -> GAT(128->128,H=4,concat) -> ELU ->
// GAT(512->128,H=1) -> mean-pool -> MLP classifier.
// Round 5: MFMA GEMM epilogue staged through LDS for full-cacheline stores
// (round 4 was store-bound: 2.9x write amplification); hx2 stored bf16;
// 4-deep ILP batching in the aggregation gathers.

namespace {

constexpr int NNODE = 65536;   // B*F
constexpr int NEDGE = 262144;
constexpr int NGRAPH = 2048;
constexpr int FPG = 32;

typedef __attribute__((ext_vector_type(8))) short bf16x8;
typedef __attribute__((ext_vector_type(4))) float f32x4;

__device__ __forceinline__ float lrelu02(float x) { return x > 0.f ? x : 0.2f * x; }
__device__ __forceinline__ float bf_lo(unsigned u) { return __uint_as_float(u << 16); }
__device__ __forceinline__ float bf_hi(unsigned u) { return __uint_as_float(u & 0xffff0000u); }
__device__ __forceinline__ unsigned short f2b(float f) {  // RNE bf16 round
  unsigned u = __float_as_uint(f);
  return (unsigned short)((u + 0x7fffu + ((u >> 16) & 1u)) >> 16);
}

__device__ __forceinline__ void load8(const float* p, float o[8]) {
  float4 a = *(const float4*)p;
  float4 b = *(const float4*)(p + 4);
  o[0] = a.x; o[1] = a.y; o[2] = a.z; o[3] = a.w;
  o[4] = b.x; o[5] = b.y; o[6] = b.z; o[7] = b.w;
}
__device__ __forceinline__ void store4(unsigned short* p, const float v[4]) {
  ushort4 o; o.x = f2b(v[0]); o.y = f2b(v[1]); o.z = f2b(v[2]); o.w = f2b(v[3]);
  *(ushort4*)p = o;
}

// ---------------- CSR build ----------------

__global__ __launch_bounds__(256) void hist_kernel(const int* __restrict__ dst, int* __restrict__ deg) {
  int e = blockIdx.x * 256 + threadIdx.x;
  if (e < NEDGE) atomicAdd(&deg[dst[e]], 1);
}

__global__ __launch_bounds__(1024) void scan_kernel(const int* __restrict__ deg, int* __restrict__ rowptr,
                                                    int* __restrict__ cursor) {
  __shared__ int sums[1024];
  int t = threadIdx.x;
  int base = t * 64;
  int s = 0;
  for (int i = 0; i < 64; ++i) s += deg[base + i];
  sums[t] = s;
  __syncthreads();
  for (int off = 1; off < 1024; off <<= 1) {
    int v = (t >= off) ? sums[t - off] : 0;
    __syncthreads();
    sums[t] += v;
    __syncthreads();
  }
  int run = (t == 0) ? 0 : sums[t - 1];
  for (int i = 0; i < 64; ++i) {
    rowptr[base + i] = run;
    cursor[base + i] = run;
    run += deg[base + i];
  }
  if (t == 1023) rowptr[NNODE] = run;
}

__global__ __launch_bounds__(256) void scatter_kernel(const int* __restrict__ src, const int* __restrict__ dst,
                                                      int* __restrict__ cursor, int* __restrict__ csr_src,
                                                      int* __restrict__ csr_dst) {
  int e = blockIdx.x * 256 + threadIdx.x;
  if (e < NEDGE) {
    int s = src[e], d = dst[e];
    int p = atomicAdd(&cursor[d], 1);
    csr_src[p] = s;
    csr_dst[p] = d;
  }
}

// ---------------- weight convert: Wt[n][k] = bf16(W[k][n]) ----------------

__global__ __launch_bounds__(256) void convw_kernel(const float* __restrict__ W, unsigned short* __restrict__ Wt,
                                                    int K, int N) {
  int idx = blockIdx.x * 256 + threadIdx.x;
  if (idx >= K * N) return;
  int n = idx / K, k = idx - n * K;
  Wt[idx] = f2b(W[(size_t)k * N + n]);
}

// ---------------- per-edge attention weights (CSR order) ----------------

__global__ __launch_bounds__(256) void edgew1_kernel(const int* __restrict__ csr_src, const int* __restrict__ csr_dst,
                                                     const float* __restrict__ al_s, const float* __restrict__ al_d,
                                                     float* __restrict__ w1) {
  int p = blockIdx.x * 256 + threadIdx.x;
  if (p >= NEDGE) return;
  int s = csr_src[p], d = csr_dst[p];
  float4 as = *(const float4*)&al_s[s * 4];
  float4 ad = *(const float4*)&al_d[d * 4];
  float4 w;
  w.x = expf(lrelu02(as.x + ad.x));
  w.y = expf(lrelu02(as.y + ad.y));
  w.z = expf(lrelu02(as.z + ad.z));
  w.w = expf(lrelu02(as.w + ad.w));
  *(float4*)&w1[(size_t)p * 4] = w;
}

__global__ __launch_bounds__(256) void edgew2_kernel(const int* __restrict__ csr_src, const int* __restrict__ csr_dst,
                                                     const float* __restrict__ al_s, const float* __restrict__ al_d,
                                                     float* __restrict__ w2) {
  int p = blockIdx.x * 256 + threadIdx.x;
  if (p >= NEDGE) return;
  w2[p] = expf(lrelu02(al_s[csr_src[p]] + al_d[csr_dst[p]]));
}

// ---------------- MFMA GEMM: C[M x Nc] = A[M x K] @ Wt[Nc x K]^T -> bf16 ----------------
// BM=BN=128, BK=64, 256 threads = 4 waves (2x2), each wave 64x64 out (4x4 frags).
// LDS tiles [128 rows][64 bf16] with byte-XOR swizzle ((row&7)<<4) on 16B chunks.
// Epilogue: acc -> bf16 LDS tile [128][136] -> full-cacheline uint4 global stores.

__device__ __forceinline__ bf16x8 frag_ld(const unsigned short* lds, int row, int kbyte) {
  const char* base = (const char*)lds + row * 128;
  int sw = (row & 7) << 4;
  uint2 lo = *(const uint2*)(base + (kbyte ^ sw));
  uint2 hi = *(const uint2*)(base + ((kbyte + 32) ^ sw));
  union { bf16x8 v; uint2 u2[2]; } f;
  f.u2[0] = lo;
  f.u2[1] = hi;
  return f.v;
}

template <int K>
__global__ __launch_bounds__(256) void gemm_mfma_kernel(const unsigned short* __restrict__ A,
                                                        const unsigned short* __restrict__ Bt,
                                                        unsigned short* __restrict__ C, int Nc) {
  __shared__ char smem[128 * 136 * 2];  // 34816 B: holds As+Bs (32 KB) then C-stage
  unsigned short* As = (unsigned short*)smem;
  unsigned short* Bs = As + 8192;
  unsigned short* Cs = (unsigned short*)smem;  // [128][136]

  const int tid = threadIdx.x;
  const int lane = tid & 63;
  const int wave = tid >> 6;
  const int wm = wave >> 1, wn = wave & 1;
  const size_t bm = (size_t)blockIdx.x * 128;
  const int bn = blockIdx.y * 128;

  // staging: thread covers rows {srow, srow+32, srow+64, srow+96}, 16B each
  const int srow = tid >> 3;
  const int scolb = (tid & 7) << 4;
  const int sdst = srow * 64 + ((scolb ^ ((srow & 7) << 4)) >> 1);  // ushort index
  const char* Ag = (const char*)(A + (bm + srow) * K) + scolb;
  const char* Bg = (const char*)(Bt + (size_t)(bn + srow) * K) + scolb;

  f32x4 zero = {0.f, 0.f, 0.f, 0.f};
  f32x4 acc[4][4];
#pragma unroll
  for (int i = 0; i < 4; ++i)
#pragma unroll
    for (int j = 0; j < 4; ++j) acc[i][j] = zero;

  const int ln = lane & 15, lg = lane >> 4;
  const int fr_a = wm * 64 + ln;     // + mt*16
  const int fr_b = wn * 64 + ln;     // + nt*16
  const int kb0 = lg << 3;           // 0,8,16,24 bytes

  for (int kt = 0; kt < K; kt += 64) {
    uint4 av[4], bv[4];
#pragma unroll
    for (int i = 0; i < 4; ++i) {
      av[i] = *(const uint4*)(Ag + (size_t)32 * i * K * 2);
      bv[i] = *(const uint4*)(Bg + (size_t)32 * i * K * 2);
    }
    Ag += 128;  // +64 bf16 in k
    Bg += 128;
    if (kt) __syncthreads();  // previous tile fully consumed before overwrite
#pragma unroll
    for (int i = 0; i < 4; ++i) {
      *(uint4*)(As + sdst + 2048 * i) = av[i];
      *(uint4*)(Bs + sdst + 2048 * i) = bv[i];
    }
    __syncthreads();
#pragma unroll
    for (int kk = 0; kk < 2; ++kk) {
      bf16x8 af[4], bfr[4];
#pragma unroll
      for (int mt = 0; mt < 4; ++mt) af[mt] = frag_ld(As, fr_a + mt * 16, kk * 64 + kb0);
#pragma unroll
      for (int nt = 0; nt < 4; ++nt) bfr[nt] = frag_ld(Bs, fr_b + nt * 16, kk * 64 + kb0);
#pragma unroll
      for (int mt = 0; mt < 4; ++mt)
#pragma unroll
        for (int nt = 0; nt < 4; ++nt)
          acc[mt][nt] = __builtin_amdgcn_mfma_f32_16x16x32_bf16(af[mt], bfr[nt], acc[mt][nt], 0, 0, 0);
    }
  }

  // ---- epilogue: stage bf16 tile in LDS, then coalesced 128B-per-thread stores ----
  __syncthreads();  // all frag reads done; smem becomes C-stage
#pragma unroll
  for (int mt = 0; mt < 4; ++mt) {
#pragma unroll
    for (int r = 0; r < 4; ++r) {
      unsigned short* rp = Cs + (wm * 64 + mt * 16 + lg * 4 + r) * 136 + wn * 64 + ln;
#pragma unroll
      for (int nt = 0; nt < 4; ++nt) rp[nt * 16] = f2b(acc[mt][nt][r]);
    }
  }
  __syncthreads();
  const int row_l = tid >> 1;
  const int colh = (tid & 1) << 6;  // 0 or 64 ushorts
  const unsigned short* sp = Cs + row_l * 136 + colh;
  unsigned short* dp = C + (bm + row_l) * Nc + bn + colh;
#pragma unroll
  for (int i = 0; i < 8; ++i) *(uint4*)(dp + i * 8) = *(const uint4*)(sp + i * 8);
}

// ---------------- vector GEMM (aligner only): C = A[M x K] @ B[K x Nc] + bias ----------------

__global__ __launch_bounds__(256) void gemm_align_kernel(const float* __restrict__ A, const float* __restrict__ B,
                                                         unsigned short* __restrict__ C, const float* __restrict__ bias,
                                                         int Nc, int K) {
  __shared__ float Asm[16][132];
  __shared__ float Bsm[16][132];
  const int tid = threadIdx.x;
  const int tx = tid & 15, ty = tid >> 4;
  const int bm = blockIdx.x, bn = blockIdx.y;
  const int m_l = tid >> 1;
  const int kh = (tid & 1) * 8;
  const int kb = tid >> 4;
  const int nq = (tid & 15) * 8;
  const float* Ap = A + (size_t)(bm * 128 + m_l) * K + kh;
  const float* Bp = B + (size_t)kb * Nc + bn * 128 + nq;

  float acc[8][8];
#pragma unroll
  for (int i = 0; i < 8; ++i)
#pragma unroll
    for (int j = 0; j < 8; ++j) acc[i][j] = 0.f;

  const int ksteps = K / 16;
  for (int t = 0; t < ksteps; ++t) {
    float av8[8], bv8[8];
    load8(Ap + t * 16, av8);
    load8(Bp + (size_t)t * 16 * Nc, bv8);
    __syncthreads();
#pragma unroll
    for (int q = 0; q < 8; ++q) Asm[kh + q][m_l] = av8[q];
    *(float4*)&Bsm[kb][nq] = *(float4*)&bv8[0];
    *(float4*)&Bsm[kb][nq + 4] = *(float4*)&bv8[4];
    __syncthreads();
#pragma unroll
    for (int kk = 0; kk < 16; ++kk) {
      float4 av0 = *(const float4*)&Asm[kk][ty * 4];
      float4 av1 = *(const float4*)&Asm[kk][64 + ty * 4];
      float4 bv0 = *(const float4*)&Bsm[kk][tx * 4];
      float4 bv1 = *(const float4*)&Bsm[kk][64 + tx * 4];
      float av[8] = {av0.x, av0.y, av0.z, av0.w, av1.x, av1.y, av1.z, av1.w};
      float bv[8] = {bv0.x, bv0.y, bv0.z, bv0.w, bv1.x, bv1.y, bv1.z, bv1.w};
#pragma unroll
      for (int i = 0; i < 8; ++i)
#pragma unroll
        for (int j = 0; j < 8; ++j) acc[i][j] += av[i] * bv[j];
    }
  }

  const int cn0 = bn * 128 + tx * 4;
#pragma unroll
  for (int i = 0; i < 8; ++i) {
    int r = bm * 128 + ((i < 4) ? (ty * 4 + i) : (64 + ty * 4 + i - 4));
    unsigned short* Crow = C + (size_t)r * Nc;
    float o0[4] = {acc[i][0], acc[i][1], acc[i][2], acc[i][3]};
    float o1[4] = {acc[i][4], acc[i][5], acc[i][6], acc[i][7]};
#pragma unroll
    for (int j = 0; j < 4; ++j) {
      o0[j] += bias[cn0 + j];
      o1[j] += bias[cn0 + 64 + j];
    }
    store4(Crow + cn0, o0);
    store4(Crow + cn0 + 64, o1);
  }
}

// ---------------- attention logits ----------------

__global__ __launch_bounds__(256) void al1_kernel(const unsigned short* __restrict__ hx,
                                                  const float* __restrict__ att_src,
                                                  const float* __restrict__ att_dst,
                                                  float* __restrict__ al_s, float* __restrict__ al_d) {
  int n = blockIdx.x;
  int h = threadIdx.x >> 6;
  int lane = threadIdx.x & 63;
  unsigned v = *(const unsigned*)&hx[(size_t)n * 512 + h * 128 + lane * 2];
  float v0 = bf_lo(v), v1 = bf_hi(v);
  float2 as = *(const float2*)&att_src[h * 128 + lane * 2];
  float2 ad = *(const float2*)&att_dst[h * 128 + lane * 2];
  float s = v0 * as.x + v1 * as.y;
  float d = v0 * ad.x + v1 * ad.y;
  for (int off = 32; off; off >>= 1) {
    s += __shfl_down(s, off);
    d += __shfl_down(d, off);
  }
  if (lane == 0) {
    al_s[n * 4 + h] = s;
    al_d[n * 4 + h] = d;
  }
}

__global__ __launch_bounds__(256) void al2_kernel(const unsigned short* __restrict__ hx,
                                                  const float* __restrict__ att_src,
                                                  const float* __restrict__ att_dst,
                                                  float* __restrict__ al_s, float* __restrict__ al_d) {
  int n = blockIdx.x * 4 + (threadIdx.x >> 6);
  int lane = threadIdx.x & 63;
  unsigned v = *(const unsigned*)&hx[(size_t)n * 128 + lane * 2];
  float v0 = bf_lo(v), v1 = bf_hi(v);
  float2 as = *(const float2*)&att_src[lane * 2];
  float2 ad = *(const float2*)&att_dst[lane * 2];
  float s = v0 * as.x + v1 * as.y;
  float d = v0 * ad.x + v1 * ad.y;
  for (int off = 32; off; off >>= 1) {
    s += __shfl_down(s, off);
    d += __shfl_down(d, off);
  }
  if (lane == 0) {
    al_s[n] = s;
    al_d[n] = d;
  }
}

// ---------------- GAT aggregation: weighted gather, 4-deep ILP ----------------

__global__ __launch_bounds__(256) void agg1_kernel(const unsigned short* __restrict__ hx,
                                                   const float* __restrict__ al_s, const float* __restrict__ al_d,
                                                   const int* __restrict__ rowptr, const int* __restrict__ csr_src,
                                                   const float* __restrict__ w1, const float* __restrict__ b1,
                                                   unsigned short* __restrict__ xout) {
  int n = blockIdx.x;
  int h = threadIdx.x >> 6;
  int c2 = (threadIdx.x & 63) * 2;
  const int col = h * 128 + c2;
  float w0 = expf(lrelu02(al_s[n * 4 + h] + al_d[n * 4 + h]));  // self-loop
  unsigned u = *(const unsigned*)&hx[(size_t)n * 512 + col];
  float acc0 = w0 * bf_lo(u), acc1 = w0 * bf_hi(u);
  float den = w0;
  int p0 = rowptr[n], p1 = rowptr[n + 1];
  int p = p0;
  for (; p + 4 <= p1; p += 4) {
    int s0 = csr_src[p], s1 = csr_src[p + 1], s2 = csr_src[p + 2], s3 = csr_src[p + 3];
    float wa = w1[(size_t)p * 4 + h];
    float wb = w1[(size_t)(p + 1) * 4 + h];
    float wc = w1[(size_t)(p + 2) * 4 + h];
    float wd = w1[(size_t)(p + 3) * 4 + h];
    unsigned u0 = *(const unsigned*)&hx[(size_t)s0 * 512 + col];
    unsigned u1 = *(const unsigned*)&hx[(size_t)s1 * 512 + col];
    unsigned u2 = *(const unsigned*)&hx[(size_t)s2 * 512 + col];
    unsigned u3 = *(const unsigned*)&hx[(size_t)s3 * 512 + col];
    acc0 += wa * bf_lo(u0) + wb * bf_lo(u1) + wc * bf_lo(u2) + wd * bf_lo(u3);
    acc1 += wa * bf_hi(u0) + wb * bf_hi(u1) + wc * bf_hi(u2) + wd * bf_hi(u3);
    den += wa + wb + wc + wd;
  }
  for (; p < p1; ++p) {
    int s = csr_src[p];
    float w = w1[(size_t)p * 4 + h];
    unsigned uu = *(const unsigned*)&hx[(size_t)s * 512 + col];
    acc0 += w * bf_lo(uu);
    acc1 += w * bf_hi(uu);
    den += w;
  }
  float inv = 1.f / (den + 1e-16f);
  float v0 = acc0 * inv + b1[col];
  float v1 = acc1 * inv + b1[col + 1];
  v0 = v0 > 0.f ? v0 : expm1f(v0);  // fused ELU
  v1 = v1 > 0.f ? v1 : expm1f(v1);
  ushort2 o; o.x = f2b(v0); o.y = f2b(v1);
  *(ushort2*)&xout[(size_t)n * 512 + col] = o;
}

__global__ __launch_bounds__(256) void agg2_kernel(const unsigned short* __restrict__ hx,
                                                   const float* __restrict__ al_s, const float* __restrict__ al_d,
                                                   const int* __restrict__ rowptr, const int* __restrict__ csr_src,
                                                   const float* __restrict__ w2, const float* __restrict__ b2,
                                                   float* __restrict__ out) {
  int n = blockIdx.x * 4 + (threadIdx.x >> 6);
  int c2 = (threadIdx.x & 63) * 2;
  float w0 = expf(lrelu02(al_s[n] + al_d[n]));
  unsigned u = *(const unsigned*)&hx[(size_t)n * 128 + c2];
  float acc0 = w0 * bf_lo(u), acc1 = w0 * bf_hi(u);
  float den = w0;
  int p0 = rowptr[n], p1 = rowptr[n + 1];
  int p = p0;
  for (; p + 4 <= p1; p += 4) {
    int s0 = csr_src[p], s1 = csr_src[p + 1], s2 = csr_src[p + 2], s3 = csr_src[p + 3];
    float wa = w2[p], wb = w2[p + 1], wc = w2[p + 2], wd = w2[p + 3];
    unsigned u0 = *(const unsigned*)&hx[(size_t)s0 * 128 + c2];
    unsigned u1 = *(const unsigned*)&hx[(size_t)s1 * 128 + c2];
    unsigned u2 = *(const unsigned*)&hx[(size_t)s2 * 128 + c2];
    unsigned u3 = *(const unsigned*)&hx[(size_t)s3 * 128 + c2];
    acc0 += wa * bf_lo(u0) + wb * bf_lo(u1) + wc * bf_lo(u2) + wd * bf_lo(u3);
    acc1 += wa * bf_hi(u0) + wb * bf_hi(u1) + wc * bf_hi(u2) + wd * bf_hi(u3);
    den += wa + wb + wc + wd;
  }
  for (; p < p1; ++p) {
    int s = csr_src[p];
    float w = w2[p];
    unsigned uu = *(const unsigned*)&hx[(size_t)s * 128 + c2];
    acc0 += w * bf_lo(uu);
    acc1 += w * bf_hi(uu);
    den += w;
  }
  float inv = 1.f / (den + 1e-16f);
  float2 o;
  o.x = acc0 * inv + b2[c2];
  o.y = acc1 * inv + b2[c2 + 1];
  *(float2*)&out[(size_t)n * 128 + c2] = o;
}

// ---------------- mean-pool + classifier MLP ----------------

__global__ __launch_bounds__(128) void poolcls_kernel(const float* __restrict__ x, const float* __restrict__ Wc1,
                                                      const float* __restrict__ bc1, const float* __restrict__ Wc2,
                                                      const float* __restrict__ bc2, float* __restrict__ out) {
  __shared__ float g[128];
  __shared__ float hcls[64];
  int b = blockIdx.x;
  int t = threadIdx.x;
  const float* base = x + (size_t)b * FPG * 128;
  float s = 0.f;
#pragma unroll
  for (int i = 0; i < FPG; ++i) s += base[i * 128 + t];
  g[t] = s * (1.0f / FPG);
  __syncthreads();
  if (t < 64) {
    float a = bc1[t];
#pragma unroll 4
    for (int k = 0; k < 128; ++k) a += g[k] * Wc1[k * 64 + t];
    hcls[t] = a > 0.f ? a : 0.01f * a;
  }
  __syncthreads();
  if (t < 10) {
    float a = bc2[t];
#pragma unroll
    for (int k = 0; k < 64; ++k) a += hcls[k] * Wc2[k * 10 + t];
    out[b * 10 + t] = a;
  }
}

}  // namespace

extern "C" void kernel_launch(void* const* d_in, const int* in_sizes, int n_in,
                              void* d_out, int out_size, void* d_ws, size_t ws_size,
                              hipStream_t stream) {
  const float* emb = (const float*)d_in[0];
  const int* edge = (const int*)d_in[1];
  // d_in[2] = batch = arange(N)//FPG -> exploited structurally in poolcls
  const float* W_align = (const float*)d_in[3];
  const float* b_align = (const float*)d_in[4];
  const float* W1 = (const float*)d_in[5];
  const float* att_src1 = (const float*)d_in[6];
  const float* att_dst1 = (const float*)d_in[7];
  const float* b1 = (const float*)d_in[8];
  const float* W2 = (const float*)d_in[9];
  const float* att_src2 = (const float*)d_in[10];
  const float* att_dst2 = (const float*)d_in[11];
  const float* b2 = (const float*)d_in[12];
  const float* Wc1 = (const float*)d_in[13];
  const float* bc1 = (const float*)d_in[14];
  const float* Wc2 = (const float*)d_in[15];
  const float* bc2 = (const float*)d_in[16];

  // workspace bump allocator (256B aligned). Peak ~163 MB.
  char* ws = (char*)d_ws;
  size_t off = 0;
  auto alloc = [&](size_t bytes) -> char* {
    char* p = ws + off;
    off += (bytes + 255) & ~(size_t)255;
    return p;
  };
  unsigned short* x0 = (unsigned short*)alloc((size_t)NNODE * 128 * 2);  // aligned x, bf16
  char* big = alloc((size_t)NNODE * 512 * 2);                            // 67.1 MB region
  unsigned short* x1 = (unsigned short*)alloc((size_t)NNODE * 512 * 2);  // ELU(GAT1), bf16
  float* al_s1 = (float*)alloc((size_t)NNODE * 4 * 4);
  float* al_d1 = (float*)alloc((size_t)NNODE * 4 * 4);
  float* al_s2 = (float*)alloc((size_t)NNODE * 4);
  float* al_d2 = (float*)alloc((size_t)NNODE * 4);
  int* deg = (int*)alloc((size_t)NNODE * 4);
  int* rowptr = (int*)alloc((size_t)(NNODE + 1) * 4);
  int* cursor = (int*)alloc((size_t)NNODE * 4);
  int* csr_src = (int*)alloc((size_t)NEDGE * 4);
  int* csr_dst = (int*)alloc((size_t)NEDGE * 4);
  float* w1 = (float*)alloc((size_t)NEDGE * 4 * 4);
  float* w2 = (float*)alloc((size_t)NEDGE * 4);
  unsigned short* w1t = (unsigned short*)alloc((size_t)512 * 128 * 2);  // W1^T bf16 [512][128]
  unsigned short* w2t = (unsigned short*)alloc((size_t)128 * 512 * 2);  // W2^T bf16 [128][512]

  // region aliasing: hx1 (bf16 [N,512]) lives in `big` until agg1 completes;
  // afterwards hx2 (bf16 [N,128]) and out2 (f32 [N,128]) share the same region.
  unsigned short* hx1 = (unsigned short*)big;
  unsigned short* hx2 = (unsigned short*)big;
  float* out2 = (float*)(big + (size_t)NNODE * 128 * 4);

  const int* src = edge;
  const int* dst = edge + NEDGE;

  // CSR by dst (shared by both GAT layers) + weight conversion
  hipMemsetAsync(deg, 0, (size_t)NNODE * 4, stream);
  hist_kernel<<<NEDGE / 256, 256, 0, stream>>>(dst, deg);
  scan_kernel<<<1, 1024, 0, stream>>>(deg, rowptr, cursor);
  scatter_kernel<<<NEDGE / 256, 256, 0, stream>>>(src, dst, cursor, csr_src, csr_dst);
  convw_kernel<<<256, 256, 0, stream>>>(W1, w1t, 128, 512);
  convw_kernel<<<256, 256, 0, stream>>>(W2, w2t, 512, 128);

  // aligner: x0 = emb @ W_align + b_align   [65536,64]@[64,128] -> bf16
  gemm_align_kernel<<<dim3(NNODE / 128, 1), 256, 0, stream>>>(emb, W_align, x0, b_align, 128, 64);
  // GAT1 transform: hx1 = x0 @ W1           [65536,128]@[128,512] -> bf16 (MFMA)
  gemm_mfma_kernel<128><<<dim3(512, 4), 256, 0, stream>>>(x0, w1t, hx1, 512);
  al1_kernel<<<NNODE, 256, 0, stream>>>(hx1, att_src1, att_dst1, al_s1, al_d1);
  edgew1_kernel<<<NEDGE / 256, 256, 0, stream>>>(csr_src, csr_dst, al_s1, al_d1, w1);
  agg1_kernel<<<NNODE, 256, 0, stream>>>(hx1, al_s1, al_d1, rowptr, csr_src, w1, b1, x1);
  // GAT2 transform: hx2 = x1 @ W2           [65536,512]@[512,128] -> bf16 (MFMA, aliases dead hx1)
  gemm_mfma_kernel<512><<<dim3(512, 1), 256, 0, stream>>>(x1, w2t, hx2, 128);
  al2_kernel<<<NNODE / 4, 256, 0, stream>>>(hx2, att_src2, att_dst2, al_s2, al_d2);
  edgew2_kernel<<<NEDGE / 256, 256, 0, stream>>>(csr_src, csr_dst, al_s2, al_d2, w2);
  agg2_kernel<<<NNODE / 4, 256, 0, stream>>>(hx2, al_s2, al_d2, rowptr, csr_src, w2, b2, out2);
  // pool + classifier
  poolcls_kernel<<<NGRAPH, 128, 0, stream>>>(out2, Wc1, bc1, Wc2, bc2, (float*)d_out);
}

// Round 6
// 358.001 us; speedup vs baseline: 1.6408x; 1.0661x over previous
//
#include <hip/hip_runtime.h>

// ProtocolTreeGAttention: aligner Linear -> GAT(128->128,H=4,concat) -> ELU ->
// GAT(512->128,H=1) -> mean-pool -> MLP classifier.
// Round 6: GAT1 restructured to aggregate-then-transform (attention logits
// computed from x0 via pre-transformed attention vectors; 4-head weighted
// aggregation of 128-dim x0 rows -> block-diagonal MFMA GEMM with fused
// bias+ELU). Gather volume for GAT1 drops 4x and its table is L2/L3-resident.

namespace {

constexpr int NNODE = 65536;   // B*F
constexpr int NEDGE = 262144;
constexpr int NGRAPH = 2048;
constexpr int FPG = 32;

typedef __attribute__((ext_vector_type(8))) short bf16x8;
typedef __attribute__((ext_vector_type(4))) float f32x4;

__device__ __forceinline__ float lrelu02(float x) { return x > 0.f ? x : 0.2f * x; }
__device__ __forceinline__ float bf_lo(unsigned u) { return __uint_as_float(u << 16); }
__device__ __forceinline__ float bf_hi(unsigned u) { return __uint_as_float(u & 0xffff0000u); }
__device__ __forceinline__ unsigned short f2b(float f) {  // RNE bf16 round
  unsigned u = __float_as_uint(f);
  return (unsigned short)((u + 0x7fffu + ((u >> 16) & 1u)) >> 16);
}

__device__ __forceinline__ void load8(const float* p, float o[8]) {
  float4 a = *(const float4*)p;
  float4 b = *(const float4*)(p + 4);
  o[0] = a.x; o[1] = a.y; o[2] = a.z; o[3] = a.w;
  o[4] = b.x; o[5] = b.y; o[6] = b.z; o[7] = b.w;
}
__device__ __forceinline__ void store4(unsigned short* p, const float v[4]) {
  ushort4 o; o.x = f2b(v[0]); o.y = f2b(v[1]); o.z = f2b(v[2]); o.w = f2b(v[3]);
  *(ushort4*)p = o;
}

// ---------------- CSR build ----------------

__global__ __launch_bounds__(256) void hist_kernel(const int* __restrict__ dst, int* __restrict__ deg) {
  int e = blockIdx.x * 256 + threadIdx.x;
  if (e < NEDGE) atomicAdd(&deg[dst[e]], 1);
}

__global__ __launch_bounds__(1024) void scan_kernel(const int* __restrict__ deg, int* __restrict__ rowptr,
                                                    int* __restrict__ cursor) {
  __shared__ int sums[1024];
  int t = threadIdx.x;
  int base = t * 64;
  int s = 0;
  for (int i = 0; i < 64; ++i) s += deg[base + i];
  sums[t] = s;
  __syncthreads();
  for (int off = 1; off < 1024; off <<= 1) {
    int v = (t >= off) ? sums[t - off] : 0;
    __syncthreads();
    sums[t] += v;
    __syncthreads();
  }
  int run = (t == 0) ? 0 : sums[t - 1];
  for (int i = 0; i < 64; ++i) {
    rowptr[base + i] = run;
    cursor[base + i] = run;
    run += deg[base + i];
  }
  if (t == 1023) rowptr[NNODE] = run;
}

__global__ __launch_bounds__(256) void scatter_kernel(const int* __restrict__ src, const int* __restrict__ dst,
                                                      int* __restrict__ cursor, int* __restrict__ csr_src,
                                                      int* __restrict__ csr_dst) {
  int e = blockIdx.x * 256 + threadIdx.x;
  if (e < NEDGE) {
    int s = src[e], d = dst[e];
    int p = atomicAdd(&cursor[d], 1);
    csr_src[p] = s;
    csr_dst[p] = d;
  }
}

// ---------------- weight convert: Wt[n][k] = bf16(W[k][n]) ----------------

__global__ __launch_bounds__(256) void convw_kernel(const float* __restrict__ W, unsigned short* __restrict__ Wt,
                                                    int K, int N) {
  int idx = blockIdx.x * 256 + threadIdx.x;
  if (idx >= K * N) return;
  int n = idx / K, k = idx - n * K;
  Wt[idx] = f2b(W[(size_t)k * N + n]);
}

// ---------------- pre-transformed GAT1 attention vectors ----------------
// vs1[h*128+c] = sum_j W1[c, h*128+j] * att_src1[h,j]  (al_s1[n,h] = x0[n]·vs1[h])

__global__ __launch_bounds__(256) void attv1_kernel(const float* __restrict__ W1, const float* __restrict__ as1,
                                                    const float* __restrict__ ad1, float* __restrict__ vs1,
                                                    float* __restrict__ vd1) {
  int idx = blockIdx.x * 256 + threadIdx.x;  // 0..511
  int h = idx >> 7, c = idx & 127;
  float s = 0.f, d = 0.f;
  const float* wrow = W1 + (size_t)c * 512 + h * 128;
  const float* ar = as1 + h * 128;
  const float* dr = ad1 + h * 128;
  for (int j = 0; j < 128; ++j) {
    float w = wrow[j];
    s += w * ar[j];
    d += w * dr[j];
  }
  vs1[idx] = s;
  vd1[idx] = d;
}

// ---------------- per-edge attention weights (CSR order) ----------------

__global__ __launch_bounds__(256) void edgew1_kernel(const int* __restrict__ csr_src, const int* __restrict__ csr_dst,
                                                     const float* __restrict__ al_s, const float* __restrict__ al_d,
                                                     float* __restrict__ w1) {
  int p = blockIdx.x * 256 + threadIdx.x;
  if (p >= NEDGE) return;
  int s = csr_src[p], d = csr_dst[p];
  float4 as = *(const float4*)&al_s[s * 4];
  float4 ad = *(const float4*)&al_d[d * 4];
  float4 w;
  w.x = expf(lrelu02(as.x + ad.x));
  w.y = expf(lrelu02(as.y + ad.y));
  w.z = expf(lrelu02(as.z + ad.z));
  w.w = expf(lrelu02(as.w + ad.w));
  *(float4*)&w1[(size_t)p * 4] = w;
}

__global__ __launch_bounds__(256) void edgew2_kernel(const int* __restrict__ csr_src, const int* __restrict__ csr_dst,
                                                     const float* __restrict__ al_s, const float* __restrict__ al_d,
                                                     float* __restrict__ w2) {
  int p = blockIdx.x * 256 + threadIdx.x;
  if (p >= NEDGE) return;
  w2[p] = expf(lrelu02(al_s[csr_src[p]] + al_d[csr_dst[p]]));
}

// ---------------- MFMA GEMM: C[M x Nc](bf16) = A[M x K] @ Bt[Nc x K]^T ----------------
// BM=BN=128, BK=64, 256 threads = 4 waves (2x2), each wave 64x64 out (4x4 frags).
// LDS tiles [128 rows][64 bf16] with byte-XOR swizzle ((row&7)<<4) on 16B chunks.
// COLSEL: A column slice = bn*128 (block-diagonal / per-head GEMM).
// Epilogue: (+bias, ELU) -> bf16 LDS tile [128][136] -> full-cacheline stores.

__device__ __forceinline__ bf16x8 frag_ld(const unsigned short* lds, int row, int kbyte) {
  const char* base = (const char*)lds + row * 128;
  int sw = (row & 7) << 4;
  uint2 lo = *(const uint2*)(base + (kbyte ^ sw));
  uint2 hi = *(const uint2*)(base + ((kbyte + 32) ^ sw));
  union { bf16x8 v; uint2 u2[2]; } f;
  f.u2[0] = lo;
  f.u2[1] = hi;
  return f.v;
}

template <int K, int LDA, bool COLSEL, bool HASBIAS, bool DOELU>
__global__ __launch_bounds__(256) void gemm_mfma_kernel(const unsigned short* __restrict__ A,
                                                        const unsigned short* __restrict__ Bt,
                                                        unsigned short* __restrict__ C,
                                                        const float* __restrict__ bias, int Nc) {
  __shared__ char smem[128 * 136 * 2];  // 34816 B: holds As+Bs (32 KB) then C-stage
  unsigned short* As = (unsigned short*)smem;
  unsigned short* Bs = As + 8192;
  unsigned short* Cs = (unsigned short*)smem;  // [128][136]

  const int tid = threadIdx.x;
  const int lane = tid & 63;
  const int wave = tid >> 6;
  const int wm = wave >> 1, wn = wave & 1;
  const size_t bm = (size_t)blockIdx.x * 128;
  const int bn = blockIdx.y * 128;

  // staging: thread covers rows {srow, srow+32, srow+64, srow+96}, 16B each
  const int srow = tid >> 3;
  const int scolb = (tid & 7) << 4;
  const int sdst = srow * 64 + ((scolb ^ ((srow & 7) << 4)) >> 1);  // ushort index
  const size_t acol = COLSEL ? (size_t)bn : 0;
  const char* Ag = (const char*)(A + (bm + srow) * LDA + acol) + scolb;
  const char* Bg = (const char*)(Bt + (size_t)(bn + srow) * K) + scolb;

  f32x4 zero = {0.f, 0.f, 0.f, 0.f};
  f32x4 acc[4][4];
#pragma unroll
  for (int i = 0; i < 4; ++i)
#pragma unroll
    for (int j = 0; j < 4; ++j) acc[i][j] = zero;

  const int ln = lane & 15, lg = lane >> 4;
  const int fr_a = wm * 64 + ln;  // + mt*16
  const int fr_b = wn * 64 + ln;  // + nt*16
  const int kb0 = lg << 3;        // 0,8,16,24 bytes

  for (int kt = 0; kt < K; kt += 64) {
    uint4 av[4], bv[4];
#pragma unroll
    for (int i = 0; i < 4; ++i) {
      av[i] = *(const uint4*)(Ag + (size_t)32 * i * LDA * 2);
      bv[i] = *(const uint4*)(Bg + (size_t)32 * i * K * 2);
    }
    Ag += 128;  // +64 bf16 in k
    Bg += 128;
    if (kt) __syncthreads();  // previous tile fully consumed before overwrite
#pragma unroll
    for (int i = 0; i < 4; ++i) {
      *(uint4*)(As + sdst + 2048 * i) = av[i];
      *(uint4*)(Bs + sdst + 2048 * i) = bv[i];
    }
    __syncthreads();
#pragma unroll
    for (int kk = 0; kk < 2; ++kk) {
      bf16x8 af[4], bfr[4];
#pragma unroll
      for (int mt = 0; mt < 4; ++mt) af[mt] = frag_ld(As, fr_a + mt * 16, kk * 64 + kb0);
#pragma unroll
      for (int nt = 0; nt < 4; ++nt) bfr[nt] = frag_ld(Bs, fr_b + nt * 16, kk * 64 + kb0);
#pragma unroll
      for (int mt = 0; mt < 4; ++mt)
#pragma unroll
        for (int nt = 0; nt < 4; ++nt)
          acc[mt][nt] = __builtin_amdgcn_mfma_f32_16x16x32_bf16(af[mt], bfr[nt], acc[mt][nt], 0, 0, 0);
    }
  }

  // ---- epilogue: bias/ELU, stage bf16 tile in LDS, coalesced 128B stores ----
  float bvals[4] = {0.f, 0.f, 0.f, 0.f};
  if constexpr (HASBIAS) {
#pragma unroll
    for (int nt = 0; nt < 4; ++nt) bvals[nt] = bias[bn + wn * 64 + nt * 16 + ln];
  }
  __syncthreads();  // all frag reads done; smem becomes C-stage
#pragma unroll
  for (int mt = 0; mt < 4; ++mt) {
#pragma unroll
    for (int r = 0; r < 4; ++r) {
      unsigned short* rp = Cs + (wm * 64 + mt * 16 + lg * 4 + r) * 136 + wn * 64 + ln;
#pragma unroll
      for (int nt = 0; nt < 4; ++nt) {
        float v = acc[mt][nt][r];
        if constexpr (HASBIAS) v += bvals[nt];
        if constexpr (DOELU) v = v > 0.f ? v : expm1f(v);
        rp[nt * 16] = f2b(v);
      }
    }
  }
  __syncthreads();
  const int row_l = tid >> 1;
  const int colh = (tid & 1) << 6;  // 0 or 64 ushorts
  const unsigned short* sp = Cs + row_l * 136 + colh;
  unsigned short* dp = C + (bm + row_l) * Nc + bn + colh;
#pragma unroll
  for (int i = 0; i < 8; ++i) *(uint4*)(dp + i * 8) = *(const uint4*)(sp + i * 8);
}

// ---------------- vector GEMM (aligner only): C = A[M x K] @ B[K x Nc] + bias ----------------

__global__ __launch_bounds__(256) void gemm_align_kernel(const float* __restrict__ A, const float* __restrict__ B,
                                                         unsigned short* __restrict__ C, const float* __restrict__ bias,
                                                         int Nc, int K) {
  __shared__ float Asm[16][132];
  __shared__ float Bsm[16][132];
  const int tid = threadIdx.x;
  const int tx = tid & 15, ty = tid >> 4;
  const int bm = blockIdx.x, bn = blockIdx.y;
  const int m_l = tid >> 1;
  const int kh = (tid & 1) * 8;
  const int kb = tid >> 4;
  const int nq = (tid & 15) * 8;
  const float* Ap = A + (size_t)(bm * 128 + m_l) * K + kh;
  const float* Bp = B + (size_t)kb * Nc + bn * 128 + nq;

  float acc[8][8];
#pragma unroll
  for (int i = 0; i < 8; ++i)
#pragma unroll
    for (int j = 0; j < 8; ++j) acc[i][j] = 0.f;

  const int ksteps = K / 16;
  for (int t = 0; t < ksteps; ++t) {
    float av8[8], bv8[8];
    load8(Ap + t * 16, av8);
    load8(Bp + (size_t)t * 16 * Nc, bv8);
    __syncthreads();
#pragma unroll
    for (int q = 0; q < 8; ++q) Asm[kh + q][m_l] = av8[q];
    *(float4*)&Bsm[kb][nq] = *(float4*)&bv8[0];
    *(float4*)&Bsm[kb][nq + 4] = *(float4*)&bv8[4];
    __syncthreads();
#pragma unroll
    for (int kk = 0; kk < 16; ++kk) {
      float4 av0 = *(const float4*)&Asm[kk][ty * 4];
      float4 av1 = *(const float4*)&Asm[kk][64 + ty * 4];
      float4 bv0 = *(const float4*)&Bsm[kk][tx * 4];
      float4 bv1 = *(const float4*)&Bsm[kk][64 + tx * 4];
      float av[8] = {av0.x, av0.y, av0.z, av0.w, av1.x, av1.y, av1.z, av1.w};
      float bv[8] = {bv0.x, bv0.y, bv0.z, bv0.w, bv1.x, bv1.y, bv1.z, bv1.w};
#pragma unroll
      for (int i = 0; i < 8; ++i)
#pragma unroll
        for (int j = 0; j < 8; ++j) acc[i][j] += av[i] * bv[j];
    }
  }

  const int cn0 = bn * 128 + tx * 4;
#pragma unroll
  for (int i = 0; i < 8; ++i) {
    int r = bm * 128 + ((i < 4) ? (ty * 4 + i) : (64 + ty * 4 + i - 4));
    unsigned short* Crow = C + (size_t)r * Nc;
    float o0[4] = {acc[i][0], acc[i][1], acc[i][2], acc[i][3]};
    float o1[4] = {acc[i][4], acc[i][5], acc[i][6], acc[i][7]};
#pragma unroll
    for (int j = 0; j < 4; ++j) {
      o0[j] += bias[cn0 + j];
      o1[j] += bias[cn0 + 64 + j];
    }
    store4(Crow + cn0, o0);
    store4(Crow + cn0 + 64, o1);
  }
}

// ---------------- attention logits ----------------
// al1: from x0 (128-dim) with pre-transformed vectors vs1/vd1.

__global__ __launch_bounds__(256) void al1_kernel(const unsigned short* __restrict__ x0,
                                                  const float* __restrict__ vs1, const float* __restrict__ vd1,
                                                  float* __restrict__ al_s, float* __restrict__ al_d) {
  int n = blockIdx.x;
  int h = threadIdx.x >> 6;
  int lane = threadIdx.x & 63;
  unsigned v = *(const unsigned*)&x0[(size_t)n * 128 + lane * 2];
  float v0 = bf_lo(v), v1 = bf_hi(v);
  float2 as = *(const float2*)&vs1[h * 128 + lane * 2];
  float2 ad = *(const float2*)&vd1[h * 128 + lane * 2];
  float s = v0 * as.x + v1 * as.y;
  float d = v0 * ad.x + v1 * ad.y;
  for (int off = 32; off; off >>= 1) {
    s += __shfl_down(s, off);
    d += __shfl_down(d, off);
  }
  if (lane == 0) {
    al_s[n * 4 + h] = s;
    al_d[n * 4 + h] = d;
  }
}

__global__ __launch_bounds__(256) void al2_kernel(const unsigned short* __restrict__ hx,
                                                  const float* __restrict__ att_src,
                                                  const float* __restrict__ att_dst,
                                                  float* __restrict__ al_s, float* __restrict__ al_d) {
  int n = blockIdx.x * 4 + (threadIdx.x >> 6);
  int lane = threadIdx.x & 63;
  unsigned v = *(const unsigned*)&hx[(size_t)n * 128 + lane * 2];
  float v0 = bf_lo(v), v1 = bf_hi(v);
  float2 as = *(const float2*)&att_src[lane * 2];
  float2 ad = *(const float2*)&att_dst[lane * 2];
  float s = v0 * as.x + v1 * as.y;
  float d = v0 * ad.x + v1 * ad.y;
  for (int off = 32; off; off >>= 1) {
    s += __shfl_down(s, off);
    d += __shfl_down(d, off);
  }
  if (lane == 0) {
    al_s[n] = s;
    al_d[n] = d;
  }
}

// ---------------- GAT1 aggregation over x0: 4-head weighted gather ----------------
// ybar[n,h,:] = (w0_h*x0[n] + sum_p w1[p,h]*x0[src_p]) / den_h.  64 lanes/node,
// 2 channels/lane; the gathered x0 value is shared by all 4 heads.

__global__ __launch_bounds__(256) void agg1_kernel(const unsigned short* __restrict__ x0,
                                                   const float* __restrict__ al_s, const float* __restrict__ al_d,
                                                   const int* __restrict__ rowptr, const int* __restrict__ csr_src,
                                                   const float* __restrict__ w1, unsigned short* __restrict__ ybar) {
  int n = blockIdx.x * 4 + (threadIdx.x >> 6);
  int c2 = (threadIdx.x & 63) * 2;
  float4 As4 = *(const float4*)&al_s[n * 4];
  float4 Ad4 = *(const float4*)&al_d[n * 4];
  float w00 = expf(lrelu02(As4.x + Ad4.x));
  float w01 = expf(lrelu02(As4.y + Ad4.y));
  float w02 = expf(lrelu02(As4.z + Ad4.z));
  float w03 = expf(lrelu02(As4.w + Ad4.w));
  unsigned u = *(const unsigned*)&x0[(size_t)n * 128 + c2];
  float lo = bf_lo(u), hi = bf_hi(u);
  float a00 = w00 * lo, a01 = w01 * lo, a02 = w02 * lo, a03 = w03 * lo;
  float a10 = w00 * hi, a11 = w01 * hi, a12 = w02 * hi, a13 = w03 * hi;
  float d0 = w00, d1 = w01, d2 = w02, d3 = w03;
  int p0 = rowptr[n], p1 = rowptr[n + 1];
  int p = p0;
  for (; p + 4 <= p1; p += 4) {
    int s0 = csr_src[p], s1 = csr_src[p + 1], s2 = csr_src[p + 2], s3 = csr_src[p + 3];
    float4 wA = *(const float4*)&w1[(size_t)p * 4];
    float4 wB = *(const float4*)&w1[(size_t)(p + 1) * 4];
    float4 wC = *(const float4*)&w1[(size_t)(p + 2) * 4];
    float4 wD = *(const float4*)&w1[(size_t)(p + 3) * 4];
    unsigned u0 = *(const unsigned*)&x0[(size_t)s0 * 128 + c2];
    unsigned u1 = *(const unsigned*)&x0[(size_t)s1 * 128 + c2];
    unsigned u2 = *(const unsigned*)&x0[(size_t)s2 * 128 + c2];
    unsigned u3 = *(const unsigned*)&x0[(size_t)s3 * 128 + c2];
    float l0 = bf_lo(u0), h0 = bf_hi(u0);
    float l1 = bf_lo(u1), h1 = bf_hi(u1);
    float l2 = bf_lo(u2), h2 = bf_hi(u2);
    float l3 = bf_lo(u3), h3 = bf_hi(u3);
    a00 += wA.x * l0 + wB.x * l1 + wC.x * l2 + wD.x * l3;
    a01 += wA.y * l0 + wB.y * l1 + wC.y * l2 + wD.y * l3;
    a02 += wA.z * l0 + wB.z * l1 + wC.z * l2 + wD.z * l3;
    a03 += wA.w * l0 + wB.w * l1 + wC.w * l2 + wD.w * l3;
    a10 += wA.x * h0 + wB.x * h1 + wC.x * h2 + wD.x * h3;
    a11 += wA.y * h0 + wB.y * h1 + wC.y * h2 + wD.y * h3;
    a12 += wA.z * h0 + wB.z * h1 + wC.z * h2 + wD.z * h3;
    a13 += wA.w * h0 + wB.w * h1 + wC.w * h2 + wD.w * h3;
    d0 += wA.x + wB.x + wC.x + wD.x;
    d1 += wA.y + wB.y + wC.y + wD.y;
    d2 += wA.z + wB.z + wC.z + wD.z;
    d3 += wA.w + wB.w + wC.w + wD.w;
  }
  for (; p < p1; ++p) {
    int s = csr_src[p];
    float4 wA = *(const float4*)&w1[(size_t)p * 4];
    unsigned uu = *(const unsigned*)&x0[(size_t)s * 128 + c2];
    float l = bf_lo(uu), hh = bf_hi(uu);
    a00 += wA.x * l; a01 += wA.y * l; a02 += wA.z * l; a03 += wA.w * l;
    a10 += wA.x * hh; a11 += wA.y * hh; a12 += wA.z * hh; a13 += wA.w * hh;
    d0 += wA.x; d1 += wA.y; d2 += wA.z; d3 += wA.w;
  }
  unsigned short* yb = ybar + (size_t)n * 512 + c2;
  float i0 = 1.f / (d0 + 1e-16f), i1 = 1.f / (d1 + 1e-16f);
  float i2 = 1.f / (d2 + 1e-16f), i3 = 1.f / (d3 + 1e-16f);
  ushort2 o;
  o.x = f2b(a00 * i0); o.y = f2b(a10 * i0); *(ushort2*)(yb + 0) = o;
  o.x = f2b(a01 * i1); o.y = f2b(a11 * i1); *(ushort2*)(yb + 128) = o;
  o.x = f2b(a02 * i2); o.y = f2b(a12 * i2); *(ushort2*)(yb + 256) = o;
  o.x = f2b(a03 * i3); o.y = f2b(a13 * i3); *(ushort2*)(yb + 384) = o;
}

// ---------------- GAT2 aggregation: weighted gather over hx2, 4-deep ILP ----------------

__global__ __launch_bounds__(256) void agg2_kernel(const unsigned short* __restrict__ hx,
                                                   const float* __restrict__ al_s, const float* __restrict__ al_d,
                                                   const int* __restrict__ rowptr, const int* __restrict__ csr_src,
                                                   const float* __restrict__ w2, const float* __restrict__ b2,
                                                   float* __restrict__ out) {
  int n = blockIdx.x * 4 + (threadIdx.x >> 6);
  int c2 = (threadIdx.x & 63) * 2;
  float w0 = expf(lrelu02(al_s[n] + al_d[n]));
  unsigned u = *(const unsigned*)&hx[(size_t)n * 128 + c2];
  float acc0 = w0 * bf_lo(u), acc1 = w0 * bf_hi(u);
  float den = w0;
  int p0 = rowptr[n], p1 = rowptr[n + 1];
  int p = p0;
  for (; p + 4 <= p1; p += 4) {
    int s0 = csr_src[p], s1 = csr_src[p + 1], s2 = csr_src[p + 2], s3 = csr_src[p + 3];
    float wa = w2[p], wb = w2[p + 1], wc = w2[p + 2], wd = w2[p + 3];
    unsigned u0 = *(const unsigned*)&hx[(size_t)s0 * 128 + c2];
    unsigned u1 = *(const unsigned*)&hx[(size_t)s1 * 128 + c2];
    unsigned u2 = *(const unsigned*)&hx[(size_t)s2 * 128 + c2];
    unsigned u3 = *(const unsigned*)&hx[(size_t)s3 * 128 + c2];
    acc0 += wa * bf_lo(u0) + wb * bf_lo(u1) + wc * bf_lo(u2) + wd * bf_lo(u3);
    acc1 += wa * bf_hi(u0) + wb * bf_hi(u1) + wc * bf_hi(u2) + wd * bf_hi(u3);
    den += wa + wb + wc + wd;
  }
  for (; p < p1; ++p) {
    int s = csr_src[p];
    float w = w2[p];
    unsigned uu = *(const unsigned*)&hx[(size_t)s * 128 + c2];
    acc0 += w * bf_lo(uu);
    acc1 += w * bf_hi(uu);
    den += w;
  }
  float inv = 1.f / (den + 1e-16f);
  float2 o;
  o.x = acc0 * inv + b2[c2];
  o.y = acc1 * inv + b2[c2 + 1];
  *(float2*)&out[(size_t)n * 128 + c2] = o;
}

// ---------------- mean-pool + classifier MLP ----------------

__global__ __launch_bounds__(128) void poolcls_kernel(const float* __restrict__ x, const float* __restrict__ Wc1,
                                                      const float* __restrict__ bc1, const float* __restrict__ Wc2,
                                                      const float* __restrict__ bc2, float* __restrict__ out) {
  __shared__ float g[128];
  __shared__ float hcls[64];
  int b = blockIdx.x;
  int t = threadIdx.x;
  const float* base = x + (size_t)b * FPG * 128;
  float s = 0.f;
#pragma unroll
  for (int i = 0; i < FPG; ++i) s += base[i * 128 + t];
  g[t] = s * (1.0f / FPG);
  __syncthreads();
  if (t < 64) {
    float a = bc1[t];
#pragma unroll 4
    for (int k = 0; k < 128; ++k) a += g[k] * Wc1[k * 64 + t];
    hcls[t] = a > 0.f ? a : 0.01f * a;
  }
  __syncthreads();
  if (t < 10) {
    float a = bc2[t];
#pragma unroll
    for (int k = 0; k < 64; ++k) a += hcls[k] * Wc2[k * 10 + t];
    out[b * 10 + t] = a;
  }
}

}  // namespace

extern "C" void kernel_launch(void* const* d_in, const int* in_sizes, int n_in,
                              void* d_out, int out_size, void* d_ws, size_t ws_size,
                              hipStream_t stream) {
  const float* emb = (const float*)d_in[0];
  const int* edge = (const int*)d_in[1];
  // d_in[2] = batch = arange(N)//FPG -> exploited structurally in poolcls
  const float* W_align = (const float*)d_in[3];
  const float* b_align = (const float*)d_in[4];
  const float* W1 = (const float*)d_in[5];
  const float* att_src1 = (const float*)d_in[6];
  const float* att_dst1 = (const float*)d_in[7];
  const float* b1 = (const float*)d_in[8];
  const float* W2 = (const float*)d_in[9];
  const float* att_src2 = (const float*)d_in[10];
  const float* att_dst2 = (const float*)d_in[11];
  const float* b2 = (const float*)d_in[12];
  const float* Wc1 = (const float*)d_in[13];
  const float* bc1 = (const float*)d_in[14];
  const float* Wc2 = (const float*)d_in[15];
  const float* bc2 = (const float*)d_in[16];

  // workspace bump allocator (256B aligned). Peak ~162 MB.
  char* ws = (char*)d_ws;
  size_t off = 0;
  auto alloc = [&](size_t bytes) -> char* {
    char* p = ws + off;
    off += (bytes + 255) & ~(size_t)255;
    return p;
  };
  unsigned short* x0 = (unsigned short*)alloc((size_t)NNODE * 128 * 2);  // aligned x, bf16
  char* regA = alloc((size_t)NNODE * 512 * 2);                           // 67.1 MB: ybar -> hx2/out2
  unsigned short* x1 = (unsigned short*)alloc((size_t)NNODE * 512 * 2);  // ELU(GAT1), bf16
  float* al_s1 = (float*)alloc((size_t)NNODE * 4 * 4);
  float* al_d1 = (float*)alloc((size_t)NNODE * 4 * 4);
  float* al_s2 = (float*)alloc((size_t)NNODE * 4);
  float* al_d2 = (float*)alloc((size_t)NNODE * 4);
  int* deg = (int*)alloc((size_t)NNODE * 4);
  int* rowptr = (int*)alloc((size_t)(NNODE + 1) * 4);
  int* cursor = (int*)alloc((size_t)NNODE * 4);
  int* csr_src = (int*)alloc((size_t)NEDGE * 4);
  int* csr_dst = (int*)alloc((size_t)NEDGE * 4);
  float* w1 = (float*)alloc((size_t)NEDGE * 4 * 4);
  float* w2 = (float*)alloc((size_t)NEDGE * 4);
  unsigned short* w1t = (unsigned short*)alloc((size_t)512 * 128 * 2);  // W1^T bf16 [512][128]
  unsigned short* w2t = (unsigned short*)alloc((size_t)128 * 512 * 2);  // W2^T bf16 [128][512]
  float* vs1 = (float*)alloc((size_t)512 * 4);  // pre-transformed att vectors
  float* vd1 = (float*)alloc((size_t)512 * 4);

  // region aliasing: ybar (bf16 [N,512]) lives in regA until GEMM1' completes;
  // afterwards hx2 (bf16 [N,128]) and out2 (f32 [N,128]) share the region.
  unsigned short* ybar = (unsigned short*)regA;
  unsigned short* hx2 = (unsigned short*)regA;                // offset 0 (16.8 MB)
  float* out2 = (float*)(regA + (size_t)NNODE * 128 * 4);     // offset 33.5 MB

  const int* src = edge;
  const int* dst = edge + NEDGE;

  // CSR by dst (shared by both GAT layers) + weight conversion + att pre-transform
  hipMemsetAsync(deg, 0, (size_t)NNODE * 4, stream);
  hist_kernel<<<NEDGE / 256, 256, 0, stream>>>(dst, deg);
  scan_kernel<<<1, 1024, 0, stream>>>(deg, rowptr, cursor);
  scatter_kernel<<<NEDGE / 256, 256, 0, stream>>>(src, dst, cursor, csr_src, csr_dst);
  convw_kernel<<<256, 256, 0, stream>>>(W1, w1t, 128, 512);
  convw_kernel<<<256, 256, 0, stream>>>(W2, w2t, 512, 128);
  attv1_kernel<<<2, 256, 0, stream>>>(W1, att_src1, att_dst1, vs1, vd1);

  // aligner: x0 = emb @ W_align + b_align   [65536,64]@[64,128] -> bf16
  gemm_align_kernel<<<dim3(NNODE / 128, 1), 256, 0, stream>>>(emb, W_align, x0, b_align, 128, 64);
  // GAT1 logits from x0 directly (al = x0 · (W1 @ att))
  al1_kernel<<<NNODE, 256, 0, stream>>>(x0, vs1, vd1, al_s1, al_d1);
  edgew1_kernel<<<NEDGE / 256, 256, 0, stream>>>(csr_src, csr_dst, al_s1, al_d1, w1);
  // GAT1 aggregate-first: ybar[n,h,:] = softmax-weighted mean of x0 rows
  agg1_kernel<<<NNODE / 4, 256, 0, stream>>>(x0, al_s1, al_d1, rowptr, csr_src, w1, ybar);
  // GAT1 transform (block-diagonal per head) + b1 + ELU: x1 = elu(ybar @ W1_h + b1)
  gemm_mfma_kernel<128, 512, true, true, true><<<dim3(512, 4), 256, 0, stream>>>(ybar, w1t, x1, b1, 512);
  // GAT2 transform: hx2 = x1 @ W2           [65536,512]@[512,128] -> bf16 (aliases dead ybar)
  gemm_mfma_kernel<512, 512, false, false, false><<<dim3(512, 1), 256, 0, stream>>>(x1, w2t, hx2, nullptr, 128);
  al2_kernel<<<NNODE / 4, 256, 0, stream>>>(hx2, att_src2, att_dst2, al_s2, al_d2);
  edgew2_kernel<<<NEDGE / 256, 256, 0, stream>>>(csr_src, csr_dst, al_s2, al_d2, w2);
  agg2_kernel<<<NNODE / 4, 256, 0, stream>>>(hx2, al_s2, al_d2, rowptr, csr_src, w2, b2, out2);
  // pool + classifier
  poolcls_kernel<<<NGRAPH, 128, 0, stream>>>(out2, Wc1, bc1, Wc2, bc2, (float*)d_out);
}

// Round 7
// 342.953 us; speedup vs baseline: 1.7128x; 1.0439x over previous
//
#include <hip/hip_runtime.h>

// ProtocolTreeGAttention: aligner Linear -> GAT(128->128,H=4,concat) -> ELU ->
// GAT(512->128,H=1) -> mean-pool -> MLP classifier.
// Round 7: MFMA GEMM epilogue store remapped for per-WAVE-instruction line
// coverage (round 6 had per-thread contiguity -> 64 partial 16B line-touches
// per instruction -> 3x HBM write amplification).

namespace {

constexpr int NNODE = 65536;   // B*F
constexpr int NEDGE = 262144;
constexpr int NGRAPH = 2048;
constexpr int FPG = 32;

typedef __attribute__((ext_vector_type(8))) short bf16x8;
typedef __attribute__((ext_vector_type(4))) float f32x4;

__device__ __forceinline__ float lrelu02(float x) { return x > 0.f ? x : 0.2f * x; }
__device__ __forceinline__ float bf_lo(unsigned u) { return __uint_as_float(u << 16); }
__device__ __forceinline__ float bf_hi(unsigned u) { return __uint_as_float(u & 0xffff0000u); }
__device__ __forceinline__ unsigned short f2b(float f) {  // RNE bf16 round
  unsigned u = __float_as_uint(f);
  return (unsigned short)((u + 0x7fffu + ((u >> 16) & 1u)) >> 16);
}

__device__ __forceinline__ void load8(const float* p, float o[8]) {
  float4 a = *(const float4*)p;
  float4 b = *(const float4*)(p + 4);
  o[0] = a.x; o[1] = a.y; o[2] = a.z; o[3] = a.w;
  o[4] = b.x; o[5] = b.y; o[6] = b.z; o[7] = b.w;
}
__device__ __forceinline__ void store4(unsigned short* p, const float v[4]) {
  ushort4 o; o.x = f2b(v[0]); o.y = f2b(v[1]); o.z = f2b(v[2]); o.w = f2b(v[3]);
  *(ushort4*)p = o;
}

// ---------------- CSR build ----------------

__global__ __launch_bounds__(256) void hist_kernel(const int* __restrict__ dst, int* __restrict__ deg) {
  int e = blockIdx.x * 256 + threadIdx.x;
  if (e < NEDGE) atomicAdd(&deg[dst[e]], 1);
}

__global__ __launch_bounds__(1024) void scan_kernel(const int* __restrict__ deg, int* __restrict__ rowptr,
                                                    int* __restrict__ cursor) {
  __shared__ int sums[1024];
  int t = threadIdx.x;
  int base = t * 64;
  int s = 0;
  for (int i = 0; i < 64; ++i) s += deg[base + i];
  sums[t] = s;
  __syncthreads();
  for (int off = 1; off < 1024; off <<= 1) {
    int v = (t >= off) ? sums[t - off] : 0;
    __syncthreads();
    sums[t] += v;
    __syncthreads();
  }
  int run = (t == 0) ? 0 : sums[t - 1];
  for (int i = 0; i < 64; ++i) {
    rowptr[base + i] = run;
    cursor[base + i] = run;
    run += deg[base + i];
  }
  if (t == 1023) rowptr[NNODE] = run;
}

__global__ __launch_bounds__(256) void scatter_kernel(const int* __restrict__ src, const int* __restrict__ dst,
                                                      int* __restrict__ cursor, int* __restrict__ csr_src,
                                                      int* __restrict__ csr_dst) {
  int e = blockIdx.x * 256 + threadIdx.x;
  if (e < NEDGE) {
    int s = src[e], d = dst[e];
    int p = atomicAdd(&cursor[d], 1);
    csr_src[p] = s;
    csr_dst[p] = d;
  }
}

// ---------------- weight convert: Wt[n][k] = bf16(W[k][n]) ----------------

__global__ __launch_bounds__(256) void convw_kernel(const float* __restrict__ W, unsigned short* __restrict__ Wt,
                                                    int K, int N) {
  int idx = blockIdx.x * 256 + threadIdx.x;
  if (idx >= K * N) return;
  int n = idx / K, k = idx - n * K;
  Wt[idx] = f2b(W[(size_t)k * N + n]);
}

// ---------------- pre-transformed GAT1 attention vectors ----------------
// vs1[h*128+c] = sum_j W1[c, h*128+j] * att_src1[h,j]  (al_s1[n,h] = x0[n]·vs1[h])

__global__ __launch_bounds__(256) void attv1_kernel(const float* __restrict__ W1, const float* __restrict__ as1,
                                                    const float* __restrict__ ad1, float* __restrict__ vs1,
                                                    float* __restrict__ vd1) {
  int idx = blockIdx.x * 256 + threadIdx.x;  // 0..511
  int h = idx >> 7, c = idx & 127;
  float s = 0.f, d = 0.f;
  const float* wrow = W1 + (size_t)c * 512 + h * 128;
  const float* ar = as1 + h * 128;
  const float* dr = ad1 + h * 128;
  for (int j = 0; j < 128; ++j) {
    float w = wrow[j];
    s += w * ar[j];
    d += w * dr[j];
  }
  vs1[idx] = s;
  vd1[idx] = d;
}

// ---------------- per-edge attention weights (CSR order) ----------------

__global__ __launch_bounds__(256) void edgew1_kernel(const int* __restrict__ csr_src, const int* __restrict__ csr_dst,
                                                     const float* __restrict__ al_s, const float* __restrict__ al_d,
                                                     float* __restrict__ w1) {
  int p = blockIdx.x * 256 + threadIdx.x;
  if (p >= NEDGE) return;
  int s = csr_src[p], d = csr_dst[p];
  float4 as = *(const float4*)&al_s[s * 4];
  float4 ad = *(const float4*)&al_d[d * 4];
  float4 w;
  w.x = expf(lrelu02(as.x + ad.x));
  w.y = expf(lrelu02(as.y + ad.y));
  w.z = expf(lrelu02(as.z + ad.z));
  w.w = expf(lrelu02(as.w + ad.w));
  *(float4*)&w1[(size_t)p * 4] = w;
}

__global__ __launch_bounds__(256) void edgew2_kernel(const int* __restrict__ csr_src, const int* __restrict__ csr_dst,
                                                     const float* __restrict__ al_s, const float* __restrict__ al_d,
                                                     float* __restrict__ w2) {
  int p = blockIdx.x * 256 + threadIdx.x;
  if (p >= NEDGE) return;
  w2[p] = expf(lrelu02(al_s[csr_src[p]] + al_d[csr_dst[p]]));
}

// ---------------- MFMA GEMM: C[M x Nc](bf16) = A[M x K] @ Bt[Nc x K]^T ----------------
// BM=BN=128, BK=64, 256 threads = 4 waves (2x2), each wave 64x64 out (4x4 frags).
// LDS tiles [128 rows][64 bf16] with byte-XOR swizzle ((row&7)<<4) on 16B chunks.
// COLSEL: A column slice = bn*128 (block-diagonal / per-head GEMM).
// Epilogue: (+bias, ELU) -> bf16 LDS tile [128][136] -> per-instruction
// full-cacheline stores (16 lanes x 16B = one 256B row slice).

__device__ __forceinline__ bf16x8 frag_ld(const unsigned short* lds, int row, int kbyte) {
  const char* base = (const char*)lds + row * 128;
  int sw = (row & 7) << 4;
  uint2 lo = *(const uint2*)(base + (kbyte ^ sw));
  uint2 hi = *(const uint2*)(base + ((kbyte + 32) ^ sw));
  union { bf16x8 v; uint2 u2[2]; } f;
  f.u2[0] = lo;
  f.u2[1] = hi;
  return f.v;
}

template <int K, int LDA, bool COLSEL, bool HASBIAS, bool DOELU>
__global__ __launch_bounds__(256) void gemm_mfma_kernel(const unsigned short* __restrict__ A,
                                                        const unsigned short* __restrict__ Bt,
                                                        unsigned short* __restrict__ C,
                                                        const float* __restrict__ bias, int Nc) {
  __shared__ char smem[128 * 136 * 2];  // 34816 B: holds As+Bs (32 KB) then C-stage
  unsigned short* As = (unsigned short*)smem;
  unsigned short* Bs = As + 8192;
  unsigned short* Cs = (unsigned short*)smem;  // [128][136]

  const int tid = threadIdx.x;
  const int lane = tid & 63;
  const int wave = tid >> 6;
  const int wm = wave >> 1, wn = wave & 1;
  const size_t bm = (size_t)blockIdx.x * 128;
  const int bn = blockIdx.y * 128;

  // staging: thread covers rows {srow, srow+32, srow+64, srow+96}, 16B each
  const int srow = tid >> 3;
  const int scolb = (tid & 7) << 4;
  const int sdst = srow * 64 + ((scolb ^ ((srow & 7) << 4)) >> 1);  // ushort index
  const size_t acol = COLSEL ? (size_t)bn : 0;
  const char* Ag = (const char*)(A + (bm + srow) * LDA + acol) + scolb;
  const char* Bg = (const char*)(Bt + (size_t)(bn + srow) * K) + scolb;

  f32x4 zero = {0.f, 0.f, 0.f, 0.f};
  f32x4 acc[4][4];
#pragma unroll
  for (int i = 0; i < 4; ++i)
#pragma unroll
    for (int j = 0; j < 4; ++j) acc[i][j] = zero;

  const int ln = lane & 15, lg = lane >> 4;
  const int fr_a = wm * 64 + ln;  // + mt*16
  const int fr_b = wn * 64 + ln;  // + nt*16
  const int kb0 = lg << 3;        // 0,8,16,24 bytes

  for (int kt = 0; kt < K; kt += 64) {
    uint4 av[4], bv[4];
#pragma unroll
    for (int i = 0; i < 4; ++i) {
      av[i] = *(const uint4*)(Ag + (size_t)32 * i * LDA * 2);
      bv[i] = *(const uint4*)(Bg + (size_t)32 * i * K * 2);
    }
    Ag += 128;  // +64 bf16 in k
    Bg += 128;
    if (kt) __syncthreads();  // previous tile fully consumed before overwrite
#pragma unroll
    for (int i = 0; i < 4; ++i) {
      *(uint4*)(As + sdst + 2048 * i) = av[i];
      *(uint4*)(Bs + sdst + 2048 * i) = bv[i];
    }
    __syncthreads();
#pragma unroll
    for (int kk = 0; kk < 2; ++kk) {
      bf16x8 af[4], bfr[4];
#pragma unroll
      for (int mt = 0; mt < 4; ++mt) af[mt] = frag_ld(As, fr_a + mt * 16, kk * 64 + kb0);
#pragma unroll
      for (int nt = 0; nt < 4; ++nt) bfr[nt] = frag_ld(Bs, fr_b + nt * 16, kk * 64 + kb0);
#pragma unroll
      for (int mt = 0; mt < 4; ++mt)
#pragma unroll
        for (int nt = 0; nt < 4; ++nt)
          acc[mt][nt] = __builtin_amdgcn_mfma_f32_16x16x32_bf16(af[mt], bfr[nt], acc[mt][nt], 0, 0, 0);
    }
  }

  // ---- epilogue: bias/ELU, stage bf16 tile in LDS, wave-coalesced stores ----
  float bvals[4] = {0.f, 0.f, 0.f, 0.f};
  if constexpr (HASBIAS) {
#pragma unroll
    for (int nt = 0; nt < 4; ++nt) bvals[nt] = bias[bn + wn * 64 + nt * 16 + ln];
  }
  __syncthreads();  // all frag reads done; smem becomes C-stage
#pragma unroll
  for (int mt = 0; mt < 4; ++mt) {
#pragma unroll
    for (int r = 0; r < 4; ++r) {
      unsigned short* rp = Cs + (wm * 64 + mt * 16 + lg * 4 + r) * 136 + wn * 64 + ln;
#pragma unroll
      for (int nt = 0; nt < 4; ++nt) {
        float v = acc[mt][nt][r];
        if constexpr (HASBIAS) v += bvals[nt];
        if constexpr (DOELU) v = v > 0.f ? v : expm1f(v);
        rp[nt * 16] = f2b(v);
      }
    }
  }
  __syncthreads();
  // per-instruction: 16 consecutive lanes cover one row's 256B slice ->
  // every 128B line fully written by a single wave store instruction.
  const int r16 = tid >> 4;           // row within 16-row group
  const int cchunk = (tid & 15) * 8;  // 16B chunk within the 256B row slice
#pragma unroll
  for (int it = 0; it < 8; ++it) {
    int row = it * 16 + r16;
    *(uint4*)(C + (bm + row) * Nc + bn + cchunk) = *(const uint4*)(Cs + row * 136 + cchunk);
  }
}

// ---------------- vector GEMM (aligner only): C = A[M x K] @ B[K x Nc] + bias ----------------

__global__ __launch_bounds__(256) void gemm_align_kernel(const float* __restrict__ A, const float* __restrict__ B,
                                                         unsigned short* __restrict__ C, const float* __restrict__ bias,
                                                         int Nc, int K) {
  __shared__ float Asm[16][132];
  __shared__ float Bsm[16][132];
  const int tid = threadIdx.x;
  const int tx = tid & 15, ty = tid >> 4;
  const int bm = blockIdx.x, bn = blockIdx.y;
  const int m_l = tid >> 1;
  const int kh = (tid & 1) * 8;
  const int kb = tid >> 4;
  const int nq = (tid & 15) * 8;
  const float* Ap = A + (size_t)(bm * 128 + m_l) * K + kh;
  const float* Bp = B + (size_t)kb * Nc + bn * 128 + nq;

  float acc[8][8];
#pragma unroll
  for (int i = 0; i < 8; ++i)
#pragma unroll
    for (int j = 0; j < 8; ++j) acc[i][j] = 0.f;

  const int ksteps = K / 16;
  for (int t = 0; t < ksteps; ++t) {
    float av8[8], bv8[8];
    load8(Ap + t * 16, av8);
    load8(Bp + (size_t)t * 16 * Nc, bv8);
    __syncthreads();
#pragma unroll
    for (int q = 0; q < 8; ++q) Asm[kh + q][m_l] = av8[q];
    *(float4*)&Bsm[kb][nq] = *(float4*)&bv8[0];
    *(float4*)&Bsm[kb][nq + 4] = *(float4*)&bv8[4];
    __syncthreads();
#pragma unroll
    for (int kk = 0; kk < 16; ++kk) {
      float4 av0 = *(const float4*)&Asm[kk][ty * 4];
      float4 av1 = *(const float4*)&Asm[kk][64 + ty * 4];
      float4 bv0 = *(const float4*)&Bsm[kk][tx * 4];
      float4 bv1 = *(const float4*)&Bsm[kk][64 + tx * 4];
      float av[8] = {av0.x, av0.y, av0.z, av0.w, av1.x, av1.y, av1.z, av1.w};
      float bv[8] = {bv0.x, bv0.y, bv0.z, bv0.w, bv1.x, bv1.y, bv1.z, bv1.w};
#pragma unroll
      for (int i = 0; i < 8; ++i)
#pragma unroll
        for (int j = 0; j < 8; ++j) acc[i][j] += av[i] * bv[j];
    }
  }

  const int cn0 = bn * 128 + tx * 4;
#pragma unroll
  for (int i = 0; i < 8; ++i) {
    int r = bm * 128 + ((i < 4) ? (ty * 4 + i) : (64 + ty * 4 + i - 4));
    unsigned short* Crow = C + (size_t)r * Nc;
    float o0[4] = {acc[i][0], acc[i][1], acc[i][2], acc[i][3]};
    float o1[4] = {acc[i][4], acc[i][5], acc[i][6], acc[i][7]};
#pragma unroll
    for (int j = 0; j < 4; ++j) {
      o0[j] += bias[cn0 + j];
      o1[j] += bias[cn0 + 64 + j];
    }
    store4(Crow + cn0, o0);
    store4(Crow + cn0 + 64, o1);
  }
}

// ---------------- attention logits ----------------
// al1: from x0 (128-dim) with pre-transformed vectors vs1/vd1.

__global__ __launch_bounds__(256) void al1_kernel(const unsigned short* __restrict__ x0,
                                                  const float* __restrict__ vs1, const float* __restrict__ vd1,
                                                  float* __restrict__ al_s, float* __restrict__ al_d) {
  int n = blockIdx.x;
  int h = threadIdx.x >> 6;
  int lane = threadIdx.x & 63;
  unsigned v = *(const unsigned*)&x0[(size_t)n * 128 + lane * 2];
  float v0 = bf_lo(v), v1 = bf_hi(v);
  float2 as = *(const float2*)&vs1[h * 128 + lane * 2];
  float2 ad = *(const float2*)&vd1[h * 128 + lane * 2];
  float s = v0 * as.x + v1 * as.y;
  float d = v0 * ad.x + v1 * ad.y;
  for (int off = 32; off; off >>= 1) {
    s += __shfl_down(s, off);
    d += __shfl_down(d, off);
  }
  if (lane == 0) {
    al_s[n * 4 + h] = s;
    al_d[n * 4 + h] = d;
  }
}

__global__ __launch_bounds__(256) void al2_kernel(const unsigned short* __restrict__ hx,
                                                  const float* __restrict__ att_src,
                                                  const float* __restrict__ att_dst,
                                                  float* __restrict__ al_s, float* __restrict__ al_d) {
  int n = blockIdx.x * 4 + (threadIdx.x >> 6);
  int lane = threadIdx.x & 63;
  unsigned v = *(const unsigned*)&hx[(size_t)n * 128 + lane * 2];
  float v0 = bf_lo(v), v1 = bf_hi(v);
  float2 as = *(const float2*)&att_src[lane * 2];
  float2 ad = *(const float2*)&att_dst[lane * 2];
  float s = v0 * as.x + v1 * as.y;
  float d = v0 * ad.x + v1 * ad.y;
  for (int off = 32; off; off >>= 1) {
    s += __shfl_down(s, off);
    d += __shfl_down(d, off);
  }
  if (lane == 0) {
    al_s[n] = s;
    al_d[n] = d;
  }
}

// ---------------- GAT1 aggregation over x0: 4-head weighted gather ----------------

__global__ __launch_bounds__(256) void agg1_kernel(const unsigned short* __restrict__ x0,
                                                   const float* __restrict__ al_s, const float* __restrict__ al_d,
                                                   const int* __restrict__ rowptr, const int* __restrict__ csr_src,
                                                   const float* __restrict__ w1, unsigned short* __restrict__ ybar) {
  int n = blockIdx.x * 4 + (threadIdx.x >> 6);
  int c2 = (threadIdx.x & 63) * 2;
  float4 As4 = *(const float4*)&al_s[n * 4];
  float4 Ad4 = *(const float4*)&al_d[n * 4];
  float w00 = expf(lrelu02(As4.x + Ad4.x));
  float w01 = expf(lrelu02(As4.y + Ad4.y));
  float w02 = expf(lrelu02(As4.z + Ad4.z));
  float w03 = expf(lrelu02(As4.w + Ad4.w));
  unsigned u = *(const unsigned*)&x0[(size_t)n * 128 + c2];
  float lo = bf_lo(u), hi = bf_hi(u);
  float a00 = w00 * lo, a01 = w01 * lo, a02 = w02 * lo, a03 = w03 * lo;
  float a10 = w00 * hi, a11 = w01 * hi, a12 = w02 * hi, a13 = w03 * hi;
  float d0 = w00, d1 = w01, d2 = w02, d3 = w03;
  int p0 = rowptr[n], p1 = rowptr[n + 1];
  int p = p0;
  for (; p + 4 <= p1; p += 4) {
    int s0 = csr_src[p], s1 = csr_src[p + 1], s2 = csr_src[p + 2], s3 = csr_src[p + 3];
    float4 wA = *(const float4*)&w1[(size_t)p * 4];
    float4 wB = *(const float4*)&w1[(size_t)(p + 1) * 4];
    float4 wC = *(const float4*)&w1[(size_t)(p + 2) * 4];
    float4 wD = *(const float4*)&w1[(size_t)(p + 3) * 4];
    unsigned u0 = *(const unsigned*)&x0[(size_t)s0 * 128 + c2];
    unsigned u1 = *(const unsigned*)&x0[(size_t)s1 * 128 + c2];
    unsigned u2 = *(const unsigned*)&x0[(size_t)s2 * 128 + c2];
    unsigned u3 = *(const unsigned*)&x0[(size_t)s3 * 128 + c2];
    float l0 = bf_lo(u0), h0 = bf_hi(u0);
    float l1 = bf_lo(u1), h1 = bf_hi(u1);
    float l2 = bf_lo(u2), h2 = bf_hi(u2);
    float l3 = bf_lo(u3), h3 = bf_hi(u3);
    a00 += wA.x * l0 + wB.x * l1 + wC.x * l2 + wD.x * l3;
    a01 += wA.y * l0 + wB.y * l1 + wC.y * l2 + wD.y * l3;
    a02 += wA.z * l0 + wB.z * l1 + wC.z * l2 + wD.z * l3;
    a03 += wA.w * l0 + wB.w * l1 + wC.w * l2 + wD.w * l3;
    a10 += wA.x * h0 + wB.x * h1 + wC.x * h2 + wD.x * h3;
    a11 += wA.y * h0 + wB.y * h1 + wC.y * h2 + wD.y * h3;
    a12 += wA.z * h0 + wB.z * h1 + wC.z * h2 + wD.z * h3;
    a13 += wA.w * h0 + wB.w * h1 + wC.w * h2 + wD.w * h3;
    d0 += wA.x + wB.x + wC.x + wD.x;
    d1 += wA.y + wB.y + wC.y + wD.y;
    d2 += wA.z + wB.z + wC.z + wD.z;
    d3 += wA.w + wB.w + wC.w + wD.w;
  }
  for (; p < p1; ++p) {
    int s = csr_src[p];
    float4 wA = *(const float4*)&w1[(size_t)p * 4];
    unsigned uu = *(const unsigned*)&x0[(size_t)s * 128 + c2];
    float l = bf_lo(uu), hh = bf_hi(uu);
    a00 += wA.x * l; a01 += wA.y * l; a02 += wA.z * l; a03 += wA.w * l;
    a10 += wA.x * hh; a11 += wA.y * hh; a12 += wA.z * hh; a13 += wA.w * hh;
    d0 += wA.x; d1 += wA.y; d2 += wA.z; d3 += wA.w;
  }
  unsigned short* yb = ybar + (size_t)n * 512 + c2;
  float i0 = 1.f / (d0 + 1e-16f), i1 = 1.f / (d1 + 1e-16f);
  float i2 = 1.f / (d2 + 1e-16f), i3 = 1.f / (d3 + 1e-16f);
  ushort2 o;
  o.x = f2b(a00 * i0); o.y = f2b(a10 * i0); *(ushort2*)(yb + 0) = o;
  o.x = f2b(a01 * i1); o.y = f2b(a11 * i1); *(ushort2*)(yb + 128) = o;
  o.x = f2b(a02 * i2); o.y = f2b(a12 * i2); *(ushort2*)(yb + 256) = o;
  o.x = f2b(a03 * i3); o.y = f2b(a13 * i3); *(ushort2*)(yb + 384) = o;
}

// ---------------- GAT2 aggregation: weighted gather over hx2, 4-deep ILP ----------------

__global__ __launch_bounds__(256) void agg2_kernel(const unsigned short* __restrict__ hx,
                                                   const float* __restrict__ al_s, const float* __restrict__ al_d,
                                                   const int* __restrict__ rowptr, const int* __restrict__ csr_src,
                                                   const float* __restrict__ w2, const float* __restrict__ b2,
                                                   float* __restrict__ out) {
  int n = blockIdx.x * 4 + (threadIdx.x >> 6);
  int c2 = (threadIdx.x & 63) * 2;
  float w0 = expf(lrelu02(al_s[n] + al_d[n]));
  unsigned u = *(const unsigned*)&hx[(size_t)n * 128 + c2];
  float acc0 = w0 * bf_lo(u), acc1 = w0 * bf_hi(u);
  float den = w0;
  int p0 = rowptr[n], p1 = rowptr[n + 1];
  int p = p0;
  for (; p + 4 <= p1; p += 4) {
    int s0 = csr_src[p], s1 = csr_src[p + 1], s2 = csr_src[p + 2], s3 = csr_src[p + 3];
    float wa = w2[p], wb = w2[p + 1], wc = w2[p + 2], wd = w2[p + 3];
    unsigned u0 = *(const unsigned*)&hx[(size_t)s0 * 128 + c2];
    unsigned u1 = *(const unsigned*)&hx[(size_t)s1 * 128 + c2];
    unsigned u2 = *(const unsigned*)&hx[(size_t)s2 * 128 + c2];
    unsigned u3 = *(const unsigned*)&hx[(size_t)s3 * 128 + c2];
    acc0 += wa * bf_lo(u0) + wb * bf_lo(u1) + wc * bf_lo(u2) + wd * bf_lo(u3);
    acc1 += wa * bf_hi(u0) + wb * bf_hi(u1) + wc * bf_hi(u2) + wd * bf_hi(u3);
    den += wa + wb + wc + wd;
  }
  for (; p < p1; ++p) {
    int s = csr_src[p];
    float w = w2[p];
    unsigned uu = *(const unsigned*)&hx[(size_t)s * 128 + c2];
    acc0 += w * bf_lo(uu);
    acc1 += w * bf_hi(uu);
    den += w;
  }
  float inv = 1.f / (den + 1e-16f);
  float2 o;
  o.x = acc0 * inv + b2[c2];
  o.y = acc1 * inv + b2[c2 + 1];
  *(float2*)&out[(size_t)n * 128 + c2] = o;
}

// ---------------- mean-pool + classifier MLP ----------------

__global__ __launch_bounds__(128) void poolcls_kernel(const float* __restrict__ x, const float* __restrict__ Wc1,
                                                      const float* __restrict__ bc1, const float* __restrict__ Wc2,
                                                      const float* __restrict__ bc2, float* __restrict__ out) {
  __shared__ float g[128];
  __shared__ float hcls[64];
  int b = blockIdx.x;
  int t = threadIdx.x;
  const float* base = x + (size_t)b * FPG * 128;
  float s = 0.f;
#pragma unroll
  for (int i = 0; i < FPG; ++i) s += base[i * 128 + t];
  g[t] = s * (1.0f / FPG);
  __syncthreads();
  if (t < 64) {
    float a = bc1[t];
#pragma unroll 4
    for (int k = 0; k < 128; ++k) a += g[k] * Wc1[k * 64 + t];
    hcls[t] = a > 0.f ? a : 0.01f * a;
  }
  __syncthreads();
  if (t < 10) {
    float a = bc2[t];
#pragma unroll
    for (int k = 0; k < 64; ++k) a += hcls[k] * Wc2[k * 10 + t];
    out[b * 10 + t] = a;
  }
}

}  // namespace

extern "C" void kernel_launch(void* const* d_in, const int* in_sizes, int n_in,
                              void* d_out, int out_size, void* d_ws, size_t ws_size,
                              hipStream_t stream) {
  const float* emb = (const float*)d_in[0];
  const int* edge = (const int*)d_in[1];
  // d_in[2] = batch = arange(N)//FPG -> exploited structurally in poolcls
  const float* W_align = (const float*)d_in[3];
  const float* b_align = (const float*)d_in[4];
  const float* W1 = (const float*)d_in[5];
  const float* att_src1 = (const float*)d_in[6];
  const float* att_dst1 = (const float*)d_in[7];
  const float* b1 = (const float*)d_in[8];
  const float* W2 = (const float*)d_in[9];
  const float* att_src2 = (const float*)d_in[10];
  const float* att_dst2 = (const float*)d_in[11];
  const float* b2 = (const float*)d_in[12];
  const float* Wc1 = (const float*)d_in[13];
  const float* bc1 = (const float*)d_in[14];
  const float* Wc2 = (const float*)d_in[15];
  const float* bc2 = (const float*)d_in[16];

  // workspace bump allocator (256B aligned). Peak ~162 MB.
  char* ws = (char*)d_ws;
  size_t off = 0;
  auto alloc = [&](size_t bytes) -> char* {
    char* p = ws + off;
    off += (bytes + 255) & ~(size_t)255;
    return p;
  };
  unsigned short* x0 = (unsigned short*)alloc((size_t)NNODE * 128 * 2);  // aligned x, bf16
  char* regA = alloc((size_t)NNODE * 512 * 2);                           // 67.1 MB: ybar -> hx2/out2
  unsigned short* x1 = (unsigned short*)alloc((size_t)NNODE * 512 * 2);  // ELU(GAT1), bf16
  float* al_s1 = (float*)alloc((size_t)NNODE * 4 * 4);
  float* al_d1 = (float*)alloc((size_t)NNODE * 4 * 4);
  float* al_s2 = (float*)alloc((size_t)NNODE * 4);
  float* al_d2 = (float*)alloc((size_t)NNODE * 4);
  int* deg = (int*)alloc((size_t)NNODE * 4);
  int* rowptr = (int*)alloc((size_t)(NNODE + 1) * 4);
  int* cursor = (int*)alloc((size_t)NNODE * 4);
  int* csr_src = (int*)alloc((size_t)NEDGE * 4);
  int* csr_dst = (int*)alloc((size_t)NEDGE * 4);
  float* w1 = (float*)alloc((size_t)NEDGE * 4 * 4);
  float* w2 = (float*)alloc((size_t)NEDGE * 4);
  unsigned short* w1t = (unsigned short*)alloc((size_t)512 * 128 * 2);  // W1^T bf16 [512][128]
  unsigned short* w2t = (unsigned short*)alloc((size_t)128 * 512 * 2);  // W2^T bf16 [128][512]
  float* vs1 = (float*)alloc((size_t)512 * 4);  // pre-transformed att vectors
  float* vd1 = (float*)alloc((size_t)512 * 4);

  // region aliasing: ybar (bf16 [N,512]) lives in regA until GEMM1' completes;
  // afterwards hx2 (bf16 [N,128]) and out2 (f32 [N,128]) share the region.
  unsigned short* ybar = (unsigned short*)regA;
  unsigned short* hx2 = (unsigned short*)regA;                // offset 0 (16.8 MB)
  float* out2 = (float*)(regA + (size_t)NNODE * 128 * 4);     // offset 33.5 MB

  const int* src = edge;
  const int* dst = edge + NEDGE;

  // CSR by dst (shared by both GAT layers) + weight conversion + att pre-transform
  hipMemsetAsync(deg, 0, (size_t)NNODE * 4, stream);
  hist_kernel<<<NEDGE / 256, 256, 0, stream>>>(dst, deg);
  scan_kernel<<<1, 1024, 0, stream>>>(deg, rowptr, cursor);
  scatter_kernel<<<NEDGE / 256, 256, 0, stream>>>(src, dst, cursor, csr_src, csr_dst);
  convw_kernel<<<256, 256, 0, stream>>>(W1, w1t, 128, 512);
  convw_kernel<<<256, 256, 0, stream>>>(W2, w2t, 512, 128);
  attv1_kernel<<<2, 256, 0, stream>>>(W1, att_src1, att_dst1, vs1, vd1);

  // aligner: x0 = emb @ W_align + b_align   [65536,64]@[64,128] -> bf16
  gemm_align_kernel<<<dim3(NNODE / 128, 1), 256, 0, stream>>>(emb, W_align, x0, b_align, 128, 64);
  // GAT1 logits from x0 directly (al = x0 · (W1 @ att))
  al1_kernel<<<NNODE, 256, 0, stream>>>(x0, vs1, vd1, al_s1, al_d1);
  edgew1_kernel<<<NEDGE / 256, 256, 0, stream>>>(csr_src, csr_dst, al_s1, al_d1, w1);
  // GAT1 aggregate-first: ybar[n,h,:] = softmax-weighted mean of x0 rows
  agg1_kernel<<<NNODE / 4, 256, 0, stream>>>(x0, al_s1, al_d1, rowptr, csr_src, w1, ybar);
  // GAT1 transform (block-diagonal per head) + b1 + ELU: x1 = elu(ybar @ W1_h + b1)
  gemm_mfma_kernel<128, 512, true, true, true><<<dim3(512, 4), 256, 0, stream>>>(ybar, w1t, x1, b1, 512);
  // GAT2 transform: hx2 = x1 @ W2           [65536,512]@[512,128] -> bf16 (aliases dead ybar)
  gemm_mfma_kernel<512, 512, false, false, false><<<dim3(512, 1), 256, 0, stream>>>(x1, w2t, hx2, nullptr, 128);
  al2_kernel<<<NNODE / 4, 256, 0, stream>>>(hx2, att_src2, att_dst2, al_s2, al_d2);
  edgew2_kernel<<<NEDGE / 256, 256, 0, stream>>>(csr_src, csr_dst, al_s2, al_d2, w2);
  agg2_kernel<<<NNODE / 4, 256, 0, stream>>>(hx2, al_s2, al_d2, rowptr, csr_src, w2, b2, out2);
  // pool + classifier
  poolcls_kernel<<<NGRAPH, 128, 0, stream>>>(out2, Wc1, bc1, Wc2, bc2, (float*)d_out);
}

// Round 8
// 310.991 us; speedup vs baseline: 1.8888x; 1.1028x over previous
//
#include <hip/hip_runtime.h>

// ProtocolTreeGAttention: aligner Linear -> GAT(128->128,H=4,concat) -> ELU ->
// GAT(512->128,H=1) -> mean-pool -> MLP classifier.
// Round 8: GAT1-transform(+bias+ELU) and GAT2-transform fused into one MFMA
// kernel; x1 lives only in LDS (rounds 5-7 showed the x1 global write costs
// 3x in HBM WRITE traffic regardless of store pattern).

namespace {

constexpr int NNODE = 65536;   // B*F
constexpr int NEDGE = 262144;
constexpr int NGRAPH = 2048;
constexpr int FPG = 32;

typedef __attribute__((ext_vector_type(8))) short bf16x8;
typedef __attribute__((ext_vector_type(4))) float f32x4;

__device__ __forceinline__ float lrelu02(float x) { return x > 0.f ? x : 0.2f * x; }
__device__ __forceinline__ float bf_lo(unsigned u) { return __uint_as_float(u << 16); }
__device__ __forceinline__ float bf_hi(unsigned u) { return __uint_as_float(u & 0xffff0000u); }
__device__ __forceinline__ unsigned short f2b(float f) {  // RNE bf16 round
  unsigned u = __float_as_uint(f);
  return (unsigned short)((u + 0x7fffu + ((u >> 16) & 1u)) >> 16);
}

__device__ __forceinline__ void load8(const float* p, float o[8]) {
  float4 a = *(const float4*)p;
  float4 b = *(const float4*)(p + 4);
  o[0] = a.x; o[1] = a.y; o[2] = a.z; o[3] = a.w;
  o[4] = b.x; o[5] = b.y; o[6] = b.z; o[7] = b.w;
}
__device__ __forceinline__ void store4(unsigned short* p, const float v[4]) {
  ushort4 o; o.x = f2b(v[0]); o.y = f2b(v[1]); o.z = f2b(v[2]); o.w = f2b(v[3]);
  *(ushort4*)p = o;
}

// ---------------- CSR build ----------------

__global__ __launch_bounds__(256) void hist_kernel(const int* __restrict__ dst, int* __restrict__ deg) {
  int e = blockIdx.x * 256 + threadIdx.x;
  if (e < NEDGE) atomicAdd(&deg[dst[e]], 1);
}

__global__ __launch_bounds__(1024) void scan_kernel(const int* __restrict__ deg, int* __restrict__ rowptr,
                                                    int* __restrict__ cursor) {
  __shared__ int sums[1024];
  int t = threadIdx.x;
  int base = t * 64;
  int s = 0;
  for (int i = 0; i < 64; ++i) s += deg[base + i];
  sums[t] = s;
  __syncthreads();
  for (int off = 1; off < 1024; off <<= 1) {
    int v = (t >= off) ? sums[t - off] : 0;
    __syncthreads();
    sums[t] += v;
    __syncthreads();
  }
  int run = (t == 0) ? 0 : sums[t - 1];
  for (int i = 0; i < 64; ++i) {
    rowptr[base + i] = run;
    cursor[base + i] = run;
    run += deg[base + i];
  }
  if (t == 1023) rowptr[NNODE] = run;
}

__global__ __launch_bounds__(256) void scatter_kernel(const int* __restrict__ src, const int* __restrict__ dst,
                                                      int* __restrict__ cursor, int* __restrict__ csr_src,
                                                      int* __restrict__ csr_dst) {
  int e = blockIdx.x * 256 + threadIdx.x;
  if (e < NEDGE) {
    int s = src[e], d = dst[e];
    int p = atomicAdd(&cursor[d], 1);
    csr_src[p] = s;
    csr_dst[p] = d;
  }
}

// ---------------- weight convert: Wt[n][k] = bf16(W[k][n]) ----------------

__global__ __launch_bounds__(256) void convw_kernel(const float* __restrict__ W, unsigned short* __restrict__ Wt,
                                                    int K, int N) {
  int idx = blockIdx.x * 256 + threadIdx.x;
  if (idx >= K * N) return;
  int n = idx / K, k = idx - n * K;
  Wt[idx] = f2b(W[(size_t)k * N + n]);
}

// ---------------- pre-transformed GAT1 attention vectors ----------------

__global__ __launch_bounds__(256) void attv1_kernel(const float* __restrict__ W1, const float* __restrict__ as1,
                                                    const float* __restrict__ ad1, float* __restrict__ vs1,
                                                    float* __restrict__ vd1) {
  int idx = blockIdx.x * 256 + threadIdx.x;  // 0..511
  int h = idx >> 7, c = idx & 127;
  float s = 0.f, d = 0.f;
  const float* wrow = W1 + (size_t)c * 512 + h * 128;
  const float* ar = as1 + h * 128;
  const float* dr = ad1 + h * 128;
  for (int j = 0; j < 128; ++j) {
    float w = wrow[j];
    s += w * ar[j];
    d += w * dr[j];
  }
  vs1[idx] = s;
  vd1[idx] = d;
}

// ---------------- per-edge attention weights (CSR order) ----------------

__global__ __launch_bounds__(256) void edgew1_kernel(const int* __restrict__ csr_src, const int* __restrict__ csr_dst,
                                                     const float* __restrict__ al_s, const float* __restrict__ al_d,
                                                     float* __restrict__ w1) {
  int p = blockIdx.x * 256 + threadIdx.x;
  if (p >= NEDGE) return;
  int s = csr_src[p], d = csr_dst[p];
  float4 as = *(const float4*)&al_s[s * 4];
  float4 ad = *(const float4*)&al_d[d * 4];
  float4 w;
  w.x = expf(lrelu02(as.x + ad.x));
  w.y = expf(lrelu02(as.y + ad.y));
  w.z = expf(lrelu02(as.z + ad.z));
  w.w = expf(lrelu02(as.w + ad.w));
  *(float4*)&w1[(size_t)p * 4] = w;
}

__global__ __launch_bounds__(256) void edgew2_kernel(const int* __restrict__ csr_src, const int* __restrict__ csr_dst,
                                                     const float* __restrict__ al_s, const float* __restrict__ al_d,
                                                     float* __restrict__ w2) {
  int p = blockIdx.x * 256 + threadIdx.x;
  if (p >= NEDGE) return;
  w2[p] = expf(lrelu02(al_s[csr_src[p]] + al_d[csr_dst[p]]));
}

// ---------------- LDS fragment loaders (XOR-swizzled tiles) ----------------
// frag layout (m91-verified): lane&15 = row index; k = (lane>>4)*4 + (j&3) + 16*(j>>2).

__device__ __forceinline__ bf16x8 frag_ld(const unsigned short* lds, int row, int kbyte) {
  const char* base = (const char*)lds + row * 128;  // [*][64] tile
  int sw = (row & 7) << 4;
  uint2 lo = *(const uint2*)(base + (kbyte ^ sw));
  uint2 hi = *(const uint2*)(base + ((kbyte + 32) ^ sw));
  union { bf16x8 v; uint2 u2[2]; } f;
  f.u2[0] = lo;
  f.u2[1] = hi;
  return f.v;
}

__device__ __forceinline__ bf16x8 frag_ld_x(const unsigned short* lds, int row, int kbyte) {
  const char* base = (const char*)lds + row * 256;  // [*][128] tile
  int sw = (row & 7) << 4;
  uint2 lo = *(const uint2*)(base + (kbyte ^ sw));
  uint2 hi = *(const uint2*)(base + ((kbyte + 32) ^ sw));
  union { bf16x8 v; uint2 u2[2]; } f;
  f.u2[0] = lo;
  f.u2[1] = hi;
  return f.v;
}

// ---------------- fused GAT1-transform + GAT2-transform ----------------
// Per block: 128 node rows. For head h:
//   stage 1: acc1[c][m] = sum_k W1t[h*128+c][k] * ybar[bm+m][h*128+k]   (A=W1t, B=ybar)
//            -> +b1, ELU, pack bf16 -> Xs[m][c] (row-major, swizzled), c = stage-2 k
//   stage 2: acc2[m][n] += sum_c Xs[m][c] * W2t[n][h*128+c]
// Epilogue: acc2 -> bf16 -> hx2[bm+m][n] (contiguous full-line stores).

__global__ __launch_bounds__(256, 2) void fused12_kernel(const unsigned short* __restrict__ ybar,
                                                         const unsigned short* __restrict__ w1t,
                                                         const unsigned short* __restrict__ w2t,
                                                         const float* __restrict__ b1,
                                                         unsigned short* __restrict__ hx2) {
  __shared__ char smem[65536];
  unsigned short* As = (unsigned short*)smem;   // [128][64] staging (W1t / unused in s2) 16 KiB
  unsigned short* Bs = As + 8192;               // [128][64] staging (ybar / W2t)         16 KiB
  unsigned short* Xs = Bs + 8192;               // [128][128] x1 head tile                 32 KiB

  const int tid = threadIdx.x;
  const int lane = tid & 63;
  const int wave = tid >> 6;
  const int wm = wave >> 1, wn = wave & 1;
  const size_t bm = (size_t)blockIdx.x * 128;

  const int srow = tid >> 3;         // staging: 0..31 (+32i)
  const int scolb = (tid & 7) << 4;  // 0..112 bytes
  const int sdst = srow * 64 + ((scolb ^ ((srow & 7) << 4)) >> 1);  // ushort index

  const int ln = lane & 15, lg = lane >> 4;
  const int kb0 = lg << 3;

  f32x4 zero = {0.f, 0.f, 0.f, 0.f};
  f32x4 acc2[4][4];
#pragma unroll
  for (int i = 0; i < 4; ++i)
#pragma unroll
    for (int j = 0; j < 4; ++j) acc2[i][j] = zero;

  for (int h = 0; h < 4; ++h) {
    f32x4 acc1[4][4];
#pragma unroll
    for (int i = 0; i < 4; ++i)
#pragma unroll
      for (int j = 0; j < 4; ++j) acc1[i][j] = zero;

    // ---- stage 1: K=128 over x0-dims, 2 k-tiles ----
#pragma unroll
    for (int kt = 0; kt < 2; ++kt) {
      const char* Wg = (const char*)(w1t + (size_t)(h * 128 + srow) * 128 + kt * 64) + scolb;
      const char* Yg = (const char*)(ybar + (bm + srow) * 512 + h * 128 + kt * 64) + scolb;
      uint4 av[4], bv[4];
#pragma unroll
      for (int i = 0; i < 4; ++i) {
        av[i] = *(const uint4*)(Wg + (size_t)32 * i * 256);   // W1t row stride 256 B
        bv[i] = *(const uint4*)(Yg + (size_t)32 * i * 1024);  // ybar row stride 1024 B
      }
      __syncthreads();  // previous phase's LDS reads complete
#pragma unroll
      for (int i = 0; i < 4; ++i) {
        *(uint4*)(As + sdst + 2048 * i) = av[i];
        *(uint4*)(Bs + sdst + 2048 * i) = bv[i];
      }
      __syncthreads();
#pragma unroll
      for (int kk = 0; kk < 2; ++kk) {
        bf16x8 af[4], bfr[4];
#pragma unroll
        for (int mt = 0; mt < 4; ++mt) af[mt] = frag_ld(As, wm * 64 + mt * 16 + ln, kk * 64 + kb0);
#pragma unroll
        for (int nt = 0; nt < 4; ++nt) bfr[nt] = frag_ld(Bs, wn * 64 + nt * 16 + ln, kk * 64 + kb0);
#pragma unroll
        for (int mt = 0; mt < 4; ++mt)
#pragma unroll
          for (int nt = 0; nt < 4; ++nt)
            acc1[mt][nt] = __builtin_amdgcn_mfma_f32_16x16x32_bf16(af[mt], bfr[nt], acc1[mt][nt], 0, 0, 0);
      }
    }

    // ---- pack x1h = elu(acc1 + b1) -> Xs[m][c], 8B writes ----
    // (Xs writes vs prev head's stage-2 reads are separated by stage-1's barriers.)
#pragma unroll
    for (int mt = 0; mt < 4; ++mt) {
      const int c0 = wm * 64 + mt * 16 + lg * 4;
      float4 bb = *(const float4*)&b1[h * 128 + c0];
#pragma unroll
      for (int nt = 0; nt < 4; ++nt) {
        const int m = wn * 64 + nt * 16 + ln;
        float v0 = acc1[mt][nt][0] + bb.x;
        float v1 = acc1[mt][nt][1] + bb.y;
        float v2 = acc1[mt][nt][2] + bb.z;
        float v3 = acc1[mt][nt][3] + bb.w;
        v0 = v0 > 0.f ? v0 : __expf(v0) - 1.f;
        v1 = v1 > 0.f ? v1 : __expf(v1) - 1.f;
        v2 = v2 > 0.f ? v2 : __expf(v2) - 1.f;
        v3 = v3 > 0.f ? v3 : __expf(v3) - 1.f;
        ushort4 o;
        o.x = f2b(v0); o.y = f2b(v1); o.z = f2b(v2); o.w = f2b(v3);
        *(ushort4*)((char*)Xs + m * 256 + ((c0 * 2) ^ ((m & 7) << 4))) = o;
      }
    }

    // ---- stage 2: accumulate acc2 over this head's 128 k (2 k-tiles) ----
#pragma unroll
    for (int kt = 0; kt < 2; ++kt) {
      const char* W2g = (const char*)(w2t + (size_t)srow * 512 + h * 128 + kt * 64) + scolb;
      uint4 bv[4];
#pragma unroll
      for (int i = 0; i < 4; ++i) bv[i] = *(const uint4*)(W2g + (size_t)32 * i * 1024);
      __syncthreads();  // pack-writes done by all waves; prev Bs reads done
#pragma unroll
      for (int i = 0; i < 4; ++i) *(uint4*)(Bs + sdst + 2048 * i) = bv[i];
      __syncthreads();
#pragma unroll
      for (int kk = 0; kk < 2; ++kk) {
        bf16x8 af[4], bfr[4];
#pragma unroll
        for (int mt = 0; mt < 4; ++mt)
          af[mt] = frag_ld_x(Xs, wm * 64 + mt * 16 + ln, kt * 128 + kk * 64 + kb0);
#pragma unroll
        for (int nt = 0; nt < 4; ++nt) bfr[nt] = frag_ld(Bs, wn * 64 + nt * 16 + ln, kk * 64 + kb0);
#pragma unroll
        for (int mt = 0; mt < 4; ++mt)
#pragma unroll
          for (int nt = 0; nt < 4; ++nt)
            acc2[mt][nt] = __builtin_amdgcn_mfma_f32_16x16x32_bf16(af[mt], bfr[nt], acc2[mt][nt], 0, 0, 0);
      }
    }
  }

  // ---- epilogue: acc2 -> bf16 LDS C-stage [128][136] -> contiguous stores ----
  __syncthreads();
  unsigned short* Cs = (unsigned short*)smem;
#pragma unroll
  for (int mt = 0; mt < 4; ++mt) {
#pragma unroll
    for (int r = 0; r < 4; ++r) {
      unsigned short* rp = Cs + (wm * 64 + mt * 16 + lg * 4 + r) * 136 + wn * 64 + ln;
#pragma unroll
      for (int nt = 0; nt < 4; ++nt) rp[nt * 16] = f2b(acc2[mt][nt][r]);
    }
  }
  __syncthreads();
  const int r16 = tid >> 4;
  const int cchunk = (tid & 15) * 8;
#pragma unroll
  for (int it = 0; it < 8; ++it) {
    int row = it * 16 + r16;
    *(uint4*)(hx2 + (bm + row) * 128 + cchunk) = *(const uint4*)(Cs + row * 136 + cchunk);
  }
}

// ---------------- vector GEMM (aligner only): C = A[M x K] @ B[K x Nc] + bias ----------------

__global__ __launch_bounds__(256) void gemm_align_kernel(const float* __restrict__ A, const float* __restrict__ B,
                                                         unsigned short* __restrict__ C, const float* __restrict__ bias,
                                                         int Nc, int K) {
  __shared__ float Asm[16][132];
  __shared__ float Bsm[16][132];
  const int tid = threadIdx.x;
  const int tx = tid & 15, ty = tid >> 4;
  const int bm = blockIdx.x, bn = blockIdx.y;
  const int m_l = tid >> 1;
  const int kh = (tid & 1) * 8;
  const int kb = tid >> 4;
  const int nq = (tid & 15) * 8;
  const float* Ap = A + (size_t)(bm * 128 + m_l) * K + kh;
  const float* Bp = B + (size_t)kb * Nc + bn * 128 + nq;

  float acc[8][8];
#pragma unroll
  for (int i = 0; i < 8; ++i)
#pragma unroll
    for (int j = 0; j < 8; ++j) acc[i][j] = 0.f;

  const int ksteps = K / 16;
  for (int t = 0; t < ksteps; ++t) {
    float av8[8], bv8[8];
    load8(Ap + t * 16, av8);
    load8(Bp + (size_t)t * 16 * Nc, bv8);
    __syncthreads();
#pragma unroll
    for (int q = 0; q < 8; ++q) Asm[kh + q][m_l] = av8[q];
    *(float4*)&Bsm[kb][nq] = *(float4*)&bv8[0];
    *(float4*)&Bsm[kb][nq + 4] = *(float4*)&bv8[4];
    __syncthreads();
#pragma unroll
    for (int kk = 0; kk < 16; ++kk) {
      float4 av0 = *(const float4*)&Asm[kk][ty * 4];
      float4 av1 = *(const float4*)&Asm[kk][64 + ty * 4];
      float4 bv0 = *(const float4*)&Bsm[kk][tx * 4];
      float4 bv1 = *(const float4*)&Bsm[kk][64 + tx * 4];
      float av[8] = {av0.x, av0.y, av0.z, av0.w, av1.x, av1.y, av1.z, av1.w};
      float bv[8] = {bv0.x, bv0.y, bv0.z, bv0.w, bv1.x, bv1.y, bv1.z, bv1.w};
#pragma unroll
      for (int i = 0; i < 8; ++i)
#pragma unroll
        for (int j = 0; j < 8; ++j) acc[i][j] += av[i] * bv[j];
    }
  }

  const int cn0 = bn * 128 + tx * 4;
#pragma unroll
  for (int i = 0; i < 8; ++i) {
    int r = bm * 128 + ((i < 4) ? (ty * 4 + i) : (64 + ty * 4 + i - 4));
    unsigned short* Crow = C + (size_t)r * Nc;
    float o0[4] = {acc[i][0], acc[i][1], acc[i][2], acc[i][3]};
    float o1[4] = {acc[i][4], acc[i][5], acc[i][6], acc[i][7]};
#pragma unroll
    for (int j = 0; j < 4; ++j) {
      o0[j] += bias[cn0 + j];
      o1[j] += bias[cn0 + 64 + j];
    }
    store4(Crow + cn0, o0);
    store4(Crow + cn0 + 64, o1);
  }
}

// ---------------- attention logits ----------------

__global__ __launch_bounds__(256) void al1_kernel(const unsigned short* __restrict__ x0,
                                                  const float* __restrict__ vs1, const float* __restrict__ vd1,
                                                  float* __restrict__ al_s, float* __restrict__ al_d) {
  int n = blockIdx.x;
  int h = threadIdx.x >> 6;
  int lane = threadIdx.x & 63;
  unsigned v = *(const unsigned*)&x0[(size_t)n * 128 + lane * 2];
  float v0 = bf_lo(v), v1 = bf_hi(v);
  float2 as = *(const float2*)&vs1[h * 128 + lane * 2];
  float2 ad = *(const float2*)&vd1[h * 128 + lane * 2];
  float s = v0 * as.x + v1 * as.y;
  float d = v0 * ad.x + v1 * ad.y;
  for (int off = 32; off; off >>= 1) {
    s += __shfl_down(s, off);
    d += __shfl_down(d, off);
  }
  if (lane == 0) {
    al_s[n * 4 + h] = s;
    al_d[n * 4 + h] = d;
  }
}

__global__ __launch_bounds__(256) void al2_kernel(const unsigned short* __restrict__ hx,
                                                  const float* __restrict__ att_src,
                                                  const float* __restrict__ att_dst,
                                                  float* __restrict__ al_s, float* __restrict__ al_d) {
  int n = blockIdx.x * 4 + (threadIdx.x >> 6);
  int lane = threadIdx.x & 63;
  unsigned v = *(const unsigned*)&hx[(size_t)n * 128 + lane * 2];
  float v0 = bf_lo(v), v1 = bf_hi(v);
  float2 as = *(const float2*)&att_src[lane * 2];
  float2 ad = *(const float2*)&att_dst[lane * 2];
  float s = v0 * as.x + v1 * as.y;
  float d = v0 * ad.x + v1 * ad.y;
  for (int off = 32; off; off >>= 1) {
    s += __shfl_down(s, off);
    d += __shfl_down(d, off);
  }
  if (lane == 0) {
    al_s[n] = s;
    al_d[n] = d;
  }
}

// ---------------- GAT1 aggregation over x0: 4-head weighted gather ----------------

__global__ __launch_bounds__(256) void agg1_kernel(const unsigned short* __restrict__ x0,
                                                   const float* __restrict__ al_s, const float* __restrict__ al_d,
                                                   const int* __restrict__ rowptr, const int* __restrict__ csr_src,
                                                   const float* __restrict__ w1, unsigned short* __restrict__ ybar) {
  int n = blockIdx.x * 4 + (threadIdx.x >> 6);
  int c2 = (threadIdx.x & 63) * 2;
  float4 As4 = *(const float4*)&al_s[n * 4];
  float4 Ad4 = *(const float4*)&al_d[n * 4];
  float w00 = expf(lrelu02(As4.x + Ad4.x));
  float w01 = expf(lrelu02(As4.y + Ad4.y));
  float w02 = expf(lrelu02(As4.z + Ad4.z));
  float w03 = expf(lrelu02(As4.w + Ad4.w));
  unsigned u = *(const unsigned*)&x0[(size_t)n * 128 + c2];
  float lo = bf_lo(u), hi = bf_hi(u);
  float a00 = w00 * lo, a01 = w01 * lo, a02 = w02 * lo, a03 = w03 * lo;
  float a10 = w00 * hi, a11 = w01 * hi, a12 = w02 * hi, a13 = w03 * hi;
  float d0 = w00, d1 = w01, d2 = w02, d3 = w03;
  int p0 = rowptr[n], p1 = rowptr[n + 1];
  int p = p0;
  for (; p + 4 <= p1; p += 4) {
    int s0 = csr_src[p], s1 = csr_src[p + 1], s2 = csr_src[p + 2], s3 = csr_src[p + 3];
    float4 wA = *(const float4*)&w1[(size_t)p * 4];
    float4 wB = *(const float4*)&w1[(size_t)(p + 1) * 4];
    float4 wC = *(const float4*)&w1[(size_t)(p + 2) * 4];
    float4 wD = *(const float4*)&w1[(size_t)(p + 3) * 4];
    unsigned u0 = *(const unsigned*)&x0[(size_t)s0 * 128 + c2];
    unsigned u1 = *(const unsigned*)&x0[(size_t)s1 * 128 + c2];
    unsigned u2 = *(const unsigned*)&x0[(size_t)s2 * 128 + c2];
    unsigned u3 = *(const unsigned*)&x0[(size_t)s3 * 128 + c2];
    float l0 = bf_lo(u0), h0 = bf_hi(u0);
    float l1 = bf_lo(u1), h1 = bf_hi(u1);
    float l2 = bf_lo(u2), h2 = bf_hi(u2);
    float l3 = bf_lo(u3), h3 = bf_hi(u3);
    a00 += wA.x * l0 + wB.x * l1 + wC.x * l2 + wD.x * l3;
    a01 += wA.y * l0 + wB.y * l1 + wC.y * l2 + wD.y * l3;
    a02 += wA.z * l0 + wB.z * l1 + wC.z * l2 + wD.z * l3;
    a03 += wA.w * l0 + wB.w * l1 + wC.w * l2 + wD.w * l3;
    a10 += wA.x * h0 + wB.x * h1 + wC.x * h2 + wD.x * h3;
    a11 += wA.y * h0 + wB.y * h1 + wC.y * h2 + wD.y * h3;
    a12 += wA.z * h0 + wB.z * h1 + wC.z * h2 + wD.z * h3;
    a13 += wA.w * h0 + wB.w * h1 + wC.w * h2 + wD.w * h3;
    d0 += wA.x + wB.x + wC.x + wD.x;
    d1 += wA.y + wB.y + wC.y + wD.y;
    d2 += wA.z + wB.z + wC.z + wD.z;
    d3 += wA.w + wB.w + wC.w + wD.w;
  }
  for (; p < p1; ++p) {
    int s = csr_src[p];
    float4 wA = *(const float4*)&w1[(size_t)p * 4];
    unsigned uu = *(const unsigned*)&x0[(size_t)s * 128 + c2];
    float l = bf_lo(uu), hh = bf_hi(uu);
    a00 += wA.x * l; a01 += wA.y * l; a02 += wA.z * l; a03 += wA.w * l;
    a10 += wA.x * hh; a11 += wA.y * hh; a12 += wA.z * hh; a13 += wA.w * hh;
    d0 += wA.x; d1 += wA.y; d2 += wA.z; d3 += wA.w;
  }
  unsigned short* yb = ybar + (size_t)n * 512 + c2;
  float i0 = 1.f / (d0 + 1e-16f), i1 = 1.f / (d1 + 1e-16f);
  float i2 = 1.f / (d2 + 1e-16f), i3 = 1.f / (d3 + 1e-16f);
  ushort2 o;
  o.x = f2b(a00 * i0); o.y = f2b(a10 * i0); *(ushort2*)(yb + 0) = o;
  o.x = f2b(a01 * i1); o.y = f2b(a11 * i1); *(ushort2*)(yb + 128) = o;
  o.x = f2b(a02 * i2); o.y = f2b(a12 * i2); *(ushort2*)(yb + 256) = o;
  o.x = f2b(a03 * i3); o.y = f2b(a13 * i3); *(ushort2*)(yb + 384) = o;
}

// ---------------- GAT2 aggregation: weighted gather over hx2, 4-deep ILP ----------------

__global__ __launch_bounds__(256) void agg2_kernel(const unsigned short* __restrict__ hx,
                                                   const float* __restrict__ al_s, const float* __restrict__ al_d,
                                                   const int* __restrict__ rowptr, const int* __restrict__ csr_src,
                                                   const float* __restrict__ w2, const float* __restrict__ b2,
                                                   float* __restrict__ out) {
  int n = blockIdx.x * 4 + (threadIdx.x >> 6);
  int c2 = (threadIdx.x & 63) * 2;
  float w0 = expf(lrelu02(al_s[n] + al_d[n]));
  unsigned u = *(const unsigned*)&hx[(size_t)n * 128 + c2];
  float acc0 = w0 * bf_lo(u), acc1 = w0 * bf_hi(u);
  float den = w0;
  int p0 = rowptr[n], p1 = rowptr[n + 1];
  int p = p0;
  for (; p + 4 <= p1; p += 4) {
    int s0 = csr_src[p], s1 = csr_src[p + 1], s2 = csr_src[p + 2], s3 = csr_src[p + 3];
    float wa = w2[p], wb = w2[p + 1], wc = w2[p + 2], wd = w2[p + 3];
    unsigned u0 = *(const unsigned*)&hx[(size_t)s0 * 128 + c2];
    unsigned u1 = *(const unsigned*)&hx[(size_t)s1 * 128 + c2];
    unsigned u2 = *(const unsigned*)&hx[(size_t)s2 * 128 + c2];
    unsigned u3 = *(const unsigned*)&hx[(size_t)s3 * 128 + c2];
    acc0 += wa * bf_lo(u0) + wb * bf_lo(u1) + wc * bf_lo(u2) + wd * bf_lo(u3);
    acc1 += wa * bf_hi(u0) + wb * bf_hi(u1) + wc * bf_hi(u2) + wd * bf_hi(u3);
    den += wa + wb + wc + wd;
  }
  for (; p < p1; ++p) {
    int s = csr_src[p];
    float w = w2[p];
    unsigned uu = *(const unsigned*)&hx[(size_t)s * 128 + c2];
    acc0 += w * bf_lo(uu);
    acc1 += w * bf_hi(uu);
    den += w;
  }
  float inv = 1.f / (den + 1e-16f);
  float2 o;
  o.x = acc0 * inv + b2[c2];
  o.y = acc1 * inv + b2[c2 + 1];
  *(float2*)&out[(size_t)n * 128 + c2] = o;
}

// ---------------- mean-pool + classifier MLP ----------------

__global__ __launch_bounds__(128) void poolcls_kernel(const float* __restrict__ x, const float* __restrict__ Wc1,
                                                      const float* __restrict__ bc1, const float* __restrict__ Wc2,
                                                      const float* __restrict__ bc2, float* __restrict__ out) {
  __shared__ float g[128];
  __shared__ float hcls[64];
  int b = blockIdx.x;
  int t = threadIdx.x;
  const float* base = x + (size_t)b * FPG * 128;
  float s = 0.f;
#pragma unroll
  for (int i = 0; i < FPG; ++i) s += base[i * 128 + t];
  g[t] = s * (1.0f / FPG);
  __syncthreads();
  if (t < 64) {
    float a = bc1[t];
#pragma unroll 4
    for (int k = 0; k < 128; ++k) a += g[k] * Wc1[k * 64 + t];
    hcls[t] = a > 0.f ? a : 0.01f * a;
  }
  __syncthreads();
  if (t < 10) {
    float a = bc2[t];
#pragma unroll
    for (int k = 0; k < 64; ++k) a += hcls[k] * Wc2[k * 10 + t];
    out[b * 10 + t] = a;
  }
}

}  // namespace

extern "C" void kernel_launch(void* const* d_in, const int* in_sizes, int n_in,
                              void* d_out, int out_size, void* d_ws, size_t ws_size,
                              hipStream_t stream) {
  const float* emb = (const float*)d_in[0];
  const int* edge = (const int*)d_in[1];
  // d_in[2] = batch = arange(N)//FPG -> exploited structurally in poolcls
  const float* W_align = (const float*)d_in[3];
  const float* b_align = (const float*)d_in[4];
  const float* W1 = (const float*)d_in[5];
  const float* att_src1 = (const float*)d_in[6];
  const float* att_dst1 = (const float*)d_in[7];
  const float* b1 = (const float*)d_in[8];
  const float* W2 = (const float*)d_in[9];
  const float* att_src2 = (const float*)d_in[10];
  const float* att_dst2 = (const float*)d_in[11];
  const float* b2 = (const float*)d_in[12];
  const float* Wc1 = (const float*)d_in[13];
  const float* bc1 = (const float*)d_in[14];
  const float* Wc2 = (const float*)d_in[15];
  const float* bc2 = (const float*)d_in[16];

  // workspace bump allocator (256B aligned). Peak ~143 MB.
  char* ws = (char*)d_ws;
  size_t off = 0;
  auto alloc = [&](size_t bytes) -> char* {
    char* p = ws + off;
    off += (bytes + 255) & ~(size_t)255;
    return p;
  };
  unsigned short* x0 = (unsigned short*)alloc((size_t)NNODE * 128 * 2);    // aligned x, bf16
  unsigned short* ybar = (unsigned short*)alloc((size_t)NNODE * 512 * 2);  // agg1 out, bf16
  unsigned short* hx2 = (unsigned short*)alloc((size_t)NNODE * 128 * 2);   // fused12 out, bf16
  float* out2 = (float*)alloc((size_t)NNODE * 128 * 4);                    // GAT2 out, f32
  float* al_s1 = (float*)alloc((size_t)NNODE * 4 * 4);
  float* al_d1 = (float*)alloc((size_t)NNODE * 4 * 4);
  float* al_s2 = (float*)alloc((size_t)NNODE * 4);
  float* al_d2 = (float*)alloc((size_t)NNODE * 4);
  int* deg = (int*)alloc((size_t)NNODE * 4);
  int* rowptr = (int*)alloc((size_t)(NNODE + 1) * 4);
  int* cursor = (int*)alloc((size_t)NNODE * 4);
  int* csr_src = (int*)alloc((size_t)NEDGE * 4);
  int* csr_dst = (int*)alloc((size_t)NEDGE * 4);
  float* w1 = (float*)alloc((size_t)NEDGE * 4 * 4);
  float* w2 = (float*)alloc((size_t)NEDGE * 4);
  unsigned short* w1t = (unsigned short*)alloc((size_t)512 * 128 * 2);  // W1^T bf16 [512][128]
  unsigned short* w2t = (unsigned short*)alloc((size_t)128 * 512 * 2);  // W2^T bf16 [128][512]
  float* vs1 = (float*)alloc((size_t)512 * 4);
  float* vd1 = (float*)alloc((size_t)512 * 4);

  const int* src = edge;
  const int* dst = edge + NEDGE;

  // CSR by dst (shared by both GAT layers) + weight conversion + att pre-transform
  hipMemsetAsync(deg, 0, (size_t)NNODE * 4, stream);
  hist_kernel<<<NEDGE / 256, 256, 0, stream>>>(dst, deg);
  scan_kernel<<<1, 1024, 0, stream>>>(deg, rowptr, cursor);
  scatter_kernel<<<NEDGE / 256, 256, 0, stream>>>(src, dst, cursor, csr_src, csr_dst);
  convw_kernel<<<256, 256, 0, stream>>>(W1, w1t, 128, 512);
  convw_kernel<<<256, 256, 0, stream>>>(W2, w2t, 512, 128);
  attv1_kernel<<<2, 256, 0, stream>>>(W1, att_src1, att_dst1, vs1, vd1);

  // aligner: x0 = emb @ W_align + b_align   [65536,64]@[64,128] -> bf16
  gemm_align_kernel<<<dim3(NNODE / 128, 1), 256, 0, stream>>>(emb, W_align, x0, b_align, 128, 64);
  // GAT1 logits from x0 directly (al = x0 · (W1 @ att))
  al1_kernel<<<NNODE, 256, 0, stream>>>(x0, vs1, vd1, al_s1, al_d1);
  edgew1_kernel<<<NEDGE / 256, 256, 0, stream>>>(csr_src, csr_dst, al_s1, al_d1, w1);
  // GAT1 aggregate-first: ybar[n,h,:] = softmax-weighted mean of x0 rows
  agg1_kernel<<<NNODE / 4, 256, 0, stream>>>(x0, al_s1, al_d1, rowptr, csr_src, w1, ybar);
  // fused: hx2 = elu(ybar @blockdiag W1 + b1) @ W2   (x1 stays in LDS)
  fused12_kernel<<<512, 256, 0, stream>>>(ybar, w1t, w2t, b1, hx2);
  al2_kernel<<<NNODE / 4, 256, 0, stream>>>(hx2, att_src2, att_dst2, al_s2, al_d2);
  edgew2_kernel<<<NEDGE / 256, 256, 0, stream>>>(csr_src, csr_dst, al_s2, al_d2, w2);
  agg2_kernel<<<NNODE / 4, 256, 0, stream>>>(hx2, al_s2, al_d2, rowptr, csr_src, w2, b2, out2);
  // pool + classifier
  poolcls_kernel<<<NGRAPH, 128, 0, stream>>>(out2, Wc1, bc1, Wc2, bc2, (float*)d_out);
}

// Round 9
// 263.566 us; speedup vs baseline: 2.2287x; 1.1799x over previous
//
#include <hip/hip_runtime.h>

// ProtocolTreeGAttention: aligner Linear -> GAT(128->128,H=4,concat) -> ELU ->
// GAT(512->128,H=1) -> mean-pool -> MLP classifier.
// Round 9: fused12 v2 — stage1->stage2 handoff entirely in registers (bias+ELU+
// bf16 convert on acc1 fragments), staging via global_load_lds with pre-swizzled
// per-lane source addresses. 4 barriers/head (was 8), no Xs LDS tile.

namespace {

constexpr int NNODE = 65536;   // B*F
constexpr int NEDGE = 262144;
constexpr int NGRAPH = 2048;
constexpr int FPG = 32;

typedef __attribute__((ext_vector_type(8))) short bf16x8;
typedef __attribute__((ext_vector_type(4))) float f32x4;

__device__ __forceinline__ float lrelu02(float x) { return x > 0.f ? x : 0.2f * x; }
__device__ __forceinline__ float bf_lo(unsigned u) { return __uint_as_float(u << 16); }
__device__ __forceinline__ float bf_hi(unsigned u) { return __uint_as_float(u & 0xffff0000u); }
__device__ __forceinline__ unsigned short f2b(float f) {  // RNE bf16 round
  unsigned u = __float_as_uint(f);
  return (unsigned short)((u + 0x7fffu + ((u >> 16) & 1u)) >> 16);
}

__device__ __forceinline__ void load8(const float* p, float o[8]) {
  float4 a = *(const float4*)p;
  float4 b = *(const float4*)(p + 4);
  o[0] = a.x; o[1] = a.y; o[2] = a.z; o[3] = a.w;
  o[4] = b.x; o[5] = b.y; o[6] = b.z; o[7] = b.w;
}
__device__ __forceinline__ void store4(unsigned short* p, const float v[4]) {
  ushort4 o; o.x = f2b(v[0]); o.y = f2b(v[1]); o.z = f2b(v[2]); o.w = f2b(v[3]);
  *(ushort4*)p = o;
}

// async global->LDS, 16B per lane; LDS dest is wave-uniform base + lane*16.
__device__ __forceinline__ void gload16(const void* g, unsigned short* l) {
  __builtin_amdgcn_global_load_lds((const __attribute__((address_space(1))) void*)g,
                                   (__attribute__((address_space(3))) void*)l, 16, 0, 0);
}

// ---------------- CSR build ----------------

__global__ __launch_bounds__(256) void hist_kernel(const int* __restrict__ dst, int* __restrict__ deg) {
  int e = blockIdx.x * 256 + threadIdx.x;
  if (e < NEDGE) atomicAdd(&deg[dst[e]], 1);
}

__global__ __launch_bounds__(1024) void scan_kernel(const int* __restrict__ deg, int* __restrict__ rowptr,
                                                    int* __restrict__ cursor) {
  __shared__ int sums[1024];
  int t = threadIdx.x;
  int base = t * 64;
  int s = 0;
  for (int i = 0; i < 64; ++i) s += deg[base + i];
  sums[t] = s;
  __syncthreads();
  for (int off = 1; off < 1024; off <<= 1) {
    int v = (t >= off) ? sums[t - off] : 0;
    __syncthreads();
    sums[t] += v;
    __syncthreads();
  }
  int run = (t == 0) ? 0 : sums[t - 1];
  for (int i = 0; i < 64; ++i) {
    rowptr[base + i] = run;
    cursor[base + i] = run;
    run += deg[base + i];
  }
  if (t == 1023) rowptr[NNODE] = run;
}

__global__ __launch_bounds__(256) void scatter_kernel(const int* __restrict__ src, const int* __restrict__ dst,
                                                      int* __restrict__ cursor, int* __restrict__ csr_src,
                                                      int* __restrict__ csr_dst) {
  int e = blockIdx.x * 256 + threadIdx.x;
  if (e < NEDGE) {
    int s = src[e], d = dst[e];
    int p = atomicAdd(&cursor[d], 1);
    csr_src[p] = s;
    csr_dst[p] = d;
  }
}

// ---------------- weight convert: Wt[n][k] = bf16(W[k][n]) ----------------

__global__ __launch_bounds__(256) void convw_kernel(const float* __restrict__ W, unsigned short* __restrict__ Wt,
                                                    int K, int N) {
  int idx = blockIdx.x * 256 + threadIdx.x;
  if (idx >= K * N) return;
  int n = idx / K, k = idx - n * K;
  Wt[idx] = f2b(W[(size_t)k * N + n]);
}

// ---------------- pre-transformed GAT1 attention vectors ----------------

__global__ __launch_bounds__(256) void attv1_kernel(const float* __restrict__ W1, const float* __restrict__ as1,
                                                    const float* __restrict__ ad1, float* __restrict__ vs1,
                                                    float* __restrict__ vd1) {
  int idx = blockIdx.x * 256 + threadIdx.x;  // 0..511
  int h = idx >> 7, c = idx & 127;
  float s = 0.f, d = 0.f;
  const float* wrow = W1 + (size_t)c * 512 + h * 128;
  const float* ar = as1 + h * 128;
  const float* dr = ad1 + h * 128;
  for (int j = 0; j < 128; ++j) {
    float w = wrow[j];
    s += w * ar[j];
    d += w * dr[j];
  }
  vs1[idx] = s;
  vd1[idx] = d;
}

// ---------------- per-edge attention weights (CSR order) ----------------

__global__ __launch_bounds__(256) void edgew1_kernel(const int* __restrict__ csr_src, const int* __restrict__ csr_dst,
                                                     const float* __restrict__ al_s, const float* __restrict__ al_d,
                                                     float* __restrict__ w1) {
  int p = blockIdx.x * 256 + threadIdx.x;
  if (p >= NEDGE) return;
  int s = csr_src[p], d = csr_dst[p];
  float4 as = *(const float4*)&al_s[s * 4];
  float4 ad = *(const float4*)&al_d[d * 4];
  float4 w;
  w.x = expf(lrelu02(as.x + ad.x));
  w.y = expf(lrelu02(as.y + ad.y));
  w.z = expf(lrelu02(as.z + ad.z));
  w.w = expf(lrelu02(as.w + ad.w));
  *(float4*)&w1[(size_t)p * 4] = w;
}

__global__ __launch_bounds__(256) void edgew2_kernel(const int* __restrict__ csr_src, const int* __restrict__ csr_dst,
                                                     const float* __restrict__ al_s, const float* __restrict__ al_d,
                                                     float* __restrict__ w2) {
  int p = blockIdx.x * 256 + threadIdx.x;
  if (p >= NEDGE) return;
  w2[p] = expf(lrelu02(al_s[csr_src[p]] + al_d[csr_dst[p]]));
}

// ---------------- LDS fragment loader ([*][128] bf16 tile, XOR-swizzled) ----------------
// frag layout (m91-verified): lane&15 = row index; k = (lane>>4)*4 + (j&3) + 16*(j>>2).

__device__ __forceinline__ bf16x8 frag_ld_x(const unsigned short* lds, int row, int kbyte) {
  const char* base = (const char*)lds + row * 256;
  int sw = (row & 7) << 4;
  uint2 lo = *(const uint2*)(base + (kbyte ^ sw));
  uint2 hi = *(const uint2*)(base + ((kbyte + 32) ^ sw));
  union { bf16x8 v; uint2 u2[2]; } f;
  f.u2[0] = lo;
  f.u2[1] = hi;
  return f.v;
}

// ---------------- fused GAT1-transform + GAT2-transform (v2) ----------------
// Per block: 128 node rows; 4 waves, wave w owns m-rows [w*32, w*32+32).
// Per head h:
//   stage1: acc1[ct][mf] = mfma(W1t_h c-frag, ybar m-frag): lane holds
//           c = ct*16+lg*4+r, m = w*32+mf*16+ln  -> FULL c range per wave.
//   convert: af2[j] = bf16(elu(acc1[2*kw+(j>=4)][mf][j&3] + b1))  (registers only)
//   stage2: acc2[mf][nf] += mfma(af2, W2t n-frag) over this head's 128 k.
// Staging via global_load_lds with XOR-pre-swizzled source columns.

__global__ __launch_bounds__(256, 2) void fused12_kernel(const unsigned short* __restrict__ ybar,
                                                         const unsigned short* __restrict__ w1t,
                                                         const unsigned short* __restrict__ w2t,
                                                         const float* __restrict__ b1,
                                                         unsigned short* __restrict__ hx2) {
  __shared__ char smem[65536];
  unsigned short* Ws = (unsigned short*)smem;  // [128][128] bf16: W1t_h, then W2t_h-slice
  unsigned short* Ys = Ws + 16384;             // [128][128] bf16: ybar head panel

  const int tid = threadIdx.x;
  const int lane = tid & 63;
  const int w = tid >> 6;  // wave id; m-rows [w*32, w*32+32)
  const size_t bm = (size_t)blockIdx.x * 128;

  const int ln = lane & 15, lg = lane >> 4;
  const int kb0 = lg << 3;

  // staging geometry: per wave instruction i, lane l deposits 16B at
  // LDS row (w*32 + i*4 + (l>>4)), byte (l&15)*16; source column pre-XORed.
  const int drow = (lane >> 4);            // 0..3
  const int dcol = (lane & 15) << 4;       // byte 0..240

  f32x4 zero = {0.f, 0.f, 0.f, 0.f};
  f32x4 acc2[2][8];
#pragma unroll
  for (int i = 0; i < 2; ++i)
#pragma unroll
    for (int j = 0; j < 8; ++j) acc2[i][j] = zero;

  for (int h = 0; h < 4; ++h) {
    if (h) __syncthreads();  // prev stage2 done reading Ws; Ys free since prev stage1
    // ---- stage Ws = W1t_h [128 c][128 k], Ys = ybar[bm..bm+127][h*128..+128) ----
#pragma unroll
    for (int i = 0; i < 8; ++i) {
      int row = w * 32 + i * 4 + drow;
      int bcol = dcol ^ ((row & 7) << 4);
      gload16((const char*)w1t + ((size_t)(h * 128 + row) << 8) + bcol, Ws + w * 4096 + i * 512);
      gload16((const char*)ybar + ((bm + row) << 10) + (h << 8) + bcol, Ys + w * 4096 + i * 512);
    }
    __syncthreads();  // vmcnt drained by compiler before barrier -> tiles ready

    // ---- stage1: 64 MFMA/wave, uninterrupted ----
    f32x4 acc1[8][2];
#pragma unroll
    for (int i = 0; i < 8; ++i) {
      acc1[i][0] = zero;
      acc1[i][1] = zero;
    }
#pragma unroll
    for (int kw = 0; kw < 4; ++kw) {
      bf16x8 bfr0 = frag_ld_x(Ys, w * 32 + ln, kw * 64 + kb0);
      bf16x8 bfr1 = frag_ld_x(Ys, w * 32 + 16 + ln, kw * 64 + kb0);
#pragma unroll
      for (int ct = 0; ct < 8; ++ct) {
        bf16x8 af = frag_ld_x(Ws, ct * 16 + ln, kw * 64 + kb0);
        acc1[ct][0] = __builtin_amdgcn_mfma_f32_16x16x32_bf16(af, bfr0, acc1[ct][0], 0, 0, 0);
        acc1[ct][1] = __builtin_amdgcn_mfma_f32_16x16x32_bf16(af, bfr1, acc1[ct][1], 0, 0, 0);
      }
    }
    __syncthreads();  // all waves done reading Ws (W1t_h)

    // ---- stage Ws = W2t[0..127][h*128..+128) ----
#pragma unroll
    for (int i = 0; i < 8; ++i) {
      int row = w * 32 + i * 4 + drow;
      int bcol = dcol ^ ((row & 7) << 4);
      gload16((const char*)w2t + ((size_t)row << 10) + (h << 8) + bcol, Ws + w * 4096 + i * 512);
    }
    __syncthreads();

    // ---- stage2: register convert (bias+ELU+bf16) then 64 MFMA/wave ----
#pragma unroll
    for (int kw = 0; kw < 4; ++kw) {
      float4 b_lo = *(const float4*)&b1[h * 128 + kw * 32 + lg * 4];
      float4 b_hi = *(const float4*)&b1[h * 128 + kw * 32 + 16 + lg * 4];
      bf16x8 af2[2];
#pragma unroll
      for (int mf = 0; mf < 2; ++mf) {
        union { bf16x8 v; unsigned short u[8]; } t;
#pragma unroll
        for (int r = 0; r < 4; ++r) {
          float vlo = acc1[2 * kw][mf][r] + ((const float*)&b_lo)[r];
          float vhi = acc1[2 * kw + 1][mf][r] + ((const float*)&b_hi)[r];
          vlo = vlo > 0.f ? vlo : __expf(vlo) - 1.f;
          vhi = vhi > 0.f ? vhi : __expf(vhi) - 1.f;
          t.u[r] = f2b(vlo);
          t.u[4 + r] = f2b(vhi);
        }
        af2[mf] = t.v;
      }
#pragma unroll
      for (int nf = 0; nf < 8; ++nf) {
        bf16x8 bfr = frag_ld_x(Ws, nf * 16 + ln, kw * 64 + kb0);
        acc2[0][nf] = __builtin_amdgcn_mfma_f32_16x16x32_bf16(af2[0], bfr, acc2[0][nf], 0, 0, 0);
        acc2[1][nf] = __builtin_amdgcn_mfma_f32_16x16x32_bf16(af2[1], bfr, acc2[1][nf], 0, 0, 0);
      }
    }
  }

  // ---- epilogue: acc2 -> bf16 LDS C-stage [128][136] -> full-line stores ----
  __syncthreads();
  unsigned short* Cs = (unsigned short*)smem;
#pragma unroll
  for (int mf = 0; mf < 2; ++mf) {
#pragma unroll
    for (int r = 0; r < 4; ++r) {
      unsigned short* rp = Cs + (w * 32 + mf * 16 + lg * 4 + r) * 136 + ln;
#pragma unroll
      for (int nf = 0; nf < 8; ++nf) rp[nf * 16] = f2b(acc2[mf][nf][r]);
    }
  }
  __syncthreads();
  const int r16 = tid >> 4;
  const int cchunk = (tid & 15) * 8;
#pragma unroll
  for (int it = 0; it < 8; ++it) {
    int row = it * 16 + r16;
    *(uint4*)(hx2 + (bm + row) * 128 + cchunk) = *(const uint4*)(Cs + row * 136 + cchunk);
  }
}

// ---------------- vector GEMM (aligner only): C = A[M x K] @ B[K x Nc] + bias ----------------

__global__ __launch_bounds__(256) void gemm_align_kernel(const float* __restrict__ A, const float* __restrict__ B,
                                                         unsigned short* __restrict__ C, const float* __restrict__ bias,
                                                         int Nc, int K) {
  __shared__ float Asm[16][132];
  __shared__ float Bsm[16][132];
  const int tid = threadIdx.x;
  const int tx = tid & 15, ty = tid >> 4;
  const int bm = blockIdx.x, bn = blockIdx.y;
  const int m_l = tid >> 1;
  const int kh = (tid & 1) * 8;
  const int kb = tid >> 4;
  const int nq = (tid & 15) * 8;
  const float* Ap = A + (size_t)(bm * 128 + m_l) * K + kh;
  const float* Bp = B + (size_t)kb * Nc + bn * 128 + nq;

  float acc[8][8];
#pragma unroll
  for (int i = 0; i < 8; ++i)
#pragma unroll
    for (int j = 0; j < 8; ++j) acc[i][j] = 0.f;

  const int ksteps = K / 16;
  for (int t = 0; t < ksteps; ++t) {
    float av8[8], bv8[8];
    load8(Ap + t * 16, av8);
    load8(Bp + (size_t)t * 16 * Nc, bv8);
    __syncthreads();
#pragma unroll
    for (int q = 0; q < 8; ++q) Asm[kh + q][m_l] = av8[q];
    *(float4*)&Bsm[kb][nq] = *(float4*)&bv8[0];
    *(float4*)&Bsm[kb][nq + 4] = *(float4*)&bv8[4];
    __syncthreads();
#pragma unroll
    for (int kk = 0; kk < 16; ++kk) {
      float4 av0 = *(const float4*)&Asm[kk][ty * 4];
      float4 av1 = *(const float4*)&Asm[kk][64 + ty * 4];
      float4 bv0 = *(const float4*)&Bsm[kk][tx * 4];
      float4 bv1 = *(const float4*)&Bsm[kk][64 + tx * 4];
      float av[8] = {av0.x, av0.y, av0.z, av0.w, av1.x, av1.y, av1.z, av1.w};
      float bv[8] = {bv0.x, bv0.y, bv0.z, bv0.w, bv1.x, bv1.y, bv1.z, bv1.w};
#pragma unroll
      for (int i = 0; i < 8; ++i)
#pragma unroll
        for (int j = 0; j < 8; ++j) acc[i][j] += av[i] * bv[j];
    }
  }

  const int cn0 = bn * 128 + tx * 4;
#pragma unroll
  for (int i = 0; i < 8; ++i) {
    int r = bm * 128 + ((i < 4) ? (ty * 4 + i) : (64 + ty * 4 + i - 4));
    unsigned short* Crow = C + (size_t)r * Nc;
    float o0[4] = {acc[i][0], acc[i][1], acc[i][2], acc[i][3]};
    float o1[4] = {acc[i][4], acc[i][5], acc[i][6], acc[i][7]};
#pragma unroll
    for (int j = 0; j < 4; ++j) {
      o0[j] += bias[cn0 + j];
      o1[j] += bias[cn0 + 64 + j];
    }
    store4(Crow + cn0, o0);
    store4(Crow + cn0 + 64, o1);
  }
}

// ---------------- attention logits ----------------

__global__ __launch_bounds__(256) void al1_kernel(const unsigned short* __restrict__ x0,
                                                  const float* __restrict__ vs1, const float* __restrict__ vd1,
                                                  float* __restrict__ al_s, float* __restrict__ al_d) {
  int n = blockIdx.x;
  int h = threadIdx.x >> 6;
  int lane = threadIdx.x & 63;
  unsigned v = *(const unsigned*)&x0[(size_t)n * 128 + lane * 2];
  float v0 = bf_lo(v), v1 = bf_hi(v);
  float2 as = *(const float2*)&vs1[h * 128 + lane * 2];
  float2 ad = *(const float2*)&vd1[h * 128 + lane * 2];
  float s = v0 * as.x + v1 * as.y;
  float d = v0 * ad.x + v1 * ad.y;
  for (int off = 32; off; off >>= 1) {
    s += __shfl_down(s, off);
    d += __shfl_down(d, off);
  }
  if (lane == 0) {
    al_s[n * 4 + h] = s;
    al_d[n * 4 + h] = d;
  }
}

__global__ __launch_bounds__(256) void al2_kernel(const unsigned short* __restrict__ hx,
                                                  const float* __restrict__ att_src,
                                                  const float* __restrict__ att_dst,
                                                  float* __restrict__ al_s, float* __restrict__ al_d) {
  int n = blockIdx.x * 4 + (threadIdx.x >> 6);
  int lane = threadIdx.x & 63;
  unsigned v = *(const unsigned*)&hx[(size_t)n * 128 + lane * 2];
  float v0 = bf_lo(v), v1 = bf_hi(v);
  float2 as = *(const float2*)&att_src[lane * 2];
  float2 ad = *(const float2*)&att_dst[lane * 2];
  float s = v0 * as.x + v1 * as.y;
  float d = v0 * ad.x + v1 * ad.y;
  for (int off = 32; off; off >>= 1) {
    s += __shfl_down(s, off);
    d += __shfl_down(d, off);
  }
  if (lane == 0) {
    al_s[n] = s;
    al_d[n] = d;
  }
}

// ---------------- GAT1 aggregation over x0: 4-head weighted gather ----------------

__global__ __launch_bounds__(256) void agg1_kernel(const unsigned short* __restrict__ x0,
                                                   const float* __restrict__ al_s, const float* __restrict__ al_d,
                                                   const int* __restrict__ rowptr, const int* __restrict__ csr_src,
                                                   const float* __restrict__ w1, unsigned short* __restrict__ ybar) {
  int n = blockIdx.x * 4 + (threadIdx.x >> 6);
  int c2 = (threadIdx.x & 63) * 2;
  float4 As4 = *(const float4*)&al_s[n * 4];
  float4 Ad4 = *(const float4*)&al_d[n * 4];
  float w00 = expf(lrelu02(As4.x + Ad4.x));
  float w01 = expf(lrelu02(As4.y + Ad4.y));
  float w02 = expf(lrelu02(As4.z + Ad4.z));
  float w03 = expf(lrelu02(As4.w + Ad4.w));
  unsigned u = *(const unsigned*)&x0[(size_t)n * 128 + c2];
  float lo = bf_lo(u), hi = bf_hi(u);
  float a00 = w00 * lo, a01 = w01 * lo, a02 = w02 * lo, a03 = w03 * lo;
  float a10 = w00 * hi, a11 = w01 * hi, a12 = w02 * hi, a13 = w03 * hi;
  float d0 = w00, d1 = w01, d2 = w02, d3 = w03;
  int p0 = rowptr[n], p1 = rowptr[n + 1];
  int p = p0;
  for (; p + 4 <= p1; p += 4) {
    int s0 = csr_src[p], s1 = csr_src[p + 1], s2 = csr_src[p + 2], s3 = csr_src[p + 3];
    float4 wA = *(const float4*)&w1[(size_t)p * 4];
    float4 wB = *(const float4*)&w1[(size_t)(p + 1) * 4];
    float4 wC = *(const float4*)&w1[(size_t)(p + 2) * 4];
    float4 wD = *(const float4*)&w1[(size_t)(p + 3) * 4];
    unsigned u0 = *(const unsigned*)&x0[(size_t)s0 * 128 + c2];
    unsigned u1 = *(const unsigned*)&x0[(size_t)s1 * 128 + c2];
    unsigned u2 = *(const unsigned*)&x0[(size_t)s2 * 128 + c2];
    unsigned u3 = *(const unsigned*)&x0[(size_t)s3 * 128 + c2];
    float l0 = bf_lo(u0), h0 = bf_hi(u0);
    float l1 = bf_lo(u1), h1 = bf_hi(u1);
    float l2 = bf_lo(u2), h2 = bf_hi(u2);
    float l3 = bf_lo(u3), h3 = bf_hi(u3);
    a00 += wA.x * l0 + wB.x * l1 + wC.x * l2 + wD.x * l3;
    a01 += wA.y * l0 + wB.y * l1 + wC.y * l2 + wD.y * l3;
    a02 += wA.z * l0 + wB.z * l1 + wC.z * l2 + wD.z * l3;
    a03 += wA.w * l0 + wB.w * l1 + wC.w * l2 + wD.w * l3;
    a10 += wA.x * h0 + wB.x * h1 + wC.x * h2 + wD.x * h3;
    a11 += wA.y * h0 + wB.y * h1 + wC.y * h2 + wD.y * h3;
    a12 += wA.z * h0 + wB.z * h1 + wC.z * h2 + wD.z * h3;
    a13 += wA.w * h0 + wB.w * h1 + wC.w * h2 + wD.w * h3;
    d0 += wA.x + wB.x + wC.x + wD.x;
    d1 += wA.y + wB.y + wC.y + wD.y;
    d2 += wA.z + wB.z + wC.z + wD.z;
    d3 += wA.w + wB.w + wC.w + wD.w;
  }
  for (; p < p1; ++p) {
    int s = csr_src[p];
    float4 wA = *(const float4*)&w1[(size_t)p * 4];
    unsigned uu = *(const unsigned*)&x0[(size_t)s * 128 + c2];
    float l = bf_lo(uu), hh = bf_hi(uu);
    a00 += wA.x * l; a01 += wA.y * l; a02 += wA.z * l; a03 += wA.w * l;
    a10 += wA.x * hh; a11 += wA.y * hh; a12 += wA.z * hh; a13 += wA.w * hh;
    d0 += wA.x; d1 += wA.y; d2 += wA.z; d3 += wA.w;
  }
  unsigned short* yb = ybar + (size_t)n * 512 + c2;
  float i0 = 1.f / (d0 + 1e-16f), i1 = 1.f / (d1 + 1e-16f);
  float i2 = 1.f / (d2 + 1e-16f), i3 = 1.f / (d3 + 1e-16f);
  ushort2 o;
  o.x = f2b(a00 * i0); o.y = f2b(a10 * i0); *(ushort2*)(yb + 0) = o;
  o.x = f2b(a01 * i1); o.y = f2b(a11 * i1); *(ushort2*)(yb + 128) = o;
  o.x = f2b(a02 * i2); o.y = f2b(a12 * i2); *(ushort2*)(yb + 256) = o;
  o.x = f2b(a03 * i3); o.y = f2b(a13 * i3); *(ushort2*)(yb + 384) = o;
}

// ---------------- GAT2 aggregation: weighted gather over hx2, 4-deep ILP ----------------

__global__ __launch_bounds__(256) void agg2_kernel(const unsigned short* __restrict__ hx,
                                                   const float* __restrict__ al_s, const float* __restrict__ al_d,
                                                   const int* __restrict__ rowptr, const int* __restrict__ csr_src,
                                                   const float* __restrict__ w2, const float* __restrict__ b2,
                                                   float* __restrict__ out) {
  int n = blockIdx.x * 4 + (threadIdx.x >> 6);
  int c2 = (threadIdx.x & 63) * 2;
  float w0 = expf(lrelu02(al_s[n] + al_d[n]));
  unsigned u = *(const unsigned*)&hx[(size_t)n * 128 + c2];
  float acc0 = w0 * bf_lo(u), acc1 = w0 * bf_hi(u);
  float den = w0;
  int p0 = rowptr[n], p1 = rowptr[n + 1];
  int p = p0;
  for (; p + 4 <= p1; p += 4) {
    int s0 = csr_src[p], s1 = csr_src[p + 1], s2 = csr_src[p + 2], s3 = csr_src[p + 3];
    float wa = w2[p], wb = w2[p + 1], wc = w2[p + 2], wd = w2[p + 3];
    unsigned u0 = *(const unsigned*)&hx[(size_t)s0 * 128 + c2];
    unsigned u1 = *(const unsigned*)&hx[(size_t)s1 * 128 + c2];
    unsigned u2 = *(const unsigned*)&hx[(size_t)s2 * 128 + c2];
    unsigned u3 = *(const unsigned*)&hx[(size_t)s3 * 128 + c2];
    acc0 += wa * bf_lo(u0) + wb * bf_lo(u1) + wc * bf_lo(u2) + wd * bf_lo(u3);
    acc1 += wa * bf_hi(u0) + wb * bf_hi(u1) + wc * bf_hi(u2) + wd * bf_hi(u3);
    den += wa + wb + wc + wd;
  }
  for (; p < p1; ++p) {
    int s = csr_src[p];
    float w = w2[p];
    unsigned uu = *(const unsigned*)&hx[(size_t)s * 128 + c2];
    acc0 += w * bf_lo(uu);
    acc1 += w * bf_hi(uu);
    den += w;
  }
  float inv = 1.f / (den + 1e-16f);
  float2 o;
  o.x = acc0 * inv + b2[c2];
  o.y = acc1 * inv + b2[c2 + 1];
  *(float2*)&out[(size_t)n * 128 + c2] = o;
}

// ---------------- mean-pool + classifier MLP ----------------

__global__ __launch_bounds__(128) void poolcls_kernel(const float* __restrict__ x, const float* __restrict__ Wc1,
                                                      const float* __restrict__ bc1, const float* __restrict__ Wc2,
                                                      const float* __restrict__ bc2, float* __restrict__ out) {
  __shared__ float g[128];
  __shared__ float hcls[64];
  int b = blockIdx.x;
  int t = threadIdx.x;
  const float* base = x + (size_t)b * FPG * 128;
  float s = 0.f;
#pragma unroll
  for (int i = 0; i < FPG; ++i) s += base[i * 128 + t];
  g[t] = s * (1.0f / FPG);
  __syncthreads();
  if (t < 64) {
    float a = bc1[t];
#pragma unroll 4
    for (int k = 0; k < 128; ++k) a += g[k] * Wc1[k * 64 + t];
    hcls[t] = a > 0.f ? a : 0.01f * a;
  }
  __syncthreads();
  if (t < 10) {
    float a = bc2[t];
#pragma unroll
    for (int k = 0; k < 64; ++k) a += hcls[k] * Wc2[k * 10 + t];
    out[b * 10 + t] = a;
  }
}

}  // namespace

extern "C" void kernel_launch(void* const* d_in, const int* in_sizes, int n_in,
                              void* d_out, int out_size, void* d_ws, size_t ws_size,
                              hipStream_t stream) {
  const float* emb = (const float*)d_in[0];
  const int* edge = (const int*)d_in[1];
  // d_in[2] = batch = arange(N)//FPG -> exploited structurally in poolcls
  const float* W_align = (const float*)d_in[3];
  const float* b_align = (const float*)d_in[4];
  const float* W1 = (const float*)d_in[5];
  const float* att_src1 = (const float*)d_in[6];
  const float* att_dst1 = (const float*)d_in[7];
  const float* b1 = (const float*)d_in[8];
  const float* W2 = (const float*)d_in[9];
  const float* att_src2 = (const float*)d_in[10];
  const float* att_dst2 = (const float*)d_in[11];
  const float* b2 = (const float*)d_in[12];
  const float* Wc1 = (const float*)d_in[13];
  const float* bc1 = (const float*)d_in[14];
  const float* Wc2 = (const float*)d_in[15];
  const float* bc2 = (const float*)d_in[16];

  // workspace bump allocator (256B aligned). Peak ~143 MB.
  char* ws = (char*)d_ws;
  size_t off = 0;
  auto alloc = [&](size_t bytes) -> char* {
    char* p = ws + off;
    off += (bytes + 255) & ~(size_t)255;
    return p;
  };
  unsigned short* x0 = (unsigned short*)alloc((size_t)NNODE * 128 * 2);    // aligned x, bf16
  unsigned short* ybar = (unsigned short*)alloc((size_t)NNODE * 512 * 2);  // agg1 out, bf16
  unsigned short* hx2 = (unsigned short*)alloc((size_t)NNODE * 128 * 2);   // fused12 out, bf16
  float* out2 = (float*)alloc((size_t)NNODE * 128 * 4);                    // GAT2 out, f32
  float* al_s1 = (float*)alloc((size_t)NNODE * 4 * 4);
  float* al_d1 = (float*)alloc((size_t)NNODE * 4 * 4);
  float* al_s2 = (float*)alloc((size_t)NNODE * 4);
  float* al_d2 = (float*)alloc((size_t)NNODE * 4);
  int* deg = (int*)alloc((size_t)NNODE * 4);
  int* rowptr = (int*)alloc((size_t)(NNODE + 1) * 4);
  int* cursor = (int*)alloc((size_t)NNODE * 4);
  int* csr_src = (int*)alloc((size_t)NEDGE * 4);
  int* csr_dst = (int*)alloc((size_t)NEDGE * 4);
  float* w1 = (float*)alloc((size_t)NEDGE * 4 * 4);
  float* w2 = (float*)alloc((size_t)NEDGE * 4);
  unsigned short* w1t = (unsigned short*)alloc((size_t)512 * 128 * 2);  // W1^T bf16 [512][128]
  unsigned short* w2t = (unsigned short*)alloc((size_t)128 * 512 * 2);  // W2^T bf16 [128][512]
  float* vs1 = (float*)alloc((size_t)512 * 4);
  float* vd1 = (float*)alloc((size_t)512 * 4);

  const int* src = edge;
  const int* dst = edge + NEDGE;

  // CSR by dst (shared by both GAT layers) + weight conversion + att pre-transform
  hipMemsetAsync(deg, 0, (size_t)NNODE * 4, stream);
  hist_kernel<<<NEDGE / 256, 256, 0, stream>>>(dst, deg);
  scan_kernel<<<1, 1024, 0, stream>>>(deg, rowptr, cursor);
  scatter_kernel<<<NEDGE / 256, 256, 0, stream>>>(src, dst, cursor, csr_src, csr_dst);
  convw_kernel<<<256, 256, 0, stream>>>(W1, w1t, 128, 512);
  convw_kernel<<<256, 256, 0, stream>>>(W2, w2t, 512, 128);
  attv1_kernel<<<2, 256, 0, stream>>>(W1, att_src1, att_dst1, vs1, vd1);

  // aligner: x0 = emb @ W_align + b_align   [65536,64]@[64,128] -> bf16
  gemm_align_kernel<<<dim3(NNODE / 128, 1), 256, 0, stream>>>(emb, W_align, x0, b_align, 128, 64);
  // GAT1 logits from x0 directly (al = x0 · (W1 @ att))
  al1_kernel<<<NNODE, 256, 0, stream>>>(x0, vs1, vd1, al_s1, al_d1);
  edgew1_kernel<<<NEDGE / 256, 256, 0, stream>>>(csr_src, csr_dst, al_s1, al_d1, w1);
  // GAT1 aggregate-first: ybar[n,h,:] = softmax-weighted mean of x0 rows
  agg1_kernel<<<NNODE / 4, 256, 0, stream>>>(x0, al_s1, al_d1, rowptr, csr_src, w1, ybar);
  // fused: hx2 = elu(ybar @blockdiag W1 + b1) @ W2   (x1 stays in registers/LDS)
  fused12_kernel<<<512, 256, 0, stream>>>(ybar, w1t, w2t, b1, hx2);
  al2_kernel<<<NNODE / 4, 256, 0, stream>>>(hx2, att_src2, att_dst2, al_s2, al_d2);
  edgew2_kernel<<<NEDGE / 256, 256, 0, stream>>>(csr_src, csr_dst, al_s2, al_d2, w2);
  agg2_kernel<<<NNODE / 4, 256, 0, stream>>>(hx2, al_s2, al_d2, rowptr, csr_src, w2, b2, out2);
  // pool + classifier
  poolcls_kernel<<<NGRAPH, 128, 0, stream>>>(out2, Wc1, bc1, Wc2, bc2, (float*)d_out);
}